// Round 1
// baseline (4895.481 us; speedup 1.0000x reference)
//
#include <hip/hip_runtime.h>
#include <cstdint>
#include <cstddef>

#define BT 4
#define CC 96
#define HH 64
#define WW 256
#define LL (HH*WW)    // 16384
#define KD 4
#define RR 6
#define NLAY 2
#define C4 (4*CC)     // 384

// ---------------- build batched input: X[0:2]=concat(x0,x1), X[2:4]=reverse ----------------
__global__ void k_build(const float* __restrict__ x0, const float* __restrict__ x1,
                        float* __restrict__ X){
  size_t i = (size_t)blockIdx.x*256 + threadIdx.x;
  size_t tot = (size_t)2*CC*HH*WW;
  if (i >= tot) return;
  int w = i % WW; size_t r = i / WW;
  int h = r % HH; size_t bc = r / HH;           // b*CC + c, b in 0..1
  float val;
  if (w < 128) val = x0[(bc*HH + h)*128 + w];
  else         val = x1[(bc*HH + h)*128 + (w-128)];
  X[i] = val;
  size_t ib = ((bc + (size_t)2*CC)*HH + h)*WW + (WW-1-w);
  X[ib] = val;
}

// ---------------- LayerNorm over channel dim per pixel ----------------
__global__ void k_ln(const float* __restrict__ x, float* __restrict__ o,
                     const float* __restrict__ w, const float* __restrict__ b){
  int pix = blockIdx.x*256 + threadIdx.x;
  if (pix >= BT*LL) return;
  int bb = pix / LL, l = pix % LL;
  const float* xp = x + (size_t)bb*CC*LL + l;
  float s = 0.f, ss = 0.f;
  for (int c = 0; c < CC; ++c){ float v = xp[(size_t)c*LL]; s += v; ss += v*v; }
  float mu = s*(1.f/CC);
  float var = ss*(1.f/CC) - mu*mu;
  float rs = rsqrtf(var + 1e-5f);
  float* op = o + (size_t)bb*CC*LL + l;
  for (int c = 0; c < CC; ++c)
    op[(size_t)c*LL] = (xp[(size_t)c*LL] - mu)*rs*w[c] + b[c];
}

// ---------------- f32 GEMM: out[b,m,l] = act(sum_c W[m,c]*in[b,c,l] + bias) (+res) ----------------
template<int KK, bool BIAS, bool GELU_, bool RES>
__global__ __launch_bounds__(256) void k_gemm(const float* __restrict__ Wm,
                        const float* __restrict__ in, float* __restrict__ out,
                        const float* __restrict__ bias, const float* __restrict__ res, int M){
  __shared__ float wl[KK*32];
  int lane = threadIdx.x & 63, mg = threadIdx.x >> 6;
  int l0 = blockIdx.x*512, m0 = blockIdx.y*32, b = blockIdx.z;
  for (int idx = threadIdx.x; idx < 32*KK; idx += 256){
    int m = idx & 31, c = idx >> 5;
    wl[c*32 + m] = Wm[(size_t)(m0+m)*KK + c];
  }
  __syncthreads();
  const float* ip = in + (size_t)b*KK*LL + l0 + lane;
  float acc[8][8];
  #pragma unroll
  for (int m = 0; m < 8; ++m)
    #pragma unroll
    for (int j = 0; j < 8; ++j) acc[m][j] = 0.f;
  for (int c = 0; c < KK; ++c){
    float xv[8];
    const float* r = ip + (size_t)c*LL;
    #pragma unroll
    for (int j = 0; j < 8; ++j) xv[j] = r[64*j];
    float wv[8];
    #pragma unroll
    for (int m = 0; m < 8; ++m) wv[m] = wl[c*32 + mg*8 + m];
    #pragma unroll
    for (int m = 0; m < 8; ++m)
      #pragma unroll
      for (int j = 0; j < 8; ++j) acc[m][j] = fmaf(wv[m], xv[j], acc[m][j]);
  }
  #pragma unroll
  for (int m = 0; m < 8; ++m){
    int mm = m0 + mg*8 + m;
    float bv = BIAS ? bias[mm] : 0.f;
    size_t ob = ((size_t)b*M + mm)*LL + l0 + lane;
    #pragma unroll
    for (int j = 0; j < 8; ++j){
      float v = acc[m][j] + bv;
      if (GELU_) v = 0.5f*v*(1.f + erff(v*0.7071067811865475f));
      if (RES)  v += res[ob + 64*j];
      out[ob + 64*j] = v;
    }
  }
}

// ---------------- depthwise 3x3 (SAME) + SiLU ----------------
__global__ void k_dwconv_silu(const float* __restrict__ u, float* __restrict__ v,
                              const float* __restrict__ cw){
  size_t i = (size_t)blockIdx.x*256 + threadIdx.x;
  if (i >= (size_t)BT*CC*LL) return;
  int w = i % WW; size_t t1 = i / WW;
  int h = t1 % HH; size_t bc = t1 / HH;
  int c = (int)(bc % CC);
  const float* up = u + bc*LL;
  const float* k9 = cw + c*9;
  float acc = 0.f;
  #pragma unroll
  for (int dh = -1; dh <= 1; ++dh){
    int h2 = h + dh; if (h2 < 0 || h2 >= HH) continue;
    #pragma unroll
    for (int dw = -1; dw <= 1; ++dw){
      int w2 = w + dw; if (w2 < 0 || w2 >= WW) continue;
      acc = fmaf(up[h2*WW + w2], k9[(dh+1)*3 + (dw+1)], acc);
    }
  }
  v[i] = acc / (1.f + expf(-acc));
}

// ---------------- transpose (h,w)->(w,h) per (b,c) ----------------
__global__ void k_transpose(const float* __restrict__ src, float* __restrict__ dst){
  __shared__ float tile[32][33];
  int bc = blockIdx.z;
  const float* sp = src + (size_t)bc*LL;
  float* dp = dst + (size_t)bc*LL;
  int w0 = blockIdx.x*32, h0 = blockIdx.y*32;
  int tx = threadIdx.x, ty = threadIdx.y;
  #pragma unroll
  for (int kk = 0; kk < 4; ++kk){
    int h = h0 + ty + kk*8;
    tile[ty + kk*8][tx] = sp[(size_t)h*WW + w0 + tx];
  }
  __syncthreads();
  #pragma unroll
  for (int kk = 0; kk < 4; ++kk){
    int w = w0 + ty + kk*8;
    dp[(size_t)w*HH + h0 + tx] = tile[tx][ty + kk*8];
  }
}

// ---------------- x-projection: G[b,k,d,l] = sum_c src[b,c,l]*w[k,d,c], two k per pass ----------------
__global__ void k_xproj(const float* __restrict__ src, float* __restrict__ G,
                        const float* __restrict__ xpw, int kA, int kB){
  size_t i = (size_t)blockIdx.x*256 + threadIdx.x;
  if (i >= (size_t)BT*LL) return;
  int b = (int)(i / LL), l = (int)(i % LL);
  const float* sp = src + (size_t)b*CC*LL + l;
  const float* wA = xpw + (size_t)kA*8*CC;
  const float* wB = xpw + (size_t)kB*8*CC;
  float aA[8], aB[8];
  #pragma unroll
  for (int d = 0; d < 8; ++d){ aA[d] = 0.f; aB[d] = 0.f; }
  for (int c = 0; c < CC; ++c){
    float xv = sp[(size_t)c*LL];
    #pragma unroll
    for (int d = 0; d < 8; ++d){
      aA[d] = fmaf(wA[d*CC + c], xv, aA[d]);
      aB[d] = fmaf(wB[d*CC + c], xv, aB[d]);
    }
  }
  float* gA = G + (((size_t)b*KD + kA)*8)*LL + l;
  float* gB = G + (((size_t)b*KD + kB)*8)*LL + l;
  #pragma unroll
  for (int d = 0; d < 8; ++d){ gA[(size_t)d*LL] = aA[d]; gB[(size_t)d*LL] = aB[d]; }
}

// ---------------- selective scan: one wave per (b,k,c) sequence ----------------
__global__ __launch_bounds__(256) void k_scan(const float* __restrict__ G,
                       const float* __restrict__ v, const float* __restrict__ vT,
                       float* __restrict__ y_row, float* __restrict__ y_col,
                       const float* __restrict__ dtw_, const float* __restrict__ dtb_,
                       const float* __restrict__ Alog_, const float* __restrict__ Ds_){
  int wid = threadIdx.x >> 6, lane = threadIdx.x & 63;
  int seq = blockIdx.x*4 + wid;                  // 0..1535
  int c = seq % CC, k = (seq/CC) % KD, b = seq/(CC*KD);
  const float* src = ((k & 1) ? vT : v) + ((size_t)b*CC + c)*LL;
  const float* g = G + (((size_t)b*KD + k)*8)*LL;
  bool rev = (k >= 2);
  float dtw[RR];
  #pragma unroll
  for (int r = 0; r < RR; ++r) dtw[r] = dtw_[((size_t)k*CC + c)*RR + r];
  float dtb = dtb_[k*CC + c];
  float A  = -expf(Alog_[k*CC + c]);
  float Dv = Ds_[k*CC + c];
  const int CH = LL/64;                          // 256
  int l0 = lane*CH;
  float P = 1.f, Q = 0.f;
  for (int i = 0; i < CH; ++i){
    int l = l0 + i;
    int s = rev ? (LL-1-l) : l;
    float dsum = dtb;
    #pragma unroll
    for (int r = 0; r < RR; ++r) dsum = fmaf(g[(size_t)r*LL + s], dtw[r], dsum);
    float delta = (dsum > 20.f) ? dsum : log1pf(expf(dsum));
    float a = expf(delta * A);
    float bt = delta * g[(size_t)6*LL + s] * src[s];
    Q = fmaf(a, Q, bt);
    P *= a;
  }
  #pragma unroll
  for (int off = 1; off < 64; off <<= 1){
    float Pp = __shfl_up(P, (unsigned)off);
    float Qp = __shfl_up(Q, (unsigned)off);
    if (lane >= off){ Q = fmaf(P, Qp, Q); P *= Pp; }
  }
  float hin = __shfl_up(Q, 1u);
  if (lane == 0) hin = 0.f;
  float h = hin;
  float* yout = ((k & 1) ? y_col : y_row) + ((size_t)b*CC + c)*LL;
  for (int i = 0; i < CH; ++i){
    int l = l0 + i;
    int s = rev ? (LL-1-l) : l;
    float dsum = dtb;
    #pragma unroll
    for (int r = 0; r < RR; ++r) dsum = fmaf(g[(size_t)r*LL + s], dtw[r], dsum);
    float delta = (dsum > 20.f) ? dsum : log1pf(expf(dsum));
    float a = expf(delta * A);
    float xv = src[s];
    float bt = delta * g[(size_t)6*LL + s] * xv;
    h = fmaf(a, h, bt);
    float ys = fmaf(g[(size_t)7*LL + s], h, Dv*xv);
    atomicAdd(&yout[s], ys);
  }
}

// ---------------- combine y_row + transposed y_col ----------------
__global__ void k_combine(const float* __restrict__ yr, const float* __restrict__ yc,
                          float* __restrict__ z){
  __shared__ float tile[32][33];
  int bc = blockIdx.z;
  const float* ycp = yc + (size_t)bc*LL;
  int w0 = blockIdx.x*32, h0 = blockIdx.y*32;
  int tx = threadIdx.x, ty = threadIdx.y;
  #pragma unroll
  for (int kk = 0; kk < 4; ++kk){
    int w = w0 + ty + kk*8;
    tile[ty + kk*8][tx] = ycp[(size_t)w*HH + h0 + tx];
  }
  __syncthreads();
  const float* yrp = yr + (size_t)bc*LL;
  float* zp = z + (size_t)bc*LL;
  #pragma unroll
  for (int kk = 0; kk < 4; ++kk){
    int h = h0 + ty + kk*8;
    zp[(size_t)h*WW + w0 + tx] = yrp[(size_t)h*WW + w0 + tx] + tile[tx][ty + kk*8];
  }
}

// ---------------- final output split/average ----------------
__global__ void k_output(const float* __restrict__ X, float* __restrict__ out){
  size_t i = (size_t)blockIdx.x*256 + threadIdx.x;
  size_t half = (size_t)2*CC*HH*128;
  if (i >= half) return;
  int w = i % 128; size_t r = i / 128;
  int h = r % HH; size_t bc = r / HH;
  size_t fwd = (bc*HH + h)*WW;
  size_t bwd = ((bc + (size_t)2*CC)*HH + h)*WW;
  out[i]        = 0.5f*(X[fwd + w]       + X[bwd + (WW-1-w)]);
  out[half + i] = 0.5f*(X[fwd + 128 + w] + X[bwd + (127 - w)]);
}

extern "C" void kernel_launch(void* const* d_in, const int* in_sizes, int n_in,
                              void* d_out, int out_size, void* d_ws, size_t ws_size,
                              hipStream_t stream){
  const float* x0        = (const float*)d_in[0];
  const float* x1        = (const float*)d_in[1];
  const float* norm_w    = (const float*)d_in[2];
  const float* norm_b    = (const float*)d_in[3];
  const float* in_proj_w = (const float*)d_in[4];
  const float* conv_w    = (const float*)d_in[5];
  const float* x_proj_w  = (const float*)d_in[6];
  const float* dt_w      = (const float*)d_in[7];
  const float* dt_b      = (const float*)d_in[8];
  const float* A_logs    = (const float*)d_in[9];
  const float* Ds        = (const float*)d_in[10];
  const float* out_norm_w= (const float*)d_in[11];
  const float* out_norm_b= (const float*)d_in[12];
  const float* out_proj_w= (const float*)d_in[13];
  const float* norm2_w   = (const float*)d_in[14];
  const float* norm2_b   = (const float*)d_in[15];
  const float* fc1_w     = (const float*)d_in[16];
  const float* fc1_b     = (const float*)d_in[17];
  const float* fc2_w     = (const float*)d_in[18];
  const float* fc2_b     = (const float*)d_in[19];

  const size_t SZ = (size_t)BT*CC*LL;            // 6,291,456 floats
  float* X  = (float*)d_ws;
  float* t  = X + SZ;
  float* u  = t + SZ;
  float* G  = u + SZ;                            // BT*KD*8*LL = 2,097,152 floats
  float* v  = G + (size_t)BT*KD*8*LL;
  float* vT = v + SZ;
  float* yr = vT + SZ;
  float* yc = yr + SZ;
  float* hm = v;                                 // MLP hidden overlays v,vT,yr,yc (4*SZ)

  k_build<<<(2*CC*HH*WW + 255)/256, 256, 0, stream>>>(x0, x1, X);

  for (int lay = 0; lay < NLAY; ++lay){
    const float* nw  = norm_w    + lay*CC;
    const float* nb  = norm_b    + lay*CC;
    const float* ipw = in_proj_w + (size_t)lay*CC*CC;
    const float* cw  = conv_w    + (size_t)lay*CC*9;
    const float* xpw = x_proj_w  + (size_t)lay*KD*8*CC;
    const float* dw  = dt_w      + (size_t)lay*KD*CC*RR;
    const float* db  = dt_b      + (size_t)lay*KD*CC;
    const float* Al  = A_logs    + (size_t)lay*KD*CC;
    const float* Dp  = Ds        + (size_t)lay*KD*CC;
    const float* onw = out_norm_w+ lay*CC;
    const float* onb = out_norm_b+ lay*CC;
    const float* opw = out_proj_w+ (size_t)lay*CC*CC;
    const float* n2w = norm2_w   + lay*CC;
    const float* n2b = norm2_b   + lay*CC;
    const float* f1w = fc1_w     + (size_t)lay*C4*CC;
    const float* f1b = fc1_b     + (size_t)lay*C4;
    const float* f2w = fc2_w     + (size_t)lay*CC*C4;
    const float* f2b = fc2_b     + (size_t)lay*CC;

    k_ln<<<BT*LL/256, 256, 0, stream>>>(X, t, nw, nb);
    k_gemm<96,false,false,false><<<dim3(32,3,BT), 256, 0, stream>>>(ipw, t, u, nullptr, nullptr, 96);
    k_dwconv_silu<<<(unsigned)((SZ + 255)/256), 256, 0, stream>>>(u, v, cw);
    k_transpose<<<dim3(8,2,BT*CC), dim3(32,8), 0, stream>>>(v, vT);
    k_xproj<<<BT*LL/256, 256, 0, stream>>>(v,  G, xpw, 0, 2);
    k_xproj<<<BT*LL/256, 256, 0, stream>>>(vT, G, xpw, 1, 3);
    hipMemsetAsync(yr, 0, 2*SZ*sizeof(float), stream);
    k_scan<<<384, 256, 0, stream>>>(G, v, vT, yr, yc, dw, db, Al, Dp);
    k_combine<<<dim3(8,2,BT*CC), dim3(32,8), 0, stream>>>(yr, yc, t);
    k_ln<<<BT*LL/256, 256, 0, stream>>>(t, u, onw, onb);
    k_gemm<96,false,false,true><<<dim3(32,3,BT), 256, 0, stream>>>(opw, u, X, nullptr, X, 96);
    k_ln<<<BT*LL/256, 256, 0, stream>>>(X, t, n2w, n2b);
    k_gemm<96,true,true,false><<<dim3(32,12,BT), 256, 0, stream>>>(f1w, t, hm, f1b, nullptr, C4);
    k_gemm<384,true,false,true><<<dim3(32,3,BT), 256, 0, stream>>>(f2w, hm, X, f2b, X, 96);
  }

  k_output<<<(unsigned)(((size_t)2*CC*HH*128 + 255)/256), 256, 0, stream>>>(X, (float*)d_out);
}

// Round 2
// 1075.179 us; speedup vs baseline: 4.5532x; 4.5532x over previous
//
#include <hip/hip_runtime.h>
#include <cstdint>
#include <cstddef>

#define BT 4
#define CC 96
#define HH 64
#define WW 256
#define LL (HH*WW)    // 16384
#define KD 4
#define RR 6
#define NLAY 2
#define C4 (4*CC)     // 384
#define TPW 256       // stored elements per scan wave
#define WARM 128      // lookback warm-up elements

// ---------------- build batched input: X[0:2]=concat(x0,x1), X[2:4]=reverse ----------------
__global__ void k_build(const float* __restrict__ x0, const float* __restrict__ x1,
                        float* __restrict__ X){
  size_t i = (size_t)blockIdx.x*256 + threadIdx.x;
  size_t tot = (size_t)2*CC*HH*WW;
  if (i >= tot) return;
  int w = i % WW; size_t r = i / WW;
  int h = r % HH; size_t bc = r / HH;           // b*CC + c, b in 0..1
  float val;
  if (w < 128) val = x0[(bc*HH + h)*128 + w];
  else         val = x1[(bc*HH + h)*128 + (w-128)];
  X[i] = val;
  size_t ib = ((bc + (size_t)2*CC)*HH + h)*WW + (WW-1-w);
  X[ib] = val;
}

// ---------------- LayerNorm over channel dim per pixel ----------------
__global__ void k_ln(const float* __restrict__ x, float* __restrict__ o,
                     const float* __restrict__ w, const float* __restrict__ b){
  int pix = blockIdx.x*256 + threadIdx.x;
  if (pix >= BT*LL) return;
  int bb = pix / LL, l = pix % LL;
  const float* xp = x + (size_t)bb*CC*LL + l;
  float s = 0.f, ss = 0.f;
  for (int c = 0; c < CC; ++c){ float v = xp[(size_t)c*LL]; s += v; ss += v*v; }
  float mu = s*(1.f/CC);
  float var = ss*(1.f/CC) - mu*mu;
  float rs = rsqrtf(var + 1e-5f);
  float* op = o + (size_t)bb*CC*LL + l;
  for (int c = 0; c < CC; ++c)
    op[(size_t)c*LL] = (xp[(size_t)c*LL] - mu)*rs*w[c] + b[c];
}

// ---------------- f32 GEMM: out[b,m,l] = act(sum_c W[m,c]*in[b,c,l] + bias) (+res) ----------------
template<int KK, bool BIAS, bool GELU_, bool RES>
__global__ __launch_bounds__(256) void k_gemm(const float* __restrict__ Wm,
                        const float* __restrict__ in, float* __restrict__ out,
                        const float* __restrict__ bias, const float* __restrict__ res, int M){
  __shared__ float wl[KK*32];
  int lane = threadIdx.x & 63, mg = threadIdx.x >> 6;
  int l0 = blockIdx.x*512, m0 = blockIdx.y*32, b = blockIdx.z;
  for (int idx = threadIdx.x; idx < 32*KK; idx += 256){
    int m = idx & 31, c = idx >> 5;
    wl[c*32 + m] = Wm[(size_t)(m0+m)*KK + c];
  }
  __syncthreads();
  const float* ip = in + (size_t)b*KK*LL + l0 + lane;
  float acc[8][8];
  #pragma unroll
  for (int m = 0; m < 8; ++m)
    #pragma unroll
    for (int j = 0; j < 8; ++j) acc[m][j] = 0.f;
  for (int c = 0; c < KK; ++c){
    float xv[8];
    const float* r = ip + (size_t)c*LL;
    #pragma unroll
    for (int j = 0; j < 8; ++j) xv[j] = r[64*j];
    float wv[8];
    #pragma unroll
    for (int m = 0; m < 8; ++m) wv[m] = wl[c*32 + mg*8 + m];
    #pragma unroll
    for (int m = 0; m < 8; ++m)
      #pragma unroll
      for (int j = 0; j < 8; ++j) acc[m][j] = fmaf(wv[m], xv[j], acc[m][j]);
  }
  #pragma unroll
  for (int m = 0; m < 8; ++m){
    int mm = m0 + mg*8 + m;
    float bv = BIAS ? bias[mm] : 0.f;
    size_t ob = ((size_t)b*M + mm)*LL + l0 + lane;
    #pragma unroll
    for (int j = 0; j < 8; ++j){
      float v = acc[m][j] + bv;
      if (GELU_) v = 0.5f*v*(1.f + erff(v*0.7071067811865475f));
      if (RES)  v += res[ob + 64*j];
      out[ob + 64*j] = v;
    }
  }
}

// ---------------- depthwise 3x3 (SAME) + SiLU ----------------
__global__ void k_dwconv_silu(const float* __restrict__ u, float* __restrict__ v,
                              const float* __restrict__ cw){
  size_t i = (size_t)blockIdx.x*256 + threadIdx.x;
  if (i >= (size_t)BT*CC*LL) return;
  int w = i % WW; size_t t1 = i / WW;
  int h = t1 % HH; size_t bc = t1 / HH;
  int c = (int)(bc % CC);
  const float* up = u + bc*LL;
  const float* k9 = cw + c*9;
  float acc = 0.f;
  #pragma unroll
  for (int dh = -1; dh <= 1; ++dh){
    int h2 = h + dh; if (h2 < 0 || h2 >= HH) continue;
    #pragma unroll
    for (int dw = -1; dw <= 1; ++dw){
      int w2 = w + dw; if (w2 < 0 || w2 >= WW) continue;
      acc = fmaf(up[h2*WW + w2], k9[(dh+1)*3 + (dw+1)], acc);
    }
  }
  v[i] = acc / (1.f + expf(-acc));
}

// ---------------- transpose (h,w)->(w,h) per (b,c) ----------------
__global__ void k_transpose(const float* __restrict__ src, float* __restrict__ dst){
  __shared__ float tile[32][33];
  int bc = blockIdx.z;
  const float* sp = src + (size_t)bc*LL;
  float* dp = dst + (size_t)bc*LL;
  int w0 = blockIdx.x*32, h0 = blockIdx.y*32;
  int tx = threadIdx.x, ty = threadIdx.y;
  #pragma unroll
  for (int kk = 0; kk < 4; ++kk){
    int h = h0 + ty + kk*8;
    tile[ty + kk*8][tx] = sp[(size_t)h*WW + w0 + tx];
  }
  __syncthreads();
  #pragma unroll
  for (int kk = 0; kk < 4; ++kk){
    int w = w0 + ty + kk*8;
    dp[(size_t)w*HH + h0 + tx] = tile[tx][ty + kk*8];
  }
}

// ---------------- x-projection: G[b,k,d,l] = sum_c src[b,c,l]*w[k,d,c], two k per pass ----------------
__global__ void k_xproj(const float* __restrict__ src, float* __restrict__ G,
                        const float* __restrict__ xpw, int kA, int kB){
  size_t i = (size_t)blockIdx.x*256 + threadIdx.x;
  if (i >= (size_t)BT*LL) return;
  int b = (int)(i / LL), l = (int)(i % LL);
  const float* sp = src + (size_t)b*CC*LL + l;
  const float* wA = xpw + (size_t)kA*8*CC;
  const float* wB = xpw + (size_t)kB*8*CC;
  float aA[8], aB[8];
  #pragma unroll
  for (int d = 0; d < 8; ++d){ aA[d] = 0.f; aB[d] = 0.f; }
  for (int c = 0; c < CC; ++c){
    float xv = sp[(size_t)c*LL];
    #pragma unroll
    for (int d = 0; d < 8; ++d){
      aA[d] = fmaf(wA[d*CC + c], xv, aA[d]);
      aB[d] = fmaf(wB[d*CC + c], xv, aB[d]);
    }
  }
  float* gA = G + (((size_t)b*KD + kA)*8)*LL + l;
  float* gB = G + (((size_t)b*KD + kB)*8)*LL + l;
  #pragma unroll
  for (int d = 0; d < 8; ++d){ gA[(size_t)d*LL] = aA[d]; gB[(size_t)d*LL] = aB[d]; }
}

// ---------------- tile-parallel selective scan with lookback warm-up ----------------
// one wave per (seq, tile-of-256); warm-up 128 elems (state from further back decays
// below 1e-15 since a = exp(-softplus(dt)) <~ 0.75). Coalesced: lane = element.
__global__ __launch_bounds__(256) void k_scan2(const float* __restrict__ G,
                       const float* __restrict__ v, const float* __restrict__ vT,
                       float* __restrict__ Y,     // 4 direction buffers, each BT*CC*LL
                       const float* __restrict__ dtw_, const float* __restrict__ dtb_,
                       const float* __restrict__ Alog_, const float* __restrict__ Ds_){
  const size_t SZ = (size_t)BT*CC*LL;
  int wid = threadIdx.x >> 6, lane = threadIdx.x & 63;
  int tile = blockIdx.x*4 + wid;                 // 0..63
  int seq  = blockIdx.y;                         // 0..1535
  int c = seq % CC, k = (seq/CC) % KD, b = seq/(CC*KD);
  const float* src = ((k & 1) ? vT : v) + ((size_t)b*CC + c)*LL;
  const float* g = G + (((size_t)b*KD + k)*8)*LL;
  bool rev = (k >= 2);
  float dtw[RR];
  #pragma unroll
  for (int r = 0; r < RR; ++r) dtw[r] = dtw_[((size_t)k*CC + c)*RR + r];
  float dtb = dtb_[k*CC + c];
  float A  = -expf(Alog_[k*CC + c]);
  float Dv = Ds_[k*CC + c];
  float* yout = Y + (size_t)k*SZ + ((size_t)b*CC + c)*LL;

  int lstore0 = tile*TPW;                        // first stored logical index
  int lstart  = (tile == 0) ? 0 : (lstore0 - WARM);
  int nsub    = (tile == 0) ? (TPW/64) : ((TPW+WARM)/64);
  float carry = 0.f;
  for (int subi = 0; subi < nsub; ++subi){
    int lbase = lstart + subi*64;
    int l = lbase + lane;
    int s = rev ? (LL-1-l) : l;
    float dsum = dtb;
    #pragma unroll
    for (int r = 0; r < RR; ++r) dsum = fmaf(g[(size_t)r*LL + s], dtw[r], dsum);
    float delta = (dsum > 20.f) ? dsum : log1pf(expf(dsum));
    float a = expf(delta * A);
    float xv = src[s];
    float bt = delta * g[(size_t)6*LL + s] * xv;
    float P = a, Q = bt;
    #pragma unroll
    for (int off = 1; off < 64; off <<= 1){
      float Pp = __shfl_up(P, (unsigned)off);
      float Qp = __shfl_up(Q, (unsigned)off);
      if (lane >= off){ Q = fmaf(P, Qp, Q); P *= Pp; }
    }
    float h = fmaf(P, carry, Q);
    carry = __shfl(h, 63);
    if (lbase >= lstore0){
      float ys = fmaf(g[(size_t)7*LL + s], h, Dv*xv);
      yout[s] = ys;
    }
  }
}

// ---------------- combine: z = (y0+y2) + transpose(y1+y3) ----------------
__global__ void k_combine4(const float* __restrict__ Y, float* __restrict__ z){
  const size_t SZ = (size_t)BT*CC*LL;
  __shared__ float tile[32][33];
  int bc = blockIdx.z;
  const float* y1p = Y + SZ   + (size_t)bc*LL;   // col-major [w*HH+h]
  const float* y3p = Y + 3*SZ + (size_t)bc*LL;
  int w0 = blockIdx.x*32, h0 = blockIdx.y*32;
  int tx = threadIdx.x, ty = threadIdx.y;
  #pragma unroll
  for (int kk = 0; kk < 4; ++kk){
    int w = w0 + ty + kk*8;
    size_t idx = (size_t)w*HH + h0 + tx;
    tile[ty + kk*8][tx] = y1p[idx] + y3p[idx];
  }
  __syncthreads();
  const float* y0p = Y +        (size_t)bc*LL;
  const float* y2p = Y + 2*SZ + (size_t)bc*LL;
  float* zp = z + (size_t)bc*LL;
  #pragma unroll
  for (int kk = 0; kk < 4; ++kk){
    int h = h0 + ty + kk*8;
    size_t idx = (size_t)h*WW + w0 + tx;
    zp[idx] = y0p[idx] + y2p[idx] + tile[tx][ty + kk*8];
  }
}

// ---------------- final output split/average ----------------
__global__ void k_output(const float* __restrict__ X, float* __restrict__ out){
  size_t i = (size_t)blockIdx.x*256 + threadIdx.x;
  size_t half = (size_t)2*CC*HH*128;
  if (i >= half) return;
  int w = i % 128; size_t r = i / 128;
  int h = r % HH; size_t bc = r / HH;
  size_t fwd = (bc*HH + h)*WW;
  size_t bwd = ((bc + (size_t)2*CC)*HH + h)*WW;
  out[i]        = 0.5f*(X[fwd + w]       + X[bwd + (WW-1-w)]);
  out[half + i] = 0.5f*(X[fwd + 128 + w] + X[bwd + (127 - w)]);
}

extern "C" void kernel_launch(void* const* d_in, const int* in_sizes, int n_in,
                              void* d_out, int out_size, void* d_ws, size_t ws_size,
                              hipStream_t stream){
  const float* x0        = (const float*)d_in[0];
  const float* x1        = (const float*)d_in[1];
  const float* norm_w    = (const float*)d_in[2];
  const float* norm_b    = (const float*)d_in[3];
  const float* in_proj_w = (const float*)d_in[4];
  const float* conv_w    = (const float*)d_in[5];
  const float* x_proj_w  = (const float*)d_in[6];
  const float* dt_w      = (const float*)d_in[7];
  const float* dt_b      = (const float*)d_in[8];
  const float* A_logs    = (const float*)d_in[9];
  const float* Ds        = (const float*)d_in[10];
  const float* out_norm_w= (const float*)d_in[11];
  const float* out_norm_b= (const float*)d_in[12];
  const float* out_proj_w= (const float*)d_in[13];
  const float* norm2_w   = (const float*)d_in[14];
  const float* norm2_b   = (const float*)d_in[15];
  const float* fc1_w     = (const float*)d_in[16];
  const float* fc1_b     = (const float*)d_in[17];
  const float* fc2_w     = (const float*)d_in[18];
  const float* fc2_b     = (const float*)d_in[19];

  const size_t SZ = (size_t)BT*CC*LL;            // 6,291,456 floats
  float* X  = (float*)d_ws;
  float* t  = X + SZ;
  float* u  = t + SZ;
  float* G  = u + SZ;                            // BT*KD*8*LL = 2,097,152 floats
  float* v  = G + (size_t)BT*KD*8*LL;
  float* vT = v + SZ;
  float* yr = vT + SZ;
  float* yc = yr + SZ;
  // scan output: 4 direction buffers. Y0=yr, Y1=yc, Y2=t(free), Y3=u(free)
  // but they must be contiguous per-direction via base pointer Y with k*SZ offsets:
  // use yr as base so Y0=yr, Y1=yc, and place Y2,Y3 after yc. yc+SZ would overflow
  // the old footprint only if ws is tight — instead reuse t,u by passing base = t
  // won't give contiguity. Simplest: Y = yr with 4 contiguous SZ buffers
  // (yr, yc, +2 more). Old footprint already had yr,yc at the end; extend by
  // overlaying the two extra buffers onto t,u is impossible contiguously, so we
  // instead define Y = t and order: t(Y0), u(Y1), then we need Y2,Y3 contiguous
  // after u — that's G,v which are live. => Use yr-based with 2 extra SZ past yc.
  float* Y = yr;                                 // Y[k] = yr + k*SZ (k=0..3)
  float* hm = v;                                 // MLP hidden overlays v..(4 SZ)

  k_build<<<(2*CC*HH*WW + 255)/256, 256, 0, stream>>>(x0, x1, X);

  for (int lay = 0; lay < NLAY; ++lay){
    const float* nw  = norm_w    + lay*CC;
    const float* nb  = norm_b    + lay*CC;
    const float* ipw = in_proj_w + (size_t)lay*CC*CC;
    const float* cw  = conv_w    + (size_t)lay*CC*9;
    const float* xpw = x_proj_w  + (size_t)lay*KD*8*CC;
    const float* dw  = dt_w      + (size_t)lay*KD*CC*RR;
    const float* db  = dt_b      + (size_t)lay*KD*CC;
    const float* Al  = A_logs    + (size_t)lay*KD*CC;
    const float* Dp  = Ds        + (size_t)lay*KD*CC;
    const float* onw = out_norm_w+ lay*CC;
    const float* onb = out_norm_b+ lay*CC;
    const float* opw = out_proj_w+ (size_t)lay*CC*CC;
    const float* n2w = norm2_w   + lay*CC;
    const float* n2b = norm2_b   + lay*CC;
    const float* f1w = fc1_w     + (size_t)lay*C4*CC;
    const float* f1b = fc1_b     + (size_t)lay*C4;
    const float* f2w = fc2_w     + (size_t)lay*CC*C4;
    const float* f2b = fc2_b     + (size_t)lay*CC;

    k_ln<<<BT*LL/256, 256, 0, stream>>>(X, t, nw, nb);
    k_gemm<96,false,false,false><<<dim3(32,3,BT), 256, 0, stream>>>(ipw, t, u, nullptr, nullptr, 96);
    k_dwconv_silu<<<(unsigned)((SZ + 255)/256), 256, 0, stream>>>(u, v, cw);
    k_transpose<<<dim3(8,2,BT*CC), dim3(32,8), 0, stream>>>(v, vT);
    k_xproj<<<BT*LL/256, 256, 0, stream>>>(v,  G, xpw, 0, 2);
    k_xproj<<<BT*LL/256, 256, 0, stream>>>(vT, G, xpw, 1, 3);
    k_scan2<<<dim3(16,1536), 256, 0, stream>>>(G, v, vT, Y, dw, db, Al, Dp);
    k_combine4<<<dim3(8,2,BT*CC), dim3(32,8), 0, stream>>>(Y, t);
    k_ln<<<BT*LL/256, 256, 0, stream>>>(t, u, onw, onb);
    k_gemm<96,false,false,true><<<dim3(32,3,BT), 256, 0, stream>>>(opw, u, X, nullptr, X, 96);
    k_ln<<<BT*LL/256, 256, 0, stream>>>(X, t, n2w, n2b);
    k_gemm<96,true,true,false><<<dim3(32,12,BT), 256, 0, stream>>>(f1w, t, hm, f1b, nullptr, C4);
    k_gemm<384,true,false,true><<<dim3(32,3,BT), 256, 0, stream>>>(f2w, hm, X, f2b, X, 96);
  }

  k_output<<<(unsigned)(((size_t)2*CC*HH*128 + 255)/256), 256, 0, stream>>>(X, (float*)d_out);
}

// Round 3
// 792.911 us; speedup vs baseline: 6.1741x; 1.3560x over previous
//
#include <hip/hip_runtime.h>
#include <cstdint>
#include <cstddef>

#define BT 4
#define CC 96
#define HH 64
#define WW 256
#define LL (HH*WW)    // 16384
#define KD 4
#define RR 6
#define NLAY 2
#define C4 (4*CC)     // 384

// ---------------- build batched input: X[0:2]=concat(x0,x1), X[2:4]=reverse ----------------
__global__ void k_build(const float* __restrict__ x0, const float* __restrict__ x1,
                        float* __restrict__ X){
  size_t i = (size_t)blockIdx.x*256 + threadIdx.x;
  size_t tot = (size_t)2*CC*HH*WW;
  if (i >= tot) return;
  int w = i % WW; size_t r = i / WW;
  int h = r % HH; size_t bc = r / HH;           // b*CC + c, b in 0..1
  float val;
  if (w < 128) val = x0[(bc*HH + h)*128 + w];
  else         val = x1[(bc*HH + h)*128 + (w-128)];
  X[i] = val;
  size_t ib = ((bc + (size_t)2*CC)*HH + h)*WW + (WW-1-w);
  X[ib] = val;
}

// ---------------- per-pixel LN stats: st[0..BT*LL)=mu, st[BT*LL..)=rs ----------------
__global__ void k_stats(const float* __restrict__ x, float* __restrict__ st){
  int pix = blockIdx.x*256 + threadIdx.x;
  if (pix >= BT*LL) return;
  int bb = pix / LL, l = pix % LL;
  const float* xp = x + (size_t)bb*CC*LL + l;
  float s = 0.f, ss = 0.f;
  for (int c = 0; c < CC; ++c){ float v = xp[(size_t)c*LL]; s += v; ss += v*v; }
  float mu = s*(1.f/CC);
  float var = ss*(1.f/CC) - mu*mu;
  st[pix] = mu;
  st[(size_t)BT*LL + pix] = rsqrtf(var + 1e-5f);
}

// ---------------- GEMM: out[b,m,l] = act(LN?(sum_c W[m,c]*in[b,c,l]) + bias) (+res) ----------------
// LN fused via linearity: out = rs*(sum (W.*lnw) x) - mu*rs*S1[m] + Sb[m]
template<int KK, bool LNF, bool BIAS, bool GELU_, bool RES>
__global__ __launch_bounds__(256) void k_gemm(const float* __restrict__ Wm,
    const float* __restrict__ in, float* __restrict__ out,
    const float* __restrict__ bias, const float* __restrict__ res,
    const float* __restrict__ lnw, const float* __restrict__ lnb,
    const float* __restrict__ st, int M){
  constexpr int KC = 96;
  __shared__ float wl[KC*36];
  __shared__ float s1a[32], sba[32];
  int tid = threadIdx.x, lane = tid & 63, mg = tid >> 6;
  int l0 = blockIdx.x*256, m0 = blockIdx.y*32, b = blockIdx.z;
  int lbase = l0 + lane*4;
  float acc[8][4];
  #pragma unroll
  for (int m = 0; m < 8; ++m){ acc[m][0]=0.f; acc[m][1]=0.f; acc[m][2]=0.f; acc[m][3]=0.f; }

  for (int cb = 0; cb < KK; cb += KC){
    for (int jj = tid; jj < 32*KC; jj += 256){
      int m = jj / KC, c = jj - m*KC;
      float wv = Wm[(size_t)(m0+m)*KK + cb + c];
      if (LNF) wv *= lnw[cb + c];
      wl[c*36 + m] = wv;
    }
    __syncthreads();
    if (LNF && cb == 0 && tid < 32){
      float s1 = 0.f, sb = 0.f;
      for (int c = 0; c < KC; ++c){
        s1 += wl[c*36 + tid];
        sb = fmaf(Wm[(size_t)(m0+tid)*KK + c], lnb[c], sb);
      }
      s1a[tid] = s1; sba[tid] = sb;
    }
    const float* ip = in + (size_t)b*KK*LL + (size_t)cb*LL + lbase;
    #pragma unroll 4
    for (int c = 0; c < KC; ++c){
      float4 xv = *(const float4*)(ip + (size_t)c*LL);
      const float4* wp = (const float4*)&wl[c*36 + mg*8];
      float4 wa = wp[0], wb2 = wp[1];
      float wv[8] = {wa.x,wa.y,wa.z,wa.w,wb2.x,wb2.y,wb2.z,wb2.w};
      #pragma unroll
      for (int m = 0; m < 8; ++m){
        acc[m][0] = fmaf(wv[m], xv.x, acc[m][0]);
        acc[m][1] = fmaf(wv[m], xv.y, acc[m][1]);
        acc[m][2] = fmaf(wv[m], xv.z, acc[m][2]);
        acc[m][3] = fmaf(wv[m], xv.w, acc[m][3]);
      }
    }
    __syncthreads();
  }

  float mu4[4], rs4[4];
  if (LNF){
    const float* mu = st; const float* rs = st + (size_t)BT*LL;
    int pix = b*LL + lbase;
    float4 m4 = *(const float4*)&mu[pix];
    float4 r4 = *(const float4*)&rs[pix];
    mu4[0]=m4.x; mu4[1]=m4.y; mu4[2]=m4.z; mu4[3]=m4.w;
    rs4[0]=r4.x; rs4[1]=r4.y; rs4[2]=r4.z; rs4[3]=r4.w;
  }
  #pragma unroll
  for (int m = 0; m < 8; ++m){
    int mm = m0 + mg*8 + m;
    float s1 = LNF ? s1a[mg*8+m] : 0.f;
    float sb = LNF ? sba[mg*8+m] : 0.f;
    float bv = BIAS ? bias[mm] : 0.f;
    size_t ob = ((size_t)b*M + mm)*LL + lbase;
    float o[4];
    #pragma unroll
    for (int j = 0; j < 4; ++j){
      float vv = acc[m][j];
      if (LNF) vv = fmaf(rs4[j], vv, fmaf(-mu4[j]*rs4[j], s1, sb));
      vv += bv;
      if (GELU_){
        float uu = 0.7978845608f*(vv + 0.044715f*vv*vv*vv);
        float e2 = __expf(2.f*uu);
        float th = (e2 - 1.f)/(e2 + 1.f);
        vv = 0.5f*vv*(1.f + th);
      }
      if (RES) vv += res[ob + j];
      o[j] = vv;
    }
    *(float4*)&out[ob] = make_float4(o[0],o[1],o[2],o[3]);
  }
}

// ---------------- depthwise 3x3 (SAME) + SiLU ----------------
__global__ void k_dwconv_silu(const float* __restrict__ u, float* __restrict__ v,
                              const float* __restrict__ cw){
  size_t i = (size_t)blockIdx.x*256 + threadIdx.x;
  if (i >= (size_t)BT*CC*LL) return;
  int w = i % WW; size_t t1 = i / WW;
  int h = t1 % HH; size_t bc = t1 / HH;
  int c = (int)(bc % CC);
  const float* up = u + bc*LL;
  const float* k9 = cw + c*9;
  float acc = 0.f;
  #pragma unroll
  for (int dh = -1; dh <= 1; ++dh){
    int h2 = h + dh; if (h2 < 0 || h2 >= HH) continue;
    #pragma unroll
    for (int dw = -1; dw <= 1; ++dw){
      int w2 = w + dw; if (w2 < 0 || w2 >= WW) continue;
      acc = fmaf(up[h2*WW + w2], k9[(dh+1)*3 + (dw+1)], acc);
    }
  }
  v[i] = acc / (1.f + __expf(-acc));
}

// ---------------- transpose (h,w)->(w,h) per (b,c) ----------------
__global__ void k_transpose(const float* __restrict__ src, float* __restrict__ dst){
  __shared__ float tile[32][33];
  int bc = blockIdx.z;
  const float* sp = src + (size_t)bc*LL;
  float* dp = dst + (size_t)bc*LL;
  int w0 = blockIdx.x*32, h0 = blockIdx.y*32;
  int tx = threadIdx.x, ty = threadIdx.y;
  #pragma unroll
  for (int kk = 0; kk < 4; ++kk){
    int h = h0 + ty + kk*8;
    tile[ty + kk*8][tx] = sp[(size_t)h*WW + w0 + tx];
  }
  __syncthreads();
  #pragma unroll
  for (int kk = 0; kk < 4; ++kk){
    int w = w0 + ty + kk*8;
    dp[(size_t)w*HH + h0 + tx] = tile[tx][ty + kk*8];
  }
}

// ---------------- x-projection: G[b,k,d,l] = sum_c src[b,c,l]*w[k,d,c], two k per pass ----------------
__global__ void k_xproj(const float* __restrict__ src, float* __restrict__ G,
                        const float* __restrict__ xpw, int kA, int kB){
  size_t i = (size_t)blockIdx.x*256 + threadIdx.x;
  if (i >= (size_t)BT*LL) return;
  int b = (int)(i / LL), l = (int)(i % LL);
  const float* sp = src + (size_t)b*CC*LL + l;
  const float* wA = xpw + (size_t)kA*8*CC;
  const float* wB = xpw + (size_t)kB*8*CC;
  float aA[8], aB[8];
  #pragma unroll
  for (int d = 0; d < 8; ++d){ aA[d] = 0.f; aB[d] = 0.f; }
  for (int c = 0; c < CC; ++c){
    float xv = sp[(size_t)c*LL];
    #pragma unroll
    for (int d = 0; d < 8; ++d){
      aA[d] = fmaf(wA[d*CC + c], xv, aA[d]);
      aB[d] = fmaf(wB[d*CC + c], xv, aB[d]);
    }
  }
  float* gA = G + (((size_t)b*KD + kA)*8)*LL + l;
  float* gB = G + (((size_t)b*KD + kB)*8)*LL + l;
  #pragma unroll
  for (int d = 0; d < 8; ++d){ gA[(size_t)d*LL] = aA[d]; gB[(size_t)d*LL] = aB[d]; }
}

// ---------------- tile-parallel selective scan v3 ----------------
// wave owns a 512-elem stored tile (+256 warm-up); lane holds 4 consecutive elems
// (float4 loads); local serial scan + 6-step wave shuffle scan; fast transcendentals.
__device__ __forceinline__ void ld4(const float* p, float* o){
  float4 t = *(const float4*)p; o[0]=t.x; o[1]=t.y; o[2]=t.z; o[3]=t.w;
}

template<bool REV>
__global__ __launch_bounds__(256) void k_scan3(const float* __restrict__ G,
                       const float* __restrict__ v, const float* __restrict__ vT,
                       float* __restrict__ Y,
                       const float* __restrict__ dtw_, const float* __restrict__ dtb_,
                       const float* __restrict__ Alog_, const float* __restrict__ Ds_){
  const size_t SZ = (size_t)BT*CC*LL;
  int wid = threadIdx.x >> 6, lane = threadIdx.x & 63;
  int tile = blockIdx.x*4 + wid;                 // 0..31
  int sy = blockIdx.y;                           // 0..767
  int c = sy % CC; int t2 = sy / CC; int kk = t2 & 1; int b = t2 >> 1;
  int k = REV ? (2 + kk) : kk;
  const float* src = (kk ? vT : v) + ((size_t)b*CC + c)*LL;
  const float* g = G + (((size_t)b*KD + k)*8)*LL;
  float dtw[RR];
  #pragma unroll
  for (int r = 0; r < RR; ++r) dtw[r] = dtw_[((size_t)k*CC + c)*RR + r];
  float dtb = dtb_[k*CC + c];
  float A  = -__expf(Alog_[k*CC + c]);
  float Dv = Ds_[k*CC + c];
  float* yout = Y + (size_t)k*SZ + ((size_t)b*CC + c)*LL;

  int lstore0 = tile*512;
  float carry = 0.f;
  for (int p = 0; p < 3; ++p){
    int base = lstore0 - 256 + p*256;
    if (base < 0) continue;                      // tile 0: no warm-up
    int l = base + (lane<<2);
    int ga = REV ? (LL-4-l) : l;
    float r0[4], r1[4], r2[4], r3[4], r4[4], r5[4], g6b[4], g7b[4], xb[4];
    ld4(g + 0*(size_t)LL + ga, r0);
    ld4(g + 1*(size_t)LL + ga, r1);
    ld4(g + 2*(size_t)LL + ga, r2);
    ld4(g + 3*(size_t)LL + ga, r3);
    ld4(g + 4*(size_t)LL + ga, r4);
    ld4(g + 5*(size_t)LL + ga, r5);
    ld4(g + 6*(size_t)LL + ga, g6b);
    ld4(g + 7*(size_t)LL + ga, g7b);
    ld4(src + ga, xb);
    float av[4], bt[4], g7v[4], xv[4];
    #pragma unroll
    for (int i = 0; i < 4; ++i){
      int j = REV ? (3-i) : i;
      float dsum = dtb;
      dsum = fmaf(r0[j], dtw[0], dsum);
      dsum = fmaf(r1[j], dtw[1], dsum);
      dsum = fmaf(r2[j], dtw[2], dsum);
      dsum = fmaf(r3[j], dtw[3], dsum);
      dsum = fmaf(r4[j], dtw[4], dsum);
      dsum = fmaf(r5[j], dtw[5], dsum);
      float sp = __logf(1.f + __expf(dsum));
      float delta = (dsum > 20.f) ? dsum : sp;
      av[i] = __expf(delta * A);
      xv[i] = xb[j];
      g7v[i] = g7b[j];
      bt[i] = delta * g6b[j] * xv[i];
    }
    // local (P,Q) over 4 elems
    float P = av[0], Q = bt[0];
    #pragma unroll
    for (int i = 1; i < 4; ++i){ Q = fmaf(av[i], Q, bt[i]); P *= av[i]; }
    // inclusive wave scan
    #pragma unroll
    for (int off = 1; off < 64; off <<= 1){
      float Pp = __shfl_up(P, (unsigned)off);
      float Qp = __shfl_up(Q, (unsigned)off);
      if (lane >= off){ Q = fmaf(P, Qp, Q); P *= Pp; }
    }
    float Pe = __shfl_up(P, 1u), Qe = __shfl_up(Q, 1u);
    if (lane == 0){ Pe = 1.f; Qe = 0.f; }
    float h = fmaf(Pe, carry, Qe);
    float ys[4];
    #pragma unroll
    for (int i = 0; i < 4; ++i){
      h = fmaf(av[i], h, bt[i]);
      ys[i] = fmaf(g7v[i], h, Dv*xv[i]);
    }
    carry = __shfl(h, 63);
    if (p > 0){
      float4 o;
      if (REV) o = make_float4(ys[3], ys[2], ys[1], ys[0]);
      else     o = make_float4(ys[0], ys[1], ys[2], ys[3]);
      *(float4*)&yout[ga] = o;
    }
  }
}

// ---------------- combine: z = (y0+y2) + transpose(y1+y3) ----------------
__global__ void k_combine4(const float* __restrict__ Y, float* __restrict__ z){
  const size_t SZ = (size_t)BT*CC*LL;
  __shared__ float tile[32][33];
  int bc = blockIdx.z;
  const float* y1p = Y + SZ   + (size_t)bc*LL;   // col-major [w*HH+h]
  const float* y3p = Y + 3*SZ + (size_t)bc*LL;
  int w0 = blockIdx.x*32, h0 = blockIdx.y*32;
  int tx = threadIdx.x, ty = threadIdx.y;
  #pragma unroll
  for (int kk = 0; kk < 4; ++kk){
    int w = w0 + ty + kk*8;
    size_t idx = (size_t)w*HH + h0 + tx;
    tile[ty + kk*8][tx] = y1p[idx] + y3p[idx];
  }
  __syncthreads();
  const float* y0p = Y +        (size_t)bc*LL;
  const float* y2p = Y + 2*SZ + (size_t)bc*LL;
  float* zp = z + (size_t)bc*LL;
  #pragma unroll
  for (int kk = 0; kk < 4; ++kk){
    int h = h0 + ty + kk*8;
    size_t idx = (size_t)h*WW + w0 + tx;
    zp[idx] = y0p[idx] + y2p[idx] + tile[tx][ty + kk*8];
  }
}

// ---------------- final output split/average ----------------
__global__ void k_output(const float* __restrict__ X, float* __restrict__ out){
  size_t i = (size_t)blockIdx.x*256 + threadIdx.x;
  size_t half = (size_t)2*CC*HH*128;
  if (i >= half) return;
  int w = i % 128; size_t r = i / 128;
  int h = r % HH; size_t bc = r / HH;
  size_t fwd = (bc*HH + h)*WW;
  size_t bwd = ((bc + (size_t)2*CC)*HH + h)*WW;
  out[i]        = 0.5f*(X[fwd + w]       + X[bwd + (WW-1-w)]);
  out[half + i] = 0.5f*(X[fwd + 128 + w] + X[bwd + (127 - w)]);
}

extern "C" void kernel_launch(void* const* d_in, const int* in_sizes, int n_in,
                              void* d_out, int out_size, void* d_ws, size_t ws_size,
                              hipStream_t stream){
  const float* x0        = (const float*)d_in[0];
  const float* x1        = (const float*)d_in[1];
  const float* norm_w    = (const float*)d_in[2];
  const float* norm_b    = (const float*)d_in[3];
  const float* in_proj_w = (const float*)d_in[4];
  const float* conv_w    = (const float*)d_in[5];
  const float* x_proj_w  = (const float*)d_in[6];
  const float* dt_w      = (const float*)d_in[7];
  const float* dt_b      = (const float*)d_in[8];
  const float* A_logs    = (const float*)d_in[9];
  const float* Ds        = (const float*)d_in[10];
  const float* out_norm_w= (const float*)d_in[11];
  const float* out_norm_b= (const float*)d_in[12];
  const float* out_proj_w= (const float*)d_in[13];
  const float* norm2_w   = (const float*)d_in[14];
  const float* norm2_b   = (const float*)d_in[15];
  const float* fc1_w     = (const float*)d_in[16];
  const float* fc1_b     = (const float*)d_in[17];
  const float* fc2_w     = (const float*)d_in[18];
  const float* fc2_b     = (const float*)d_in[19];

  const size_t SZ = (size_t)BT*CC*LL;            // 6,291,456 floats
  float* X  = (float*)d_ws;
  float* t  = X + SZ;
  float* u  = t + SZ;
  float* G  = u + SZ;                            // BT*KD*8*LL floats
  float* v  = G + (size_t)BT*KD*8*LL;
  float* Y  = v + 2*SZ;                          // 4 contiguous SZ buffers
  float* vT = v + SZ;
  float* hm = v;                                 // MLP hidden overlays v,vT,Y0,Y1

  k_build<<<(2*CC*HH*WW + 255)/256, 256, 0, stream>>>(x0, x1, X);

  for (int lay = 0; lay < NLAY; ++lay){
    const float* nw  = norm_w    + lay*CC;
    const float* nb  = norm_b    + lay*CC;
    const float* ipw = in_proj_w + (size_t)lay*CC*CC;
    const float* cw  = conv_w    + (size_t)lay*CC*9;
    const float* xpw = x_proj_w  + (size_t)lay*KD*8*CC;
    const float* dw  = dt_w      + (size_t)lay*KD*CC*RR;
    const float* db  = dt_b      + (size_t)lay*KD*CC;
    const float* Al  = A_logs    + (size_t)lay*KD*CC;
    const float* Dp  = Ds        + (size_t)lay*KD*CC;
    const float* onw = out_norm_w+ lay*CC;
    const float* onb = out_norm_b+ lay*CC;
    const float* opw = out_proj_w+ (size_t)lay*CC*CC;
    const float* n2w = norm2_w   + lay*CC;
    const float* n2b = norm2_b   + lay*CC;
    const float* f1w = fc1_w     + (size_t)lay*C4*CC;
    const float* f1b = fc1_b     + (size_t)lay*C4;
    const float* f2w = fc2_w     + (size_t)lay*CC*C4;
    const float* f2b = fc2_b     + (size_t)lay*CC;

    // ss2d: LN1 (fused) -> in_proj
    k_stats<<<BT*LL/256, 256, 0, stream>>>(X, t);
    k_gemm<96,true,false,false,false><<<dim3(64,3,BT), 256, 0, stream>>>(
        ipw, X, u, nullptr, nullptr, nw, nb, t, 96);
    k_dwconv_silu<<<(unsigned)((SZ + 255)/256), 256, 0, stream>>>(u, v, cw);
    k_transpose<<<dim3(8,2,BT*CC), dim3(32,8), 0, stream>>>(v, vT);
    k_xproj<<<BT*LL/256, 256, 0, stream>>>(v,  G, xpw, 0, 2);
    k_xproj<<<BT*LL/256, 256, 0, stream>>>(vT, G, xpw, 1, 3);
    k_scan3<false><<<dim3(8,768), 256, 0, stream>>>(G, v, vT, Y, dw, db, Al, Dp);
    k_scan3<true ><<<dim3(8,768), 256, 0, stream>>>(G, v, vT, Y, dw, db, Al, Dp);
    k_combine4<<<dim3(8,2,BT*CC), dim3(32,8), 0, stream>>>(Y, t);
    // out_norm (fused) -> out_proj (+residual X)
    k_stats<<<BT*LL/256, 256, 0, stream>>>(t, u);
    k_gemm<96,true,false,false,true><<<dim3(64,3,BT), 256, 0, stream>>>(
        opw, t, X, nullptr, X, onw, onb, u, 96);
    // MLP: norm2 (fused) -> fc1+gelu -> fc2 (+residual X)
    k_stats<<<BT*LL/256, 256, 0, stream>>>(X, t);
    k_gemm<96,true,true,true,false><<<dim3(64,12,BT), 256, 0, stream>>>(
        f1w, X, hm, f1b, nullptr, n2w, n2b, t, C4);
    k_gemm<384,false,true,false,true><<<dim3(64,3,BT), 256, 0, stream>>>(
        f2w, hm, X, f2b, X, nullptr, nullptr, nullptr, 96);
  }

  k_output<<<(unsigned)(((size_t)2*CC*HH*128 + 255)/256), 256, 0, stream>>>(X, (float*)d_out);
}

// Round 4
// 655.253 us; speedup vs baseline: 7.4711x; 1.2101x over previous
//
#include <hip/hip_runtime.h>
#include <cstdint>
#include <cstddef>

#define BT 4
#define CC 96
#define HH 64
#define WW 256
#define LL (HH*WW)    // 16384
#define KD 4
#define RR 6
#define NLAY 2
#define C4 (4*CC)     // 384

typedef unsigned short u16;
typedef __attribute__((ext_vector_type(8))) short bf16x8;
typedef __attribute__((ext_vector_type(4))) float f32x4;

__device__ __forceinline__ u16 f2bf(float f){
  unsigned u = __float_as_uint(f);
  unsigned r = (u + 0x7FFFu + ((u >> 16) & 1u)) >> 16;
  return (u16)r;
}
__device__ __forceinline__ float bf2f(u16 h){
  return __uint_as_float(((unsigned)h) << 16);
}

// ---------------- build batched input: X[0:2]=concat(x0,x1), X[2:4]=reverse ----------------
__global__ void k_build(const float* __restrict__ x0, const float* __restrict__ x1,
                        float* __restrict__ X){
  size_t i = (size_t)blockIdx.x*256 + threadIdx.x;
  size_t tot = (size_t)2*CC*HH*WW;
  if (i >= tot) return;
  int w = i % WW; size_t r = i / WW;
  int h = r % HH; size_t bc = r / HH;
  float val;
  if (w < 128) val = x0[(bc*HH + h)*128 + w];
  else         val = x1[(bc*HH + h)*128 + (w-128)];
  X[i] = val;
  size_t ib = ((bc + (size_t)2*CC)*HH + h)*WW + (WW-1-w);
  X[ib] = val;
}

// ---------------- pack f32 [b][c][l] -> bf16T [b*LL+l][104] (+ LN stats) ----------------
template<bool ST>
__global__ __launch_bounds__(256) void k_pack(const float* __restrict__ src,
      u16* __restrict__ dst, float* __restrict__ st){
  __shared__ float tl[CC][33];
  int tid = threadIdx.x;
  int l0 = blockIdx.x*32, b = blockIdx.y;
  for (int e = tid; e < CC*32; e += 256){
    int c = e >> 5, dl = e & 31;
    tl[c][dl] = src[((size_t)b*CC + c)*LL + l0 + dl];
  }
  __syncthreads();
  if (ST && tid < 32){
    float s = 0.f, ss = 0.f;
    for (int c = 0; c < CC; ++c){ float vv = tl[c][tid]; s += vv; ss += vv*vv; }
    float mu = s*(1.f/CC);
    float var = ss*(1.f/CC) - mu*mu;
    st[(size_t)b*LL + l0 + tid] = mu;
    st[(size_t)BT*LL + (size_t)b*LL + l0 + tid] = rsqrtf(var + 1e-5f);
  }
  int dl = tid >> 3, cg = tid & 7;
  u16* dp = dst + ((size_t)b*LL + l0 + dl)*104 + cg*12;
  #pragma unroll
  for (int q = 0; q < 3; ++q){
    ushort4 pk;
    pk.x = f2bf(tl[cg*12 + q*4 + 0][dl]);
    pk.y = f2bf(tl[cg*12 + q*4 + 1][dl]);
    pk.z = f2bf(tl[cg*12 + q*4 + 2][dl]);
    pk.w = f2bf(tl[cg*12 + q*4 + 3][dl]);
    *(ushort4*)(dp + q*4) = pk;
  }
}

// ---------------- weight prep: Wb = bf16(W .* lnw), s1 = sum bf16-W', cadd = W*lnb + bias ----------------
template<int M, int K, bool LNF, bool BIAS>
__global__ void k_prepw(const float* __restrict__ W, const float* __restrict__ lnw,
      const float* __restrict__ lnb, const float* __restrict__ bias,
      u16* __restrict__ Wb, float* __restrict__ s1, float* __restrict__ cadd){
  int m = blockIdx.x*64 + threadIdx.x;
  if (m >= M) return;
  float s1v = 0.f, sbv = 0.f;
  for (int c = 0; c < K; ++c){
    float wv = W[(size_t)m*K + c];
    float wf = LNF ? wv*lnw[c] : wv;
    u16 h = f2bf(wf);
    Wb[(size_t)m*K + c] = h;
    s1v += bf2f(h);
    if (LNF) sbv = fmaf(wv, lnb[c], sbv);
  }
  if (BIAS) sbv += bias[m];
  s1[m] = s1v;
  cadd[m] = sbv;
}

// ---------------- MFMA GEMM: out[b,m,l] = epi(sum_c W'[m,c]*inT[l,c]) ----------------
// A = W' (M x K bf16 row-major), B = inT ([l][K+8] bf16). Wave: 96m x 16l x 4 subtiles.
template<int M, int K, int CPADO, bool LNF, bool GELU_, bool RES, bool WF32, bool WBF, bool STATS>
__global__ __launch_bounds__(256) void k_gmm(
    const u16* __restrict__ Wb, const u16* __restrict__ inT,
    float* __restrict__ outF, u16* __restrict__ outT,
    const float* __restrict__ s1v, const float* __restrict__ cadd,
    const float* __restrict__ res,
    const float* __restrict__ stI, float* __restrict__ stO){
  constexpr int CPADI = K + 8;
  int tid = threadIdx.x, lane = tid & 63, wid = tid >> 6;
  int l0 = blockIdx.x*256, m0 = blockIdx.y*96;
  int lw = l0 + wid*64;
  int lr = lane & 15, lg = lane >> 4;
  f32x4 acc[6][4];
  #pragma unroll
  for (int mf = 0; mf < 6; ++mf)
    #pragma unroll
    for (int ls = 0; ls < 4; ++ls) acc[mf][ls] = (f32x4){0.f,0.f,0.f,0.f};

  const u16* wbase = Wb + (size_t)(m0 + lr)*K + lg*8;
  const u16* bbase = inT + (size_t)(lw + lr)*CPADI + lg*8;
  #pragma unroll
  for (int ks = 0; ks < K/32; ++ks){
    bf16x8 af[6];
    #pragma unroll
    for (int mf = 0; mf < 6; ++mf)
      af[mf] = *(const bf16x8*)(wbase + (size_t)mf*16*K + ks*32);
    bf16x8 bfr[4];
    #pragma unroll
    for (int ls = 0; ls < 4; ++ls)
      bfr[ls] = *(const bf16x8*)(bbase + (size_t)ls*16*CPADI + ks*32);
    #pragma unroll
    for (int mf = 0; mf < 6; ++mf)
      #pragma unroll
      for (int ls = 0; ls < 4; ++ls)
        acc[mf][ls] = __builtin_amdgcn_mfma_f32_16x16x32_bf16(af[mf], bfr[ls], acc[mf][ls], 0, 0, 0);
  }

  #pragma unroll
  for (int ls = 0; ls < 4; ++ls){
    int l = lw + ls*16 + lr;                   // global pixel
    int b = l >> 14, lb = l & (LL-1);
    float mu = 0.f, rs = 0.f;
    if (LNF){ mu = stI[l]; rs = stI[(size_t)BT*LL + l]; }
    float ssum = 0.f, ssq = 0.f;
    #pragma unroll
    for (int mf = 0; mf < 6; ++mf){
      float o[4];
      #pragma unroll
      for (int r = 0; r < 4; ++r){
        int mm = m0 + mf*16 + lg*4 + r;
        float vv = acc[mf][ls][r];
        if (LNF) vv = fmaf(rs, vv, fmaf(-mu*rs, s1v[mm], cadd[mm]));
        else     vv += cadd[mm];
        if (GELU_){
          float uu = 0.7978845608f*(vv + 0.044715f*vv*vv*vv);
          float e2 = __expf(2.f*uu);
          float th = (e2 - 1.f)/(e2 + 1.f);
          vv = 0.5f*vv*(1.f + th);
        }
        if (RES) vv += res[((size_t)b*M + mm)*LL + lb];
        if (WF32) outF[((size_t)b*M + mm)*LL + lb] = vv;
        if (STATS){ ssum += vv; ssq += vv*vv; }
        o[r] = vv;
      }
      if (WBF){
        ushort4 pk;
        pk.x = f2bf(o[0]); pk.y = f2bf(o[1]); pk.z = f2bf(o[2]); pk.w = f2bf(o[3]);
        *(ushort4*)(outT + (size_t)l*CPADO + m0 + mf*16 + lg*4) = pk;
      }
    }
    if (STATS){
      ssum += __shfl_xor(ssum, 16); ssq += __shfl_xor(ssq, 16);
      ssum += __shfl_xor(ssum, 32); ssq += __shfl_xor(ssq, 32);
      if (lane < 16){
        float mu2 = ssum*(1.f/CC);
        float var = ssq*(1.f/CC) - mu2*mu2;
        stO[l] = mu2;
        stO[(size_t)BT*LL + l] = rsqrtf(var + 1e-5f);
      }
    }
  }
}

// ---------------- depthwise 3x3 (SAME) + SiLU ----------------
__global__ void k_dwconv_silu(const float* __restrict__ u, float* __restrict__ v,
                              const float* __restrict__ cw){
  size_t i = (size_t)blockIdx.x*256 + threadIdx.x;
  if (i >= (size_t)BT*CC*LL) return;
  int w = i % WW; size_t t1 = i / WW;
  int h = t1 % HH; size_t bc = t1 / HH;
  int c = (int)(bc % CC);
  const float* up = u + bc*LL;
  const float* k9 = cw + c*9;
  float acc = 0.f;
  #pragma unroll
  for (int dh = -1; dh <= 1; ++dh){
    int h2 = h + dh; if (h2 < 0 || h2 >= HH) continue;
    #pragma unroll
    for (int dw = -1; dw <= 1; ++dw){
      int w2 = w + dw; if (w2 < 0 || w2 >= WW) continue;
      acc = fmaf(up[h2*WW + w2], k9[(dh+1)*3 + (dw+1)], acc);
    }
  }
  v[i] = acc / (1.f + __expf(-acc));
}

// ---------------- transpose (h,w)->(w,h) per (b,c) ----------------
__global__ void k_transpose(const float* __restrict__ src, float* __restrict__ dst){
  __shared__ float tile[32][33];
  int bc = blockIdx.z;
  const float* sp = src + (size_t)bc*LL;
  float* dp = dst + (size_t)bc*LL;
  int w0 = blockIdx.x*32, h0 = blockIdx.y*32;
  int tx = threadIdx.x, ty = threadIdx.y;
  #pragma unroll
  for (int kk = 0; kk < 4; ++kk){
    int h = h0 + ty + kk*8;
    tile[ty + kk*8][tx] = sp[(size_t)h*WW + w0 + tx];
  }
  __syncthreads();
  #pragma unroll
  for (int kk = 0; kk < 4; ++kk){
    int w = w0 + ty + kk*8;
    dp[(size_t)w*HH + h0 + tx] = tile[tx][ty + kk*8];
  }
}

// ---------------- x-projection ----------------
__global__ void k_xproj(const float* __restrict__ src, float* __restrict__ G,
                        const float* __restrict__ xpw, int kA, int kB){
  size_t i = (size_t)blockIdx.x*256 + threadIdx.x;
  if (i >= (size_t)BT*LL) return;
  int b = (int)(i / LL), l = (int)(i % LL);
  const float* sp = src + (size_t)b*CC*LL + l;
  const float* wA = xpw + (size_t)kA*8*CC;
  const float* wB = xpw + (size_t)kB*8*CC;
  float aA[8], aB[8];
  #pragma unroll
  for (int d = 0; d < 8; ++d){ aA[d] = 0.f; aB[d] = 0.f; }
  for (int c = 0; c < CC; ++c){
    float xv = sp[(size_t)c*LL];
    #pragma unroll
    for (int d = 0; d < 8; ++d){
      aA[d] = fmaf(wA[d*CC + c], xv, aA[d]);
      aB[d] = fmaf(wB[d*CC + c], xv, aB[d]);
    }
  }
  float* gA = G + (((size_t)b*KD + kA)*8)*LL + l;
  float* gB = G + (((size_t)b*KD + kB)*8)*LL + l;
  #pragma unroll
  for (int d = 0; d < 8; ++d){ gA[(size_t)d*LL] = aA[d]; gB[(size_t)d*LL] = aB[d]; }
}

// ---------------- tile-parallel selective scan v3 ----------------
__device__ __forceinline__ void ld4(const float* p, float* o){
  float4 t = *(const float4*)p; o[0]=t.x; o[1]=t.y; o[2]=t.z; o[3]=t.w;
}

template<bool REV>
__global__ __launch_bounds__(256) void k_scan3(const float* __restrict__ G,
                       const float* __restrict__ v, const float* __restrict__ vT,
                       float* __restrict__ Y,
                       const float* __restrict__ dtw_, const float* __restrict__ dtb_,
                       const float* __restrict__ Alog_, const float* __restrict__ Ds_){
  const size_t SZ = (size_t)BT*CC*LL;
  int wid = threadIdx.x >> 6, lane = threadIdx.x & 63;
  int tile = blockIdx.x*4 + wid;
  int sy = blockIdx.y;
  int c = sy % CC; int t2 = sy / CC; int kk = t2 & 1; int b = t2 >> 1;
  int k = REV ? (2 + kk) : kk;
  const float* src = (kk ? vT : v) + ((size_t)b*CC + c)*LL;
  const float* g = G + (((size_t)b*KD + k)*8)*LL;
  float dtw[RR];
  #pragma unroll
  for (int r = 0; r < RR; ++r) dtw[r] = dtw_[((size_t)k*CC + c)*RR + r];
  float dtb = dtb_[k*CC + c];
  float A  = -__expf(Alog_[k*CC + c]);
  float Dv = Ds_[k*CC + c];
  float* yout = Y + (size_t)k*SZ + ((size_t)b*CC + c)*LL;

  int lstore0 = tile*512;
  float carry = 0.f;
  for (int p = 0; p < 3; ++p){
    int base = lstore0 - 256 + p*256;
    if (base < 0) continue;
    int l = base + (lane<<2);
    int ga = REV ? (LL-4-l) : l;
    float r0[4], r1[4], r2[4], r3[4], r4[4], r5[4], g6b[4], g7b[4], xb[4];
    ld4(g + 0*(size_t)LL + ga, r0);
    ld4(g + 1*(size_t)LL + ga, r1);
    ld4(g + 2*(size_t)LL + ga, r2);
    ld4(g + 3*(size_t)LL + ga, r3);
    ld4(g + 4*(size_t)LL + ga, r4);
    ld4(g + 5*(size_t)LL + ga, r5);
    ld4(g + 6*(size_t)LL + ga, g6b);
    ld4(g + 7*(size_t)LL + ga, g7b);
    ld4(src + ga, xb);
    float av[4], bt[4], g7v[4], xv[4];
    #pragma unroll
    for (int i = 0; i < 4; ++i){
      int j = REV ? (3-i) : i;
      float dsum = dtb;
      dsum = fmaf(r0[j], dtw[0], dsum);
      dsum = fmaf(r1[j], dtw[1], dsum);
      dsum = fmaf(r2[j], dtw[2], dsum);
      dsum = fmaf(r3[j], dtw[3], dsum);
      dsum = fmaf(r4[j], dtw[4], dsum);
      dsum = fmaf(r5[j], dtw[5], dsum);
      float sp = __logf(1.f + __expf(dsum));
      float delta = (dsum > 20.f) ? dsum : sp;
      av[i] = __expf(delta * A);
      xv[i] = xb[j];
      g7v[i] = g7b[j];
      bt[i] = delta * g6b[j] * xv[i];
    }
    float P = av[0], Q = bt[0];
    #pragma unroll
    for (int i = 1; i < 4; ++i){ Q = fmaf(av[i], Q, bt[i]); P *= av[i]; }
    #pragma unroll
    for (int off = 1; off < 64; off <<= 1){
      float Pp = __shfl_up(P, (unsigned)off);
      float Qp = __shfl_up(Q, (unsigned)off);
      if (lane >= off){ Q = fmaf(P, Qp, Q); P *= Pp; }
    }
    float Pe = __shfl_up(P, 1u), Qe = __shfl_up(Q, 1u);
    if (lane == 0){ Pe = 1.f; Qe = 0.f; }
    float h = fmaf(Pe, carry, Qe);
    float ys[4];
    #pragma unroll
    for (int i = 0; i < 4; ++i){
      h = fmaf(av[i], h, bt[i]);
      ys[i] = fmaf(g7v[i], h, Dv*xv[i]);
    }
    carry = __shfl(h, 63);
    if (p > 0){
      float4 o;
      if (REV) o = make_float4(ys[3], ys[2], ys[1], ys[0]);
      else     o = make_float4(ys[0], ys[1], ys[2], ys[3]);
      *(float4*)&yout[ga] = o;
    }
  }
}

// ---------------- combine: z = (y0+y2) + transpose(y1+y3) ----------------
__global__ void k_combine4(const float* __restrict__ Y, float* __restrict__ z){
  const size_t SZ = (size_t)BT*CC*LL;
  __shared__ float tile[32][33];
  int bc = blockIdx.z;
  const float* y1p = Y + SZ   + (size_t)bc*LL;
  const float* y3p = Y + 3*SZ + (size_t)bc*LL;
  int w0 = blockIdx.x*32, h0 = blockIdx.y*32;
  int tx = threadIdx.x, ty = threadIdx.y;
  #pragma unroll
  for (int kk = 0; kk < 4; ++kk){
    int w = w0 + ty + kk*8;
    size_t idx = (size_t)w*HH + h0 + tx;
    tile[ty + kk*8][tx] = y1p[idx] + y3p[idx];
  }
  __syncthreads();
  const float* y0p = Y +        (size_t)bc*LL;
  const float* y2p = Y + 2*SZ + (size_t)bc*LL;
  float* zp = z + (size_t)bc*LL;
  #pragma unroll
  for (int kk = 0; kk < 4; ++kk){
    int h = h0 + ty + kk*8;
    size_t idx = (size_t)h*WW + w0 + tx;
    zp[idx] = y0p[idx] + y2p[idx] + tile[tx][ty + kk*8];
  }
}

// ---------------- final output split/average ----------------
__global__ void k_output(const float* __restrict__ X, float* __restrict__ out){
  size_t i = (size_t)blockIdx.x*256 + threadIdx.x;
  size_t half = (size_t)2*CC*HH*128;
  if (i >= half) return;
  int w = i % 128; size_t r = i / 128;
  int h = r % HH; size_t bc = r / HH;
  size_t fwd = (bc*HH + h)*WW;
  size_t bwd = ((bc + (size_t)2*CC)*HH + h)*WW;
  out[i]        = 0.5f*(X[fwd + w]       + X[bwd + (WW-1-w)]);
  out[half + i] = 0.5f*(X[fwd + 128 + w] + X[bwd + (127 - w)]);
}

extern "C" void kernel_launch(void* const* d_in, const int* in_sizes, int n_in,
                              void* d_out, int out_size, void* d_ws, size_t ws_size,
                              hipStream_t stream){
  const float* x0        = (const float*)d_in[0];
  const float* x1        = (const float*)d_in[1];
  const float* norm_w    = (const float*)d_in[2];
  const float* norm_b    = (const float*)d_in[3];
  const float* in_proj_w = (const float*)d_in[4];
  const float* conv_w    = (const float*)d_in[5];
  const float* x_proj_w  = (const float*)d_in[6];
  const float* dt_w      = (const float*)d_in[7];
  const float* dt_b      = (const float*)d_in[8];
  const float* A_logs    = (const float*)d_in[9];
  const float* Ds        = (const float*)d_in[10];
  const float* out_norm_w= (const float*)d_in[11];
  const float* out_norm_b= (const float*)d_in[12];
  const float* out_proj_w= (const float*)d_in[13];
  const float* norm2_w   = (const float*)d_in[14];
  const float* norm2_b   = (const float*)d_in[15];
  const float* fc1_w     = (const float*)d_in[16];
  const float* fc1_b     = (const float*)d_in[17];
  const float* fc2_w     = (const float*)d_in[18];
  const float* fc2_b     = (const float*)d_in[19];

  const size_t SZ = (size_t)BT*CC*LL;            // 6,291,456 floats
  float* X  = (float*)d_ws;
  float* t  = X + SZ;
  float* u  = t + SZ;
  float* G  = u + SZ;                            // BT*KD*8*LL floats
  float* v  = G + (size_t)BT*KD*8*LL;
  float* vT = v + SZ;
  float* Y  = vT + SZ;                           // 4*SZ region (scan outputs)
  u16*   XT  = (u16*)Y;                          // bf16T [BT*LL][104] (phase-disjoint w/ Y0)
  u16*   hmT = (u16*)(Y + SZ);                   // bf16T [BT*LL][392] (overlays Y1..Y3)
  u16*   tT  = (u16*)u;                          // bf16T of t (u dead by then)
  float* ext = Y + 4*SZ;
  float* stats_X = ext;                          // 2*BT*LL
  float* stats_t = stats_X + 2*(size_t)BT*LL;
  float* wp      = stats_t + 2*(size_t)BT*LL;

  // per-layer weight slots
  u16* WbI[NLAY]; float* s1I[NLAY]; float* cI[NLAY];
  u16* WbO[NLAY]; float* s1O[NLAY]; float* cO[NLAY];
  u16* Wb1[NLAY]; float* s11[NLAY]; float* c1[NLAY];
  u16* Wb2[NLAY]; float* s12[NLAY]; float* c2[NLAY];
  for (int l = 0; l < NLAY; ++l){
    WbI[l]=(u16*)wp; wp+=4608;  s1I[l]=wp; wp+=96;  cI[l]=wp; wp+=96;
    WbO[l]=(u16*)wp; wp+=4608;  s1O[l]=wp; wp+=96;  cO[l]=wp; wp+=96;
    Wb1[l]=(u16*)wp; wp+=18432; s11[l]=wp; wp+=384; c1[l]=wp; wp+=384;
    Wb2[l]=(u16*)wp; wp+=18432; s12[l]=wp; wp+=96;  c2[l]=wp; wp+=96;
  }

  // weight prep (tiny)
  for (int l = 0; l < NLAY; ++l){
    k_prepw<96,96,true,false><<<2,64,0,stream>>>(in_proj_w + (size_t)l*CC*CC,
        norm_w + l*CC, norm_b + l*CC, nullptr, WbI[l], s1I[l], cI[l]);
    k_prepw<96,96,true,false><<<2,64,0,stream>>>(out_proj_w + (size_t)l*CC*CC,
        out_norm_w + l*CC, out_norm_b + l*CC, nullptr, WbO[l], s1O[l], cO[l]);
    k_prepw<384,96,true,true><<<6,64,0,stream>>>(fc1_w + (size_t)l*C4*CC,
        norm2_w + l*CC, norm2_b + l*CC, fc1_b + (size_t)l*C4, Wb1[l], s11[l], c1[l]);
    k_prepw<96,384,false,true><<<2,64,0,stream>>>(fc2_w + (size_t)l*CC*C4,
        nullptr, nullptr, fc2_b + (size_t)l*CC, Wb2[l], s12[l], c2[l]);
  }

  k_build<<<(2*CC*HH*WW + 255)/256, 256, 0, stream>>>(x0, x1, X);
  k_pack<true><<<dim3(LL/32, BT), 256, 0, stream>>>(X, XT, stats_X);

  for (int lay = 0; lay < NLAY; ++lay){
    const float* cw  = conv_w    + (size_t)lay*CC*9;
    const float* xpw = x_proj_w  + (size_t)lay*KD*8*CC;
    const float* dw  = dt_w      + (size_t)lay*KD*CC*RR;
    const float* db  = dt_b      + (size_t)lay*KD*CC;
    const float* Al  = A_logs    + (size_t)lay*KD*CC;
    const float* Dp  = Ds        + (size_t)lay*KD*CC;

    // in_proj (LN fused): u = W' * X
    k_gmm<96,96,104,true,false,false,true,false,false><<<dim3(256,1),256,0,stream>>>(
        WbI[lay], XT, u, nullptr, s1I[lay], cI[lay], nullptr, stats_X, nullptr);
    k_dwconv_silu<<<(unsigned)((SZ + 255)/256), 256, 0, stream>>>(u, v, cw);
    k_transpose<<<dim3(8,2,BT*CC), dim3(32,8), 0, stream>>>(v, vT);
    k_xproj<<<BT*LL/256, 256, 0, stream>>>(v,  G, xpw, 0, 2);
    k_xproj<<<BT*LL/256, 256, 0, stream>>>(vT, G, xpw, 1, 3);
    k_scan3<false><<<dim3(8,768), 256, 0, stream>>>(G, v, vT, Y, dw, db, Al, Dp);
    k_scan3<true ><<<dim3(8,768), 256, 0, stream>>>(G, v, vT, Y, dw, db, Al, Dp);
    k_combine4<<<dim3(8,2,BT*CC), dim3(32,8), 0, stream>>>(Y, t);
    k_pack<true><<<dim3(LL/32, BT), 256, 0, stream>>>(t, tT, stats_t);
    // out_proj (LN fused) + residual -> X (f32 + bf16T + stats)
    k_gmm<96,96,104,true,false,true,true,true,true><<<dim3(256,1),256,0,stream>>>(
        WbO[lay], tT, X, XT, s1O[lay], cO[lay], X, stats_t, stats_X);
    // fc1 (LN fused, GELU) -> hmT (bf16 only)
    k_gmm<384,96,392,true,true,false,false,true,false><<<dim3(256,4),256,0,stream>>>(
        Wb1[lay], XT, nullptr, hmT, s11[lay], c1[lay], nullptr, stats_X, nullptr);
    // fc2 + residual -> X (f32 + bf16T + stats for next layer)
    k_gmm<96,384,104,false,false,true,true,true,true><<<dim3(256,1),256,0,stream>>>(
        Wb2[lay], hmT, X, XT, nullptr, c2[lay], X, nullptr, stats_X);
  }

  k_output<<<(unsigned)(((size_t)2*CC*HH*128 + 255)/256), 256, 0, stream>>>(X, (float*)d_out);
}

// Round 5
// 523.543 us; speedup vs baseline: 9.3507x; 1.2516x over previous
//
#include <hip/hip_runtime.h>
#include <cstdint>
#include <cstddef>

#define BT 4
#define CC 96
#define HH 64
#define WW 256
#define LL (HH*WW)    // 16384
#define KD 4
#define RR 6
#define NLAY 2
#define C4 (4*CC)     // 384
#define SLOTF 47424   // per-layer weight-slot stride in float units

typedef unsigned short u16;
typedef __attribute__((ext_vector_type(8))) short bf16x8;
typedef __attribute__((ext_vector_type(4))) float f32x4;

__device__ __forceinline__ u16 f2bf(float f){
  unsigned u = __float_as_uint(f);
  unsigned r = (u + 0x7FFFu + ((u >> 16) & 1u)) >> 16;
  return (u16)r;
}
__device__ __forceinline__ float bf2f(u16 h){
  return __uint_as_float(((unsigned)h) << 16);
}
__device__ __forceinline__ unsigned pk_bf16(float lo, float hi){
  unsigned r;
  asm volatile("v_cvt_pk_bf16_f32 %0, %1, %2" : "=v"(r) : "v"(lo), "v"(hi));
  return r;
}
__device__ __forceinline__ float gelu_f(float vv){
  float uu = 0.7978845608f*(vv + 0.044715f*vv*vv*vv);
  float e2 = __expf(2.f*uu);
  return 0.5f*vv*(1.f + (e2 - 1.f)/(e2 + 1.f));
}

// ---------------- build batched input ----------------
__global__ void k_build(const float* __restrict__ x0, const float* __restrict__ x1,
                        float* __restrict__ X){
  size_t i = (size_t)blockIdx.x*256 + threadIdx.x;
  size_t tot = (size_t)2*CC*HH*WW;
  if (i >= tot) return;
  int w = i % WW; size_t r = i / WW;
  int h = r % HH; size_t bc = r / HH;
  float val;
  if (w < 128) val = x0[(bc*HH + h)*128 + w];
  else         val = x1[(bc*HH + h)*128 + (w-128)];
  X[i] = val;
  size_t ib = ((bc + (size_t)2*CC)*HH + h)*WW + (WW-1-w);
  X[ib] = val;
}

// ---------------- pack f32 [b][c][l] -> bf16T [b*LL+l][104] (+ LN stats) ----------------
template<bool ST>
__global__ __launch_bounds__(256) void k_pack(const float* __restrict__ src,
      u16* __restrict__ dst, float* __restrict__ st){
  __shared__ float tl[CC][33];
  int tid = threadIdx.x;
  int l0 = blockIdx.x*32, b = blockIdx.y;
  for (int e = tid; e < CC*32; e += 256){
    int c = e >> 5, dl = e & 31;
    tl[c][dl] = src[((size_t)b*CC + c)*LL + l0 + dl];
  }
  __syncthreads();
  if (ST && tid < 32){
    float s = 0.f, ss = 0.f;
    for (int c = 0; c < CC; ++c){ float vv = tl[c][tid]; s += vv; ss += vv*vv; }
    float mu = s*(1.f/CC);
    float var = ss*(1.f/CC) - mu*mu;
    st[(size_t)b*LL + l0 + tid] = mu;
    st[(size_t)BT*LL + (size_t)b*LL + l0 + tid] = rsqrtf(var + 1e-5f);
  }
  int dl = tid >> 3, cg = tid & 7;
  u16* dp = dst + ((size_t)b*LL + l0 + dl)*104 + cg*12;
  #pragma unroll
  for (int q = 0; q < 3; ++q){
    ushort4 pk;
    pk.x = f2bf(tl[cg*12 + q*4 + 0][dl]);
    pk.y = f2bf(tl[cg*12 + q*4 + 1][dl]);
    pk.z = f2bf(tl[cg*12 + q*4 + 2][dl]);
    pk.w = f2bf(tl[cg*12 + q*4 + 3][dl]);
    *(ushort4*)(dp + q*4) = pk;
  }
}

// ---------------- weight prep (layered via blockIdx.y) ----------------
template<int M, int K, bool LNF, bool BIAS>
__global__ void k_prepw(const float* __restrict__ W, const float* __restrict__ lnw,
      const float* __restrict__ lnb, const float* __restrict__ bias,
      u16* __restrict__ Wb, float* __restrict__ s1, float* __restrict__ cadd){
  int lay = blockIdx.y;
  W += (size_t)lay*M*K;
  Wb += (size_t)lay*SLOTF*2;
  s1 += (size_t)lay*SLOTF;
  cadd += (size_t)lay*SLOTF;
  int m = blockIdx.x*64 + threadIdx.x;
  if (m >= M) return;
  float s1v = 0.f, sbv = 0.f;
  for (int c = 0; c < K; ++c){
    float wv = W[(size_t)m*K + c];
    float wf = LNF ? wv*lnw[lay*K + c] : wv;
    u16 h = f2bf(wf);
    Wb[(size_t)m*K + c] = h;
    s1v += bf2f(h);
    if (LNF) sbv = fmaf(wv, lnb[lay*K + c], sbv);
  }
  if (BIAS) sbv += bias[lay*M + m];
  s1[m] = s1v;
  cadd[m] = sbv;
}

// ---------------- MFMA GEMM (M=96,K=96) with LDS-staged A,B ----------------
template<bool LNF, bool RES, bool WF32, bool WBF, bool STATS>
__global__ __launch_bounds__(256) void k_gmm2(
    const u16* __restrict__ Wb, const u16* __restrict__ inT,
    float* __restrict__ outF, u16* __restrict__ outT,
    const float* __restrict__ s1v, const float* __restrict__ cadd,
    const float* __restrict__ res,
    const float* __restrict__ stI, float* __restrict__ stO){
  __shared__ u16 bt[128*104];
  __shared__ u16 wa[96*104];
  int tid = threadIdx.x, lane = tid & 63, wid = tid >> 6;
  int l0 = blockIdx.x*128;
  int lr = lane & 15, lg = lane >> 4;
  const int4* bsrc = (const int4*)(inT + (size_t)l0*104);
  for (int i = tid; i < 1664; i += 256) ((int4*)bt)[i] = bsrc[i];
  for (int i = tid; i < 96*12; i += 256){
    int r = i/12, s2 = i - r*12;
    *(int4*)&wa[r*104 + s2*8] = *(const int4*)(Wb + (size_t)r*96 + s2*8);
  }
  __syncthreads();
  f32x4 acc[6][2];
  #pragma unroll
  for (int mf = 0; mf < 6; ++mf){ acc[mf][0] = (f32x4){0,0,0,0}; acc[mf][1] = (f32x4){0,0,0,0}; }
  #pragma unroll
  for (int ks = 0; ks < 3; ++ks){
    bf16x8 af[6];
    #pragma unroll
    for (int mf = 0; mf < 6; ++mf)
      af[mf] = *(const bf16x8*)&wa[(mf*16 + lr)*104 + ks*32 + lg*8];
    bf16x8 bfr[2];
    #pragma unroll
    for (int ls = 0; ls < 2; ++ls)
      bfr[ls] = *(const bf16x8*)&bt[(wid*32 + ls*16 + lr)*104 + ks*32 + lg*8];
    #pragma unroll
    for (int mf = 0; mf < 6; ++mf)
      #pragma unroll
      for (int ls = 0; ls < 2; ++ls)
        acc[mf][ls] = __builtin_amdgcn_mfma_f32_16x16x32_bf16(af[mf], bfr[ls], acc[mf][ls], 0, 0, 0);
  }
  #pragma unroll
  for (int ls = 0; ls < 2; ++ls){
    int l = l0 + wid*32 + ls*16 + lr;
    int b = l >> 14, lb = l & (LL-1);
    float mu = 0.f, rs = 0.f;
    if (LNF){ mu = stI[l]; rs = stI[(size_t)BT*LL + l]; }
    float ssum = 0.f, ssq = 0.f;
    #pragma unroll
    for (int mf = 0; mf < 6; ++mf){
      float o[4];
      #pragma unroll
      for (int r = 0; r < 4; ++r){
        int mm = mf*16 + lg*4 + r;
        float vv = acc[mf][ls][r];
        if (LNF) vv = fmaf(rs, vv, fmaf(-mu*rs, s1v[mm], cadd[mm]));
        else     vv += cadd[mm];
        if (RES) vv += res[((size_t)b*96 + mm)*LL + lb];
        if (WF32) outF[((size_t)b*96 + mm)*LL + lb] = vv;
        if (STATS){ ssum += vv; ssq += vv*vv; }
        o[r] = vv;
      }
      if (WBF){
        ushort4 pk;
        pk.x = f2bf(o[0]); pk.y = f2bf(o[1]); pk.z = f2bf(o[2]); pk.w = f2bf(o[3]);
        *(ushort4*)(outT + (size_t)l*104 + mf*16 + lg*4) = pk;
      }
    }
    if (STATS){
      ssum += __shfl_xor(ssum, 16); ssq += __shfl_xor(ssq, 16);
      ssum += __shfl_xor(ssum, 32); ssq += __shfl_xor(ssq, 32);
      if (lane < 16){
        float mu2 = ssum*(1.f/CC);
        float var = ssq*(1.f/CC) - mu2*mu2;
        stO[l] = mu2;
        stO[(size_t)BT*LL + l] = rsqrtf(var + 1e-5f);
      }
    }
  }
}

// ---------------- fused MLP: fc1(LN)+GELU+fc2+bias+residual -> X, XT, stats ----------------
__global__ __launch_bounds__(256) void k_mlp(
    const u16* __restrict__ Wb1, const u16* __restrict__ Wb2,
    const u16* __restrict__ XT, float* __restrict__ X, u16* __restrict__ XTout,
    const float* __restrict__ s11, const float* __restrict__ c1,
    const float* __restrict__ c2,
    const float* __restrict__ stI, float* __restrict__ stO){
  __shared__ u16 bt[128*104];
  __shared__ u16 wa1[96*104];
  __shared__ u16 wa2[96*104];
  int tid = threadIdx.x, lane = tid & 63, wid = tid >> 6;
  int l0 = blockIdx.x*128;
  int lr = lane & 15, lg = lane >> 4;
  const int4* bsrc = (const int4*)(XT + (size_t)l0*104);
  for (int i = tid; i < 1664; i += 256) ((int4*)bt)[i] = bsrc[i];

  float mu[2], rs[2], nmr[2];
  #pragma unroll
  for (int ls = 0; ls < 2; ++ls){
    int l = l0 + wid*32 + ls*16 + lr;
    mu[ls] = stI[l];
    rs[ls] = stI[(size_t)BT*LL + l];
    nmr[ls] = -mu[ls]*rs[ls];
  }
  int src0 = (lane & 15) + 32*((lane >> 4) & 1);
  int src1 = src0 + 16;
  bool lowsel = (lg < 2);

  f32x4 acc2[6][2];
  #pragma unroll
  for (int mf = 0; mf < 6; ++mf){ acc2[mf][0] = (f32x4){0,0,0,0}; acc2[mf][1] = (f32x4){0,0,0,0}; }

  for (int cc = 0; cc < 4; ++cc){
    __syncthreads();
    for (int i = tid; i < 96*12; i += 256){
      int r = i/12, s2 = i - r*12;
      *(int4*)&wa1[r*104 + s2*8] = *(const int4*)(Wb1 + ((size_t)(cc*96 + r))*96 + s2*8);
      *(int4*)&wa2[r*104 + s2*8] = *(const int4*)(Wb2 + (size_t)r*384 + cc*96 + s2*8);
    }
    __syncthreads();
    // fc1 chunk: acc1[6][2] over K=96
    f32x4 acc1[6][2];
    #pragma unroll
    for (int mf = 0; mf < 6; ++mf){ acc1[mf][0] = (f32x4){0,0,0,0}; acc1[mf][1] = (f32x4){0,0,0,0}; }
    #pragma unroll
    for (int ks = 0; ks < 3; ++ks){
      bf16x8 af[6];
      #pragma unroll
      for (int mf = 0; mf < 6; ++mf)
        af[mf] = *(const bf16x8*)&wa1[(mf*16 + lr)*104 + ks*32 + lg*8];
      bf16x8 bfr[2];
      #pragma unroll
      for (int ls = 0; ls < 2; ++ls)
        bfr[ls] = *(const bf16x8*)&bt[(wid*32 + ls*16 + lr)*104 + ks*32 + lg*8];
      #pragma unroll
      for (int mf = 0; mf < 6; ++mf)
        #pragma unroll
        for (int ls = 0; ls < 2; ++ls)
          acc1[mf][ls] = __builtin_amdgcn_mfma_f32_16x16x32_bf16(af[mf], bfr[ls], acc1[mf][ls], 0, 0, 0);
    }
    // fc2 consume: per ks, LN-affine + GELU + pack + cross-lane relayout + MFMA
    #pragma unroll
    for (int ks = 0; ks < 3; ++ks){
      int mlo = 2*ks, mhi = mlo + 1;
      bf16x8 a2[6];
      #pragma unroll
      for (int mf2 = 0; mf2 < 6; ++mf2)
        a2[mf2] = *(const bf16x8*)&wa2[(mf2*16 + lr)*104 + ks*32 + lg*8];
      float4 sl = *(const float4*)&s11[cc*96 + mlo*16 + lg*4];
      float4 cl = *(const float4*)&c1 [cc*96 + mlo*16 + lg*4];
      float4 sh = *(const float4*)&s11[cc*96 + mhi*16 + lg*4];
      float4 ch = *(const float4*)&c1 [cc*96 + mhi*16 + lg*4];
      #pragma unroll
      for (int ls = 0; ls < 2; ++ls){
        float g0 = gelu_f(fmaf(rs[ls], acc1[mlo][ls][0], fmaf(nmr[ls], sl.x, cl.x)));
        float g1 = gelu_f(fmaf(rs[ls], acc1[mlo][ls][1], fmaf(nmr[ls], sl.y, cl.y)));
        float g2 = gelu_f(fmaf(rs[ls], acc1[mlo][ls][2], fmaf(nmr[ls], sl.z, cl.z)));
        float g3 = gelu_f(fmaf(rs[ls], acc1[mlo][ls][3], fmaf(nmr[ls], sl.w, cl.w)));
        unsigned plo0 = pk_bf16(g0, g1), plo1 = pk_bf16(g2, g3);
        g0 = gelu_f(fmaf(rs[ls], acc1[mhi][ls][0], fmaf(nmr[ls], sh.x, ch.x)));
        g1 = gelu_f(fmaf(rs[ls], acc1[mhi][ls][1], fmaf(nmr[ls], sh.y, ch.y)));
        g2 = gelu_f(fmaf(rs[ls], acc1[mhi][ls][2], fmaf(nmr[ls], sh.z, ch.z)));
        g3 = gelu_f(fmaf(rs[ls], acc1[mhi][ls][3], fmaf(nmr[ls], sh.w, ch.w)));
        unsigned phi0 = pk_bf16(g0, g1), phi1 = pk_bf16(g2, g3);
        int t00 = __shfl((int)plo0, src0), t01 = __shfl((int)plo1, src0);
        int t02 = __shfl((int)plo0, src1), t03 = __shfl((int)plo1, src1);
        int t10 = __shfl((int)phi0, src0), t11 = __shfl((int)phi1, src0);
        int t12 = __shfl((int)phi0, src1), t13 = __shfl((int)phi1, src1);
        int4 bi;
        bi.x = lowsel ? t00 : t10;
        bi.y = lowsel ? t01 : t11;
        bi.z = lowsel ? t02 : t12;
        bi.w = lowsel ? t03 : t13;
        bf16x8 bfr = *(bf16x8*)&bi;
        #pragma unroll
        for (int mf2 = 0; mf2 < 6; ++mf2)
          acc2[mf2][ls] = __builtin_amdgcn_mfma_f32_16x16x32_bf16(a2[mf2], bfr, acc2[mf2][ls], 0, 0, 0);
      }
    }
  }
  // epilogue: + c2 + residual -> X f32, XT bf16, stats
  #pragma unroll
  for (int ls = 0; ls < 2; ++ls){
    int l = l0 + wid*32 + ls*16 + lr;
    int b = l >> 14, lb = l & (LL-1);
    float ssum = 0.f, ssq = 0.f;
    #pragma unroll
    for (int mf = 0; mf < 6; ++mf){
      float o[4];
      #pragma unroll
      for (int r = 0; r < 4; ++r){
        int mm = mf*16 + lg*4 + r;
        float vv = acc2[mf][ls][r] + c2[mm];
        vv += X[((size_t)b*96 + mm)*LL + lb];
        X[((size_t)b*96 + mm)*LL + lb] = vv;
        ssum += vv; ssq += vv*vv;
        o[r] = vv;
      }
      ushort4 pk;
      pk.x = f2bf(o[0]); pk.y = f2bf(o[1]); pk.z = f2bf(o[2]); pk.w = f2bf(o[3]);
      *(ushort4*)(XTout + (size_t)l*104 + mf*16 + lg*4) = pk;
    }
    ssum += __shfl_xor(ssum, 16); ssq += __shfl_xor(ssq, 16);
    ssum += __shfl_xor(ssum, 32); ssq += __shfl_xor(ssq, 32);
    if (lane < 16){
      float mu2 = ssum*(1.f/CC);
      float var = ssq*(1.f/CC) - mu2*mu2;
      stO[l] = mu2;
      stO[(size_t)BT*LL + l] = rsqrtf(var + 1e-5f);
    }
  }
}

// ---------------- depthwise 3x3 (SAME) + SiLU ----------------
__global__ void k_dwconv_silu(const float* __restrict__ u, float* __restrict__ v,
                              const float* __restrict__ cw){
  size_t i = (size_t)blockIdx.x*256 + threadIdx.x;
  if (i >= (size_t)BT*CC*LL) return;
  int w = i % WW; size_t t1 = i / WW;
  int h = t1 % HH; size_t bc = t1 / HH;
  int c = (int)(bc % CC);
  const float* up = u + bc*LL;
  const float* k9 = cw + c*9;
  float acc = 0.f;
  #pragma unroll
  for (int dh = -1; dh <= 1; ++dh){
    int h2 = h + dh; if (h2 < 0 || h2 >= HH) continue;
    #pragma unroll
    for (int dw = -1; dw <= 1; ++dw){
      int w2 = w + dw; if (w2 < 0 || w2 >= WW) continue;
      acc = fmaf(up[h2*WW + w2], k9[(dh+1)*3 + (dw+1)], acc);
    }
  }
  v[i] = acc / (1.f + __expf(-acc));
}

// ---------------- transpose (h,w)->(w,h) per (b,c) ----------------
__global__ void k_transpose(const float* __restrict__ src, float* __restrict__ dst){
  __shared__ float tile[32][33];
  int bc = blockIdx.z;
  const float* sp = src + (size_t)bc*LL;
  float* dp = dst + (size_t)bc*LL;
  int w0 = blockIdx.x*32, h0 = blockIdx.y*32;
  int tx = threadIdx.x, ty = threadIdx.y;
  #pragma unroll
  for (int kk = 0; kk < 4; ++kk){
    int h = h0 + ty + kk*8;
    tile[ty + kk*8][tx] = sp[(size_t)h*WW + w0 + tx];
  }
  __syncthreads();
  #pragma unroll
  for (int kk = 0; kk < 4; ++kk){
    int w = w0 + ty + kk*8;
    dp[(size_t)w*HH + h0 + tx] = tile[tx][ty + kk*8];
  }
}

// ---------------- x-projection (both sources in one launch) ----------------
__global__ void k_xproj(const float* __restrict__ v, const float* __restrict__ vT,
                        float* __restrict__ G, const float* __restrict__ xpw){
  int which = blockIdx.y;
  const float* src = which ? vT : v;
  int kA = which ? 1 : 0, kB = which ? 3 : 2;
  size_t i = (size_t)blockIdx.x*256 + threadIdx.x;
  if (i >= (size_t)BT*LL) return;
  int b = (int)(i / LL), l = (int)(i % LL);
  const float* sp = src + (size_t)b*CC*LL + l;
  const float* wA = xpw + (size_t)kA*8*CC;
  const float* wB = xpw + (size_t)kB*8*CC;
  float aA[8], aB[8];
  #pragma unroll
  for (int d = 0; d < 8; ++d){ aA[d] = 0.f; aB[d] = 0.f; }
  for (int c = 0; c < CC; ++c){
    float xv = sp[(size_t)c*LL];
    #pragma unroll
    for (int d = 0; d < 8; ++d){
      aA[d] = fmaf(wA[d*CC + c], xv, aA[d]);
      aB[d] = fmaf(wB[d*CC + c], xv, aB[d]);
    }
  }
  float* gA = G + (((size_t)b*KD + kA)*8)*LL + l;
  float* gB = G + (((size_t)b*KD + kB)*8)*LL + l;
  #pragma unroll
  for (int d = 0; d < 8; ++d){ gA[(size_t)d*LL] = aA[d]; gB[(size_t)d*LL] = aB[d]; }
}

// ---------------- tile-parallel selective scan v3 ----------------
__device__ __forceinline__ void ld4(const float* p, float* o){
  float4 t = *(const float4*)p; o[0]=t.x; o[1]=t.y; o[2]=t.z; o[3]=t.w;
}

template<bool REV>
__global__ __launch_bounds__(256) void k_scan3(const float* __restrict__ G,
                       const float* __restrict__ v, const float* __restrict__ vT,
                       float* __restrict__ Y,
                       const float* __restrict__ dtw_, const float* __restrict__ dtb_,
                       const float* __restrict__ Alog_, const float* __restrict__ Ds_){
  const size_t SZ = (size_t)BT*CC*LL;
  int wid = threadIdx.x >> 6, lane = threadIdx.x & 63;
  int tile = blockIdx.x*4 + wid;
  int sy = blockIdx.y;
  int c = sy % CC; int t2 = sy / CC; int kk = t2 & 1; int b = t2 >> 1;
  int k = REV ? (2 + kk) : kk;
  const float* src = (kk ? vT : v) + ((size_t)b*CC + c)*LL;
  const float* g = G + (((size_t)b*KD + k)*8)*LL;
  float dtw[RR];
  #pragma unroll
  for (int r = 0; r < RR; ++r) dtw[r] = dtw_[((size_t)k*CC + c)*RR + r];
  float dtb = dtb_[k*CC + c];
  float A  = -__expf(Alog_[k*CC + c]);
  float Dv = Ds_[k*CC + c];
  float* yout = Y + (size_t)k*SZ + ((size_t)b*CC + c)*LL;

  int lstore0 = tile*512;
  float carry = 0.f;
  for (int p = 0; p < 3; ++p){
    int base = lstore0 - 256 + p*256;
    if (base < 0) continue;
    int l = base + (lane<<2);
    int ga = REV ? (LL-4-l) : l;
    float r0[4], r1[4], r2[4], r3[4], r4[4], r5[4], g6b[4], g7b[4], xb[4];
    ld4(g + 0*(size_t)LL + ga, r0);
    ld4(g + 1*(size_t)LL + ga, r1);
    ld4(g + 2*(size_t)LL + ga, r2);
    ld4(g + 3*(size_t)LL + ga, r3);
    ld4(g + 4*(size_t)LL + ga, r4);
    ld4(g + 5*(size_t)LL + ga, r5);
    ld4(g + 6*(size_t)LL + ga, g6b);
    ld4(g + 7*(size_t)LL + ga, g7b);
    ld4(src + ga, xb);
    float av[4], bt[4], g7v[4], xv[4];
    #pragma unroll
    for (int i = 0; i < 4; ++i){
      int j = REV ? (3-i) : i;
      float dsum = dtb;
      dsum = fmaf(r0[j], dtw[0], dsum);
      dsum = fmaf(r1[j], dtw[1], dsum);
      dsum = fmaf(r2[j], dtw[2], dsum);
      dsum = fmaf(r3[j], dtw[3], dsum);
      dsum = fmaf(r4[j], dtw[4], dsum);
      dsum = fmaf(r5[j], dtw[5], dsum);
      float sp = __logf(1.f + __expf(dsum));
      float delta = (dsum > 20.f) ? dsum : sp;
      av[i] = __expf(delta * A);
      xv[i] = xb[j];
      g7v[i] = g7b[j];
      bt[i] = delta * g6b[j] * xv[i];
    }
    float P = av[0], Q = bt[0];
    #pragma unroll
    for (int i = 1; i < 4; ++i){ Q = fmaf(av[i], Q, bt[i]); P *= av[i]; }
    #pragma unroll
    for (int off = 1; off < 64; off <<= 1){
      float Pp = __shfl_up(P, (unsigned)off);
      float Qp = __shfl_up(Q, (unsigned)off);
      if (lane >= off){ Q = fmaf(P, Qp, Q); P *= Pp; }
    }
    float Pe = __shfl_up(P, 1u), Qe = __shfl_up(Q, 1u);
    if (lane == 0){ Pe = 1.f; Qe = 0.f; }
    float h = fmaf(Pe, carry, Qe);
    float ys[4];
    #pragma unroll
    for (int i = 0; i < 4; ++i){
      h = fmaf(av[i], h, bt[i]);
      ys[i] = fmaf(g7v[i], h, Dv*xv[i]);
    }
    carry = __shfl(h, 63);
    if (p > 0){
      float4 o;
      if (REV) o = make_float4(ys[3], ys[2], ys[1], ys[0]);
      else     o = make_float4(ys[0], ys[1], ys[2], ys[3]);
      *(float4*)&yout[ga] = o;
    }
  }
}

// ---------------- combine: z = (y0+y2) + transpose(y1+y3) ----------------
__global__ void k_combine4(const float* __restrict__ Y, float* __restrict__ z){
  const size_t SZ = (size_t)BT*CC*LL;
  __shared__ float tile[32][33];
  int bc = blockIdx.z;
  const float* y1p = Y + SZ   + (size_t)bc*LL;
  const float* y3p = Y + 3*SZ + (size_t)bc*LL;
  int w0 = blockIdx.x*32, h0 = blockIdx.y*32;
  int tx = threadIdx.x, ty = threadIdx.y;
  #pragma unroll
  for (int kk = 0; kk < 4; ++kk){
    int w = w0 + ty + kk*8;
    size_t idx = (size_t)w*HH + h0 + tx;
    tile[ty + kk*8][tx] = y1p[idx] + y3p[idx];
  }
  __syncthreads();
  const float* y0p = Y +        (size_t)bc*LL;
  const float* y2p = Y + 2*SZ + (size_t)bc*LL;
  float* zp = z + (size_t)bc*LL;
  #pragma unroll
  for (int kk = 0; kk < 4; ++kk){
    int h = h0 + ty + kk*8;
    size_t idx = (size_t)h*WW + w0 + tx;
    zp[idx] = y0p[idx] + y2p[idx] + tile[tx][ty + kk*8];
  }
}

// ---------------- final output split/average ----------------
__global__ void k_output(const float* __restrict__ X, float* __restrict__ out){
  size_t i = (size_t)blockIdx.x*256 + threadIdx.x;
  size_t half = (size_t)2*CC*HH*128;
  if (i >= half) return;
  int w = i % 128; size_t r = i / 128;
  int h = r % HH; size_t bc = r / HH;
  size_t fwd = (bc*HH + h)*WW;
  size_t bwd = ((bc + (size_t)2*CC)*HH + h)*WW;
  out[i]        = 0.5f*(X[fwd + w]       + X[bwd + (WW-1-w)]);
  out[half + i] = 0.5f*(X[fwd + 128 + w] + X[bwd + (127 - w)]);
}

extern "C" void kernel_launch(void* const* d_in, const int* in_sizes, int n_in,
                              void* d_out, int out_size, void* d_ws, size_t ws_size,
                              hipStream_t stream){
  const float* x0        = (const float*)d_in[0];
  const float* x1        = (const float*)d_in[1];
  const float* norm_w    = (const float*)d_in[2];
  const float* norm_b    = (const float*)d_in[3];
  const float* in_proj_w = (const float*)d_in[4];
  const float* conv_w    = (const float*)d_in[5];
  const float* x_proj_w  = (const float*)d_in[6];
  const float* dt_w      = (const float*)d_in[7];
  const float* dt_b      = (const float*)d_in[8];
  const float* A_logs    = (const float*)d_in[9];
  const float* Ds        = (const float*)d_in[10];
  const float* out_norm_w= (const float*)d_in[11];
  const float* out_norm_b= (const float*)d_in[12];
  const float* out_proj_w= (const float*)d_in[13];
  const float* norm2_w   = (const float*)d_in[14];
  const float* norm2_b   = (const float*)d_in[15];
  const float* fc1_w     = (const float*)d_in[16];
  const float* fc1_b     = (const float*)d_in[17];
  const float* fc2_w     = (const float*)d_in[18];
  const float* fc2_b     = (const float*)d_in[19];

  const size_t SZ = (size_t)BT*CC*LL;            // 6,291,456 floats
  float* X  = (float*)d_ws;
  float* t  = X + SZ;
  float* u  = t + SZ;
  float* G  = u + SZ;                            // BT*KD*8*LL floats
  float* v  = G + (size_t)BT*KD*8*LL;
  float* vT = v + SZ;
  float* Y  = vT + SZ;                           // 4 contiguous SZ buffers
  u16*   XT  = (u16*)Y;                          // bf16T [BT*LL][104] (phase-disjoint w/ Y0)
  u16*   tT  = (u16*)u;                          // bf16T of t (u dead by then)
  float* ext = Y + 4*SZ;
  float* stats_X = ext;                          // 2*BT*LL
  float* stats_t = stats_X + 2*(size_t)BT*LL;
  float* wsl     = stats_t + 2*(size_t)BT*LL;    // weight slots: NLAY * SLOTF floats

  // per-layer slot offsets (float units), layout per layer:
  // WbI 4608 | s1I 96 | cI 96 | WbO 4608 | s1O 96 | cO 96 |
  // Wb1 18432 | s11 384 | c1 384 | Wb2 18432 | s12 96 | c2 96   == SLOTF
  float* p0 = wsl;
  u16*  WbI0 = (u16*)p0;          float* s1I0 = p0 + 4608;  float* cI0 = p0 + 4704;
  u16*  WbO0 = (u16*)(p0+4800);   float* s1O0 = p0 + 9408;  float* cO0 = p0 + 9504;
  u16*  Wb10 = (u16*)(p0+9600);   float* s110 = p0 + 28032; float* c10 = p0 + 28416;
  u16*  Wb20 = (u16*)(p0+28800);  float* s120 = p0 + 47232; float* c20 = p0 + 47328;

  // weight prep: 4 launches, layers via blockIdx.y
  k_prepw<96,96,true,false><<<dim3(2,NLAY),64,0,stream>>>(in_proj_w, norm_w, norm_b, nullptr, WbI0, s1I0, cI0);
  k_prepw<96,96,true,false><<<dim3(2,NLAY),64,0,stream>>>(out_proj_w, out_norm_w, out_norm_b, nullptr, WbO0, s1O0, cO0);
  k_prepw<384,96,true,true><<<dim3(6,NLAY),64,0,stream>>>(fc1_w, norm2_w, norm2_b, fc1_b, Wb10, s110, c10);
  k_prepw<96,384,false,true><<<dim3(2,NLAY),64,0,stream>>>(fc2_w, nullptr, nullptr, fc2_b, Wb20, s120, c20);

  k_build<<<(2*CC*HH*WW + 255)/256, 256, 0, stream>>>(x0, x1, X);
  k_pack<true><<<dim3(LL/32, BT), 256, 0, stream>>>(X, XT, stats_X);

  for (int lay = 0; lay < NLAY; ++lay){
    size_t so = (size_t)lay*SLOTF;
    const u16* WbI = WbI0 + so*2; const float* s1I = s1I0 + so; const float* cI = cI0 + so;
    const u16* WbO = WbO0 + so*2; const float* s1O = s1O0 + so; const float* cO = cO0 + so;
    const u16* Wb1 = Wb10 + so*2; const float* s11 = s110 + so; const float* c1 = c10 + so;
    const u16* Wb2 = Wb20 + so*2; const float* c2 = c20 + so;
    const float* cw  = conv_w    + (size_t)lay*CC*9;
    const float* xpw = x_proj_w  + (size_t)lay*KD*8*CC;
    const float* dw  = dt_w      + (size_t)lay*KD*CC*RR;
    const float* db  = dt_b      + (size_t)lay*KD*CC;
    const float* Al  = A_logs    + (size_t)lay*KD*CC;
    const float* Dp  = Ds        + (size_t)lay*KD*CC;

    // in_proj (LN fused): u = W' * X
    k_gmm2<true,false,true,false,false><<<dim3(BT*LL/128),256,0,stream>>>(
        WbI, XT, u, nullptr, s1I, cI, nullptr, stats_X, nullptr);
    k_dwconv_silu<<<(unsigned)((SZ + 255)/256), 256, 0, stream>>>(u, v, cw);
    k_transpose<<<dim3(8,2,BT*CC), dim3(32,8), 0, stream>>>(v, vT);
    k_xproj<<<dim3(BT*LL/256, 2), 256, 0, stream>>>(v, vT, G, xpw);
    k_scan3<false><<<dim3(8,768), 256, 0, stream>>>(G, v, vT, Y, dw, db, Al, Dp);
    k_scan3<true ><<<dim3(8,768), 256, 0, stream>>>(G, v, vT, Y, dw, db, Al, Dp);
    k_combine4<<<dim3(8,2,BT*CC), dim3(32,8), 0, stream>>>(Y, t);
    k_pack<true><<<dim3(LL/32, BT), 256, 0, stream>>>(t, tT, stats_t);
    // out_proj (LN fused) + residual -> X (f32 + XT bf16 + stats_X)
    k_gmm2<true,true,true,true,true><<<dim3(BT*LL/128),256,0,stream>>>(
        WbO, tT, X, XT, s1O, cO, X, stats_t, stats_X);
    // fused MLP
    k_mlp<<<dim3(BT*LL/128),256,0,stream>>>(
        Wb1, Wb2, XT, X, XT, s11, c1, c2, stats_X, stats_X);
  }

  k_output<<<(unsigned)(((size_t)2*CC*HH*128 + 255)/256), 256, 0, stream>>>(X, (float*)d_out);
}

// Round 6
// 522.645 us; speedup vs baseline: 9.3667x; 1.0017x over previous
//
#include <hip/hip_runtime.h>
#include <cstdint>
#include <cstddef>

#define BT 4
#define CC 96
#define HH 64
#define WW 256
#define LL (HH*WW)    // 16384
#define KD 4
#define RR 6
#define NLAY 2
#define C4 (4*CC)     // 384
#define SLOTF 47424   // per-layer weight-slot stride in float units

typedef unsigned short u16;
typedef __attribute__((ext_vector_type(8))) short bf16x8;
typedef __attribute__((ext_vector_type(4))) float f32x4;

__device__ __forceinline__ u16 f2bf(float f){
  unsigned u = __float_as_uint(f);
  unsigned r = (u + 0x7FFFu + ((u >> 16) & 1u)) >> 16;
  return (u16)r;
}
__device__ __forceinline__ float bf2f(u16 h){
  return __uint_as_float(((unsigned)h) << 16);
}
__device__ __forceinline__ unsigned pk_bf16(float lo, float hi){
  unsigned r;
  asm volatile("v_cvt_pk_bf16_f32 %0, %1, %2" : "=v"(r) : "v"(lo), "v"(hi));
  return r;
}
// tanh-approx GELU, division-free: 0.5v(1+tanh u) = v*(1 - 1/(e^{2u}+1))
__device__ __forceinline__ float gelu_f(float v){
  float t = v*v;
  float u = v*fmaf(0.0356774081f, t, 0.7978845608f);
  float e2 = __expf(2.f*u);
  float r = __builtin_amdgcn_rcpf(e2 + 1.f);
  return fmaf(-v, r, v);
}

// ---------------- build batched input ----------------
__global__ void k_build(const float* __restrict__ x0, const float* __restrict__ x1,
                        float* __restrict__ X){
  size_t i = (size_t)blockIdx.x*256 + threadIdx.x;
  size_t tot = (size_t)2*CC*HH*WW;
  if (i >= tot) return;
  int w = i % WW; size_t r = i / WW;
  int h = r % HH; size_t bc = r / HH;
  float val;
  if (w < 128) val = x0[(bc*HH + h)*128 + w];
  else         val = x1[(bc*HH + h)*128 + (w-128)];
  X[i] = val;
  size_t ib = ((bc + (size_t)2*CC)*HH + h)*WW + (WW-1-w);
  X[ib] = val;
}

// ---------------- pack f32 [b][c][l] -> bf16T [b*LL+l][104] (+ LN stats) ----------------
template<bool ST>
__global__ __launch_bounds__(256) void k_pack(const float* __restrict__ src,
      u16* __restrict__ dst, float* __restrict__ st){
  __shared__ float tl[CC][33];
  int tid = threadIdx.x;
  int l0 = blockIdx.x*32, b = blockIdx.y;
  for (int e = tid; e < CC*32; e += 256){
    int c = e >> 5, dl = e & 31;
    tl[c][dl] = src[((size_t)b*CC + c)*LL + l0 + dl];
  }
  __syncthreads();
  if (ST && tid < 32){
    float s = 0.f, ss = 0.f;
    for (int c = 0; c < CC; ++c){ float vv = tl[c][tid]; s += vv; ss += vv*vv; }
    float mu = s*(1.f/CC);
    float var = ss*(1.f/CC) - mu*mu;
    st[(size_t)b*LL + l0 + tid] = mu;
    st[(size_t)BT*LL + (size_t)b*LL + l0 + tid] = rsqrtf(var + 1e-5f);
  }
  int dl = tid >> 3, cg = tid & 7;
  u16* dp = dst + ((size_t)b*LL + l0 + dl)*104 + cg*12;
  #pragma unroll
  for (int q = 0; q < 3; ++q){
    ushort4 pk;
    pk.x = f2bf(tl[cg*12 + q*4 + 0][dl]);
    pk.y = f2bf(tl[cg*12 + q*4 + 1][dl]);
    pk.z = f2bf(tl[cg*12 + q*4 + 2][dl]);
    pk.w = f2bf(tl[cg*12 + q*4 + 3][dl]);
    *(ushort4*)(dp + q*4) = pk;
  }
}

// ---------------- weight prep (layered via blockIdx.y) ----------------
template<int M, int K, bool LNF, bool BIAS>
__global__ void k_prepw(const float* __restrict__ W, const float* __restrict__ lnw,
      const float* __restrict__ lnb, const float* __restrict__ bias,
      u16* __restrict__ Wb, float* __restrict__ s1, float* __restrict__ cadd){
  int lay = blockIdx.y;
  W += (size_t)lay*M*K;
  Wb += (size_t)lay*SLOTF*2;
  s1 += (size_t)lay*SLOTF;
  cadd += (size_t)lay*SLOTF;
  int m = blockIdx.x*64 + threadIdx.x;
  if (m >= M) return;
  float s1v = 0.f, sbv = 0.f;
  for (int c = 0; c < K; ++c){
    float wv = W[(size_t)m*K + c];
    float wf = LNF ? wv*lnw[lay*K + c] : wv;
    u16 h = f2bf(wf);
    Wb[(size_t)m*K + c] = h;
    s1v += bf2f(h);
    if (LNF) sbv = fmaf(wv, lnb[lay*K + c], sbv);
  }
  if (BIAS) sbv += bias[lay*M + m];
  s1[m] = s1v;
  cadd[m] = sbv;
}

// ---------------- MFMA GEMM (M=96,K=96): LDS B tile, global A (L1-resident) ----------------
template<bool LNF, bool RES, bool WF32, bool WBF, bool STATS>
__global__ __launch_bounds__(256) void k_gmm2(
    const u16* __restrict__ Wb, const u16* __restrict__ inT,
    float* __restrict__ outF, u16* __restrict__ outT,
    const float* __restrict__ s1v, const float* __restrict__ cadd,
    const float* __restrict__ res,
    const float* __restrict__ stI, float* __restrict__ stO){
  __shared__ u16 bt[128*104];
  int tid = threadIdx.x, lane = tid & 63, wid = tid >> 6;
  int l0 = blockIdx.x*128;
  int lr = lane & 15, lg = lane >> 4;
  const int4* bsrc = (const int4*)(inT + (size_t)l0*104);
  for (int i = tid; i < 1664; i += 256) ((int4*)bt)[i] = bsrc[i];
  __syncthreads();
  f32x4 acc[6][2];
  #pragma unroll
  for (int mf = 0; mf < 6; ++mf){ acc[mf][0] = (f32x4){0,0,0,0}; acc[mf][1] = (f32x4){0,0,0,0}; }
  #pragma unroll
  for (int ks = 0; ks < 3; ++ks){
    bf16x8 af[6];
    #pragma unroll
    for (int mf = 0; mf < 6; ++mf)
      af[mf] = *(const bf16x8*)(Wb + (size_t)(mf*16 + lr)*96 + ks*32 + lg*8);
    bf16x8 bfr[2];
    #pragma unroll
    for (int ls = 0; ls < 2; ++ls)
      bfr[ls] = *(const bf16x8*)&bt[(wid*32 + ls*16 + lr)*104 + ks*32 + lg*8];
    #pragma unroll
    for (int mf = 0; mf < 6; ++mf)
      #pragma unroll
      for (int ls = 0; ls < 2; ++ls)
        acc[mf][ls] = __builtin_amdgcn_mfma_f32_16x16x32_bf16(af[mf], bfr[ls], acc[mf][ls], 0, 0, 0);
  }
  #pragma unroll
  for (int ls = 0; ls < 2; ++ls){
    int l = l0 + wid*32 + ls*16 + lr;
    int b = l >> 14, lb = l & (LL-1);
    float mu = 0.f, rs = 0.f;
    if (LNF){ mu = stI[l]; rs = stI[(size_t)BT*LL + l]; }
    float ssum = 0.f, ssq = 0.f;
    #pragma unroll
    for (int mf = 0; mf < 6; ++mf){
      float o[4];
      #pragma unroll
      for (int r = 0; r < 4; ++r){
        int mm = mf*16 + lg*4 + r;
        float vv = acc[mf][ls][r];
        if (LNF) vv = fmaf(rs, vv, fmaf(-mu*rs, s1v[mm], cadd[mm]));
        else     vv += cadd[mm];
        if (RES) vv += res[((size_t)b*96 + mm)*LL + lb];
        if (WF32) outF[((size_t)b*96 + mm)*LL + lb] = vv;
        if (STATS){ ssum += vv; ssq += vv*vv; }
        o[r] = vv;
      }
      if (WBF){
        ushort4 pk;
        pk.x = f2bf(o[0]); pk.y = f2bf(o[1]); pk.z = f2bf(o[2]); pk.w = f2bf(o[3]);
        *(ushort4*)(outT + (size_t)l*104 + mf*16 + lg*4) = pk;
      }
    }
    if (STATS){
      ssum += __shfl_xor(ssum, 16); ssq += __shfl_xor(ssq, 16);
      ssum += __shfl_xor(ssum, 32); ssq += __shfl_xor(ssq, 32);
      if (lane < 16){
        float mu2 = ssum*(1.f/CC);
        float var = ssq*(1.f/CC) - mu2*mu2;
        stO[l] = mu2;
        stO[(size_t)BT*LL + l] = rsqrtf(var + 1e-5f);
      }
    }
  }
}

// ---------------- fused MLP v2: LDS hidden relayout, global weights, 1 barrier ----------------
__global__ __launch_bounds__(256) void k_mlp(
    const u16* __restrict__ Wb1, const u16* __restrict__ Wb2,
    const u16* __restrict__ XT, float* __restrict__ X, u16* __restrict__ XTout,
    const float* __restrict__ s11, const float* __restrict__ c1,
    const float* __restrict__ c2,
    const float* __restrict__ stI, float* __restrict__ stO){
  __shared__ u16 bt[128*104];
  __shared__ u16 hs[128*104];
  int tid = threadIdx.x, lane = tid & 63, wid = tid >> 6;
  int l0 = blockIdx.x*128;
  int lr = lane & 15, lg = lane >> 4;
  const int4* bsrc = (const int4*)(XT + (size_t)l0*104);
  for (int i = tid; i < 1664; i += 256) ((int4*)bt)[i] = bsrc[i];

  float rs[2], nmr[2];
  #pragma unroll
  for (int ls = 0; ls < 2; ++ls){
    int l = l0 + wid*32 + ls*16 + lr;
    float mu = stI[l];
    rs[ls] = stI[(size_t)BT*LL + l];
    nmr[ls] = -mu*rs[ls];
  }
  __syncthreads();

  f32x4 acc2[6][2];
  #pragma unroll
  for (int mf = 0; mf < 6; ++mf){ acc2[mf][0] = (f32x4){0,0,0,0}; acc2[mf][1] = (f32x4){0,0,0,0}; }

  for (int cc = 0; cc < 4; ++cc){
    // fc1 chunk (96 hidden rows) over K=96
    f32x4 acc1[6][2];
    #pragma unroll
    for (int mf = 0; mf < 6; ++mf){ acc1[mf][0] = (f32x4){0,0,0,0}; acc1[mf][1] = (f32x4){0,0,0,0}; }
    #pragma unroll
    for (int ks = 0; ks < 3; ++ks){
      bf16x8 af[6];
      #pragma unroll
      for (int mf = 0; mf < 6; ++mf)
        af[mf] = *(const bf16x8*)(Wb1 + (size_t)(cc*96 + mf*16 + lr)*96 + ks*32 + lg*8);
      bf16x8 bfr[2];
      #pragma unroll
      for (int ls = 0; ls < 2; ++ls)
        bfr[ls] = *(const bf16x8*)&bt[(wid*32 + ls*16 + lr)*104 + ks*32 + lg*8];
      #pragma unroll
      for (int mf = 0; mf < 6; ++mf)
        #pragma unroll
        for (int ls = 0; ls < 2; ++ls)
          acc1[mf][ls] = __builtin_amdgcn_mfma_f32_16x16x32_bf16(af[mf], bfr[ls], acc1[mf][ls], 0, 0, 0);
    }
    // LN-affine + GELU + bf16-pack -> hs (own wave's pixel stripe; no barrier needed)
    #pragma unroll
    for (int mf = 0; mf < 6; ++mf){
      float4 sv = *(const float4*)&s11[cc*96 + mf*16 + lg*4];
      float4 cv = *(const float4*)&c1 [cc*96 + mf*16 + lg*4];
      #pragma unroll
      for (int ls = 0; ls < 2; ++ls){
        float g0 = gelu_f(fmaf(rs[ls], acc1[mf][ls][0], fmaf(nmr[ls], sv.x, cv.x)));
        float g1 = gelu_f(fmaf(rs[ls], acc1[mf][ls][1], fmaf(nmr[ls], sv.y, cv.y)));
        float g2 = gelu_f(fmaf(rs[ls], acc1[mf][ls][2], fmaf(nmr[ls], sv.z, cv.z)));
        float g3 = gelu_f(fmaf(rs[ls], acc1[mf][ls][3], fmaf(nmr[ls], sv.w, cv.w)));
        uint2 pw;
        pw.x = pk_bf16(g0, g1);
        pw.y = pk_bf16(g2, g3);
        *(uint2*)&hs[(wid*32 + ls*16 + lr)*104 + mf*16 + lg*4] = pw;
      }
    }
    // fc2 partial over this 96-chunk
    #pragma unroll
    for (int ks = 0; ks < 3; ++ks){
      bf16x8 a2[6];
      #pragma unroll
      for (int mf2 = 0; mf2 < 6; ++mf2)
        a2[mf2] = *(const bf16x8*)(Wb2 + (size_t)(mf2*16 + lr)*384 + cc*96 + ks*32 + lg*8);
      bf16x8 bfr2[2];
      #pragma unroll
      for (int ls = 0; ls < 2; ++ls)
        bfr2[ls] = *(const bf16x8*)&hs[(wid*32 + ls*16 + lr)*104 + ks*32 + lg*8];
      #pragma unroll
      for (int mf2 = 0; mf2 < 6; ++mf2)
        #pragma unroll
        for (int ls = 0; ls < 2; ++ls)
          acc2[mf2][ls] = __builtin_amdgcn_mfma_f32_16x16x32_bf16(a2[mf2], bfr2[ls], acc2[mf2][ls], 0, 0, 0);
    }
  }
  // epilogue: + c2 + residual -> X f32, XT bf16, stats
  #pragma unroll
  for (int ls = 0; ls < 2; ++ls){
    int l = l0 + wid*32 + ls*16 + lr;
    int b = l >> 14, lb = l & (LL-1);
    float ssum = 0.f, ssq = 0.f;
    #pragma unroll
    for (int mf = 0; mf < 6; ++mf){
      float o[4];
      #pragma unroll
      for (int r = 0; r < 4; ++r){
        int mm = mf*16 + lg*4 + r;
        float vv = acc2[mf][ls][r] + c2[mm];
        vv += X[((size_t)b*96 + mm)*LL + lb];
        X[((size_t)b*96 + mm)*LL + lb] = vv;
        ssum += vv; ssq += vv*vv;
        o[r] = vv;
      }
      ushort4 pk;
      pk.x = f2bf(o[0]); pk.y = f2bf(o[1]); pk.z = f2bf(o[2]); pk.w = f2bf(o[3]);
      *(ushort4*)(XTout + (size_t)l*104 + mf*16 + lg*4) = pk;
    }
    ssum += __shfl_xor(ssum, 16); ssq += __shfl_xor(ssq, 16);
    ssum += __shfl_xor(ssum, 32); ssq += __shfl_xor(ssq, 32);
    if (lane < 16){
      float mu2 = ssum*(1.f/CC);
      float var = ssq*(1.f/CC) - mu2*mu2;
      stO[l] = mu2;
      stO[(size_t)BT*LL + l] = rsqrtf(var + 1e-5f);
    }
  }
}

// ---------------- depthwise 3x3 + SiLU, fused transpose (writes v and vT) ----------------
__global__ __launch_bounds__(256) void k_dwconv_silu_t(const float* __restrict__ u,
      float* __restrict__ v, float* __restrict__ vT, const float* __restrict__ cw){
  __shared__ float tl[32][33];
  int bc = blockIdx.z;
  int c = bc % CC;
  int w0 = blockIdx.x*32, h0 = blockIdx.y*32;
  const float* up = u + (size_t)bc*LL;
  const float* k9 = cw + c*9;
  int t = threadIdx.x;
  int wl = (t & 7)*4, hl = t >> 3;
  int h = h0 + hl, w = w0 + wl;
  float acc[4] = {0.f,0.f,0.f,0.f};
  #pragma unroll
  for (int dh = -1; dh <= 1; ++dh){
    int h2 = h + dh;
    if (h2 < 0 || h2 >= HH) continue;
    const float* row = up + (size_t)h2*WW + w;
    float4 m = *(const float4*)row;
    float lft = (w > 0) ? row[-1] : 0.f;
    float rgt = (w + 4 < WW) ? row[4] : 0.f;
    float k0 = k9[(dh+1)*3], k1 = k9[(dh+1)*3+1], k2 = k9[(dh+1)*3+2];
    acc[0] += lft*k0 + m.x*k1 + m.y*k2;
    acc[1] += m.x*k0 + m.y*k1 + m.z*k2;
    acc[2] += m.y*k0 + m.z*k1 + m.w*k2;
    acc[3] += m.z*k0 + m.w*k1 + rgt*k2;
  }
  float4 ov;
  float* po = (float*)&ov;
  #pragma unroll
  for (int j = 0; j < 4; ++j){
    float a = acc[j];
    float e = __expf(-a);
    float s = a * __builtin_amdgcn_rcpf(1.f + e);
    po[j] = s;
    tl[wl + j][hl] = s;
  }
  *(float4*)&v[(size_t)bc*LL + (size_t)h*WW + w] = ov;
  __syncthreads();
  int ww = t >> 3, hh4 = (t & 7)*4;
  float4 o2 = make_float4(tl[ww][hh4], tl[ww][hh4+1], tl[ww][hh4+2], tl[ww][hh4+3]);
  *(float4*)&vT[(size_t)bc*LL + (size_t)(w0 + ww)*HH + h0 + hh4] = o2;
}

// ---------------- x-projection (both sources in one launch) ----------------
__global__ void k_xproj(const float* __restrict__ v, const float* __restrict__ vT,
                        float* __restrict__ G, const float* __restrict__ xpw){
  int which = blockIdx.y;
  const float* src = which ? vT : v;
  int kA = which ? 1 : 0, kB = which ? 3 : 2;
  size_t i = (size_t)blockIdx.x*256 + threadIdx.x;
  if (i >= (size_t)BT*LL) return;
  int b = (int)(i / LL), l = (int)(i % LL);
  const float* sp = src + (size_t)b*CC*LL + l;
  const float* wA = xpw + (size_t)kA*8*CC;
  const float* wB = xpw + (size_t)kB*8*CC;
  float aA[8], aB[8];
  #pragma unroll
  for (int d = 0; d < 8; ++d){ aA[d] = 0.f; aB[d] = 0.f; }
  for (int c = 0; c < CC; ++c){
    float xv = sp[(size_t)c*LL];
    #pragma unroll
    for (int d = 0; d < 8; ++d){
      aA[d] = fmaf(wA[d*CC + c], xv, aA[d]);
      aB[d] = fmaf(wB[d*CC + c], xv, aB[d]);
    }
  }
  float* gA = G + (((size_t)b*KD + kA)*8)*LL + l;
  float* gB = G + (((size_t)b*KD + kB)*8)*LL + l;
  #pragma unroll
  for (int d = 0; d < 8; ++d){ gA[(size_t)d*LL] = aA[d]; gB[(size_t)d*LL] = aB[d]; }
}

// ---------------- tile-parallel selective scan (fwd+rev in one launch) ----------------
__device__ __forceinline__ void ld4(const float* p, float* o){
  float4 t = *(const float4*)p; o[0]=t.x; o[1]=t.y; o[2]=t.z; o[3]=t.w;
}
__device__ __forceinline__ void rev4(float* a){
  float t0 = a[0]; a[0] = a[3]; a[3] = t0;
  float t1 = a[1]; a[1] = a[2]; a[2] = t1;
}

__global__ __launch_bounds__(256) void k_scan3(const float* __restrict__ G,
                       const float* __restrict__ v, const float* __restrict__ vT,
                       float* __restrict__ Y,
                       const float* __restrict__ dtw_, const float* __restrict__ dtb_,
                       const float* __restrict__ Alog_, const float* __restrict__ Ds_){
  const size_t SZ = (size_t)BT*CC*LL;
  int wid = threadIdx.x >> 6, lane = threadIdx.x & 63;
  int tile = blockIdx.x*4 + wid;
  int sy = blockIdx.y;
  bool rev = (blockIdx.z != 0);
  int c = sy % CC; int t2 = sy / CC; int kk = t2 & 1; int b = t2 >> 1;
  int k = (rev ? 2 : 0) + kk;
  const float* src = (kk ? vT : v) + ((size_t)b*CC + c)*LL;
  const float* g = G + (((size_t)b*KD + k)*8)*LL;
  float dtw[RR];
  #pragma unroll
  for (int r = 0; r < RR; ++r) dtw[r] = dtw_[((size_t)k*CC + c)*RR + r];
  float dtb = dtb_[k*CC + c];
  float A  = -__expf(Alog_[k*CC + c]);
  float Dv = Ds_[k*CC + c];
  float* yout = Y + (size_t)k*SZ + ((size_t)b*CC + c)*LL;

  int lstore0 = tile*512;
  float carry = 0.f;
  for (int p = 0; p < 3; ++p){
    int base = lstore0 - 256 + p*256;
    if (base < 0) continue;
    int l = base + (lane<<2);
    int ga = rev ? (LL-4-l) : l;
    float r0[4], r1[4], r2[4], r3[4], r4[4], r5[4], g6b[4], g7b[4], xb[4];
    ld4(g + 0*(size_t)LL + ga, r0);
    ld4(g + 1*(size_t)LL + ga, r1);
    ld4(g + 2*(size_t)LL + ga, r2);
    ld4(g + 3*(size_t)LL + ga, r3);
    ld4(g + 4*(size_t)LL + ga, r4);
    ld4(g + 5*(size_t)LL + ga, r5);
    ld4(g + 6*(size_t)LL + ga, g6b);
    ld4(g + 7*(size_t)LL + ga, g7b);
    ld4(src + ga, xb);
    if (rev){
      rev4(r0); rev4(r1); rev4(r2); rev4(r3); rev4(r4); rev4(r5);
      rev4(g6b); rev4(g7b); rev4(xb);
    }
    float av[4], bt[4];
    #pragma unroll
    for (int i = 0; i < 4; ++i){
      float dsum = dtb;
      dsum = fmaf(r0[i], dtw[0], dsum);
      dsum = fmaf(r1[i], dtw[1], dsum);
      dsum = fmaf(r2[i], dtw[2], dsum);
      dsum = fmaf(r3[i], dtw[3], dsum);
      dsum = fmaf(r4[i], dtw[4], dsum);
      dsum = fmaf(r5[i], dtw[5], dsum);
      float sp = __logf(1.f + __expf(dsum));
      float delta = (dsum > 20.f) ? dsum : sp;
      av[i] = __expf(delta * A);
      bt[i] = delta * g6b[i] * xb[i];
    }
    float P = av[0], Q = bt[0];
    #pragma unroll
    for (int i = 1; i < 4; ++i){ Q = fmaf(av[i], Q, bt[i]); P *= av[i]; }
    #pragma unroll
    for (int off = 1; off < 64; off <<= 1){
      float Pp = __shfl_up(P, (unsigned)off);
      float Qp = __shfl_up(Q, (unsigned)off);
      if (lane >= off){ Q = fmaf(P, Qp, Q); P *= Pp; }
    }
    float Pe = __shfl_up(P, 1u), Qe = __shfl_up(Q, 1u);
    if (lane == 0){ Pe = 1.f; Qe = 0.f; }
    float h = fmaf(Pe, carry, Qe);
    float ys[4];
    #pragma unroll
    for (int i = 0; i < 4; ++i){
      h = fmaf(av[i], h, bt[i]);
      ys[i] = fmaf(g7b[i], h, Dv*xb[i]);
    }
    carry = __shfl(h, 63);
    if (p > 0){
      if (rev) rev4(ys);
      *(float4*)&yout[ga] = make_float4(ys[0], ys[1], ys[2], ys[3]);
    }
  }
}

// ---------------- combine: z = (y0+y2) + transpose(y1+y3) ----------------
__global__ void k_combine4(const float* __restrict__ Y, float* __restrict__ z){
  const size_t SZ = (size_t)BT*CC*LL;
  __shared__ float tile[32][33];
  int bc = blockIdx.z;
  const float* y1p = Y + SZ   + (size_t)bc*LL;
  const float* y3p = Y + 3*SZ + (size_t)bc*LL;
  int w0 = blockIdx.x*32, h0 = blockIdx.y*32;
  int tx = threadIdx.x, ty = threadIdx.y;
  #pragma unroll
  for (int kk = 0; kk < 4; ++kk){
    int w = w0 + ty + kk*8;
    size_t idx = (size_t)w*HH + h0 + tx;
    tile[ty + kk*8][tx] = y1p[idx] + y3p[idx];
  }
  __syncthreads();
  const float* y0p = Y +        (size_t)bc*LL;
  const float* y2p = Y + 2*SZ + (size_t)bc*LL;
  float* zp = z + (size_t)bc*LL;
  #pragma unroll
  for (int kk = 0; kk < 4; ++kk){
    int h = h0 + ty + kk*8;
    size_t idx = (size_t)h*WW + w0 + tx;
    zp[idx] = y0p[idx] + y2p[idx] + tile[tx][ty + kk*8];
  }
}

// ---------------- final output split/average ----------------
__global__ void k_output(const float* __restrict__ X, float* __restrict__ out){
  size_t i = (size_t)blockIdx.x*256 + threadIdx.x;
  size_t half = (size_t)2*CC*HH*128;
  if (i >= half) return;
  int w = i % 128; size_t r = i / 128;
  int h = r % HH; size_t bc = r / HH;
  size_t fwd = (bc*HH + h)*WW;
  size_t bwd = ((bc + (size_t)2*CC)*HH + h)*WW;
  out[i]        = 0.5f*(X[fwd + w]       + X[bwd + (WW-1-w)]);
  out[half + i] = 0.5f*(X[fwd + 128 + w] + X[bwd + (127 - w)]);
}

extern "C" void kernel_launch(void* const* d_in, const int* in_sizes, int n_in,
                              void* d_out, int out_size, void* d_ws, size_t ws_size,
                              hipStream_t stream){
  const float* x0        = (const float*)d_in[0];
  const float* x1        = (const float*)d_in[1];
  const float* norm_w    = (const float*)d_in[2];
  const float* norm_b    = (const float*)d_in[3];
  const float* in_proj_w = (const float*)d_in[4];
  const float* conv_w    = (const float*)d_in[5];
  const float* x_proj_w  = (const float*)d_in[6];
  const float* dt_w      = (const float*)d_in[7];
  const float* dt_b      = (const float*)d_in[8];
  const float* A_logs    = (const float*)d_in[9];
  const float* Ds        = (const float*)d_in[10];
  const float* out_norm_w= (const float*)d_in[11];
  const float* out_norm_b= (const float*)d_in[12];
  const float* out_proj_w= (const float*)d_in[13];
  const float* norm2_w   = (const float*)d_in[14];
  const float* norm2_b   = (const float*)d_in[15];
  const float* fc1_w     = (const float*)d_in[16];
  const float* fc1_b     = (const float*)d_in[17];
  const float* fc2_w     = (const float*)d_in[18];
  const float* fc2_b     = (const float*)d_in[19];

  const size_t SZ = (size_t)BT*CC*LL;            // 6,291,456 floats
  float* X  = (float*)d_ws;
  float* t  = X + SZ;
  float* u  = t + SZ;
  float* G  = u + SZ;                            // BT*KD*8*LL floats
  float* v  = G + (size_t)BT*KD*8*LL;
  float* vT = v + SZ;
  float* Y  = vT + SZ;                           // 4 contiguous SZ buffers
  u16*   XT  = (u16*)Y;                          // bf16T [BT*LL][104] (phase-disjoint w/ Y0)
  u16*   tT  = (u16*)u;                          // bf16T of t (u dead by then)
  float* ext = Y + 4*SZ;
  float* stats_X = ext;                          // 2*BT*LL
  float* stats_t = stats_X + 2*(size_t)BT*LL;
  float* wsl     = stats_t + 2*(size_t)BT*LL;    // weight slots: NLAY * SLOTF floats

  float* p0 = wsl;
  u16*  WbI0 = (u16*)p0;          float* s1I0 = p0 + 4608;  float* cI0 = p0 + 4704;
  u16*  WbO0 = (u16*)(p0+4800);   float* s1O0 = p0 + 9408;  float* cO0 = p0 + 9504;
  u16*  Wb10 = (u16*)(p0+9600);   float* s110 = p0 + 28032; float* c10 = p0 + 28416;
  u16*  Wb20 = (u16*)(p0+28800);  float* s120 = p0 + 47232; float* c20 = p0 + 47328;

  k_prepw<96,96,true,false><<<dim3(2,NLAY),64,0,stream>>>(in_proj_w, norm_w, norm_b, nullptr, WbI0, s1I0, cI0);
  k_prepw<96,96,true,false><<<dim3(2,NLAY),64,0,stream>>>(out_proj_w, out_norm_w, out_norm_b, nullptr, WbO0, s1O0, cO0);
  k_prepw<384,96,true,true><<<dim3(6,NLAY),64,0,stream>>>(fc1_w, norm2_w, norm2_b, fc1_b, Wb10, s110, c10);
  k_prepw<96,384,false,true><<<dim3(2,NLAY),64,0,stream>>>(fc2_w, nullptr, nullptr, fc2_b, Wb20, s120, c20);

  k_build<<<(2*CC*HH*WW + 255)/256, 256, 0, stream>>>(x0, x1, X);
  k_pack<true><<<dim3(LL/32, BT), 256, 0, stream>>>(X, XT, stats_X);

  for (int lay = 0; lay < NLAY; ++lay){
    size_t so = (size_t)lay*SLOTF;
    const u16* WbI = WbI0 + so*2; const float* s1I = s1I0 + so; const float* cI = cI0 + so;
    const u16* WbO = WbO0 + so*2; const float* s1O = s1O0 + so; const float* cO = cO0 + so;
    const u16* Wb1 = Wb10 + so*2; const float* s11 = s110 + so; const float* c1 = c10 + so;
    const u16* Wb2 = Wb20 + so*2; const float* c2 = c20 + so;
    const float* cw  = conv_w    + (size_t)lay*CC*9;
    const float* xpw = x_proj_w  + (size_t)lay*KD*8*CC;
    const float* dw  = dt_w      + (size_t)lay*KD*CC*RR;
    const float* db  = dt_b      + (size_t)lay*KD*CC;
    const float* Al  = A_logs    + (size_t)lay*KD*CC;
    const float* Dp  = Ds        + (size_t)lay*KD*CC;

    // in_proj (LN fused): u = W' * X
    k_gmm2<true,false,true,false,false><<<dim3(BT*LL/128),256,0,stream>>>(
        WbI, XT, u, nullptr, s1I, cI, nullptr, stats_X, nullptr);
    k_dwconv_silu_t<<<dim3(8,2,BT*CC), 256, 0, stream>>>(u, v, vT, cw);
    k_xproj<<<dim3(BT*LL/256, 2), 256, 0, stream>>>(v, vT, G, xpw);
    k_scan3<<<dim3(8,768,2), 256, 0, stream>>>(G, v, vT, Y, dw, db, Al, Dp);
    k_combine4<<<dim3(8,2,BT*CC), dim3(32,8), 0, stream>>>(Y, t);
    k_pack<true><<<dim3(LL/32, BT), 256, 0, stream>>>(t, tT, stats_t);
    // out_proj (LN fused) + residual -> X (f32 + XT bf16 + stats_X)
    k_gmm2<true,true,true,true,true><<<dim3(BT*LL/128),256,0,stream>>>(
        WbO, tT, X, XT, s1O, cO, X, stats_t, stats_X);
    // fused MLP
    k_mlp<<<dim3(BT*LL/128),256,0,stream>>>(
        Wb1, Wb2, XT, X, XT, s11, c1, c2, stats_X, stats_X);
  }

  k_output<<<(unsigned)(((size_t)2*CC*HH*128 + 255)/256), 256, 0, stream>>>(X, (float*)d_out);
}

// Round 7
// 514.662 us; speedup vs baseline: 9.5120x; 1.0155x over previous
//
#include <hip/hip_runtime.h>
#include <cstdint>
#include <cstddef>

#define BT 4
#define CC 96
#define HH 64
#define WW 256
#define LL (HH*WW)    // 16384
#define KD 4
#define RR 6
#define NLAY 2
#define C4 (4*CC)     // 384
#define SLOTF 47424   // per-layer weight-slot stride in float units

typedef unsigned short u16;
typedef __attribute__((ext_vector_type(8))) short bf16x8;
typedef __attribute__((ext_vector_type(4))) float f32x4;

__device__ __forceinline__ u16 f2bf(float f){
  unsigned u = __float_as_uint(f);
  unsigned r = (u + 0x7FFFu + ((u >> 16) & 1u)) >> 16;
  return (u16)r;
}
__device__ __forceinline__ float bf2f(u16 h){
  return __uint_as_float(((unsigned)h) << 16);
}
__device__ __forceinline__ unsigned pk_bf16(float lo, float hi){
  unsigned r;
  asm volatile("v_cvt_pk_bf16_f32 %0, %1, %2" : "=v"(r) : "v"(lo), "v"(hi));
  return r;
}
// tanh-approx GELU, division-free: 0.5v(1+tanh u) = v*(1 - 1/(e^{2u}+1))
__device__ __forceinline__ float gelu_f(float v){
  float t = v*v;
  float u = v*fmaf(0.0356774081f, t, 0.7978845608f);
  float e2 = __expf(2.f*u);
  float r = __builtin_amdgcn_rcpf(e2 + 1.f);
  return fmaf(-v, r, v);
}

// ---------------- build batched input ----------------
__global__ void k_build(const float* __restrict__ x0, const float* __restrict__ x1,
                        float* __restrict__ X){
  size_t i = (size_t)blockIdx.x*256 + threadIdx.x;
  size_t tot = (size_t)2*CC*HH*WW;
  if (i >= tot) return;
  int w = i % WW; size_t r = i / WW;
  int h = r % HH; size_t bc = r / HH;
  float val;
  if (w < 128) val = x0[(bc*HH + h)*128 + w];
  else         val = x1[(bc*HH + h)*128 + (w-128)];
  X[i] = val;
  size_t ib = ((bc + (size_t)2*CC)*HH + h)*WW + (WW-1-w);
  X[ib] = val;
}

// ---------------- pack f32 [b][c][l] -> bf16T [b*LL+l][104] (+ LN stats) ----------------
template<bool ST>
__global__ __launch_bounds__(256) void k_pack(const float* __restrict__ src,
      u16* __restrict__ dst, float* __restrict__ st){
  __shared__ float tl[CC][33];
  int tid = threadIdx.x;
  int l0 = blockIdx.x*32, b = blockIdx.y;
  for (int e = tid; e < CC*32; e += 256){
    int c = e >> 5, dl = e & 31;
    tl[c][dl] = src[((size_t)b*CC + c)*LL + l0 + dl];
  }
  __syncthreads();
  if (ST && tid < 32){
    float s = 0.f, ss = 0.f;
    for (int c = 0; c < CC; ++c){ float vv = tl[c][tid]; s += vv; ss += vv*vv; }
    float mu = s*(1.f/CC);
    float var = ss*(1.f/CC) - mu*mu;
    st[(size_t)b*LL + l0 + tid] = mu;
    st[(size_t)BT*LL + (size_t)b*LL + l0 + tid] = rsqrtf(var + 1e-5f);
  }
  int dl = tid >> 3, cg = tid & 7;
  u16* dp = dst + ((size_t)b*LL + l0 + dl)*104 + cg*12;
  #pragma unroll
  for (int q = 0; q < 3; ++q){
    ushort4 pk;
    pk.x = f2bf(tl[cg*12 + q*4 + 0][dl]);
    pk.y = f2bf(tl[cg*12 + q*4 + 1][dl]);
    pk.z = f2bf(tl[cg*12 + q*4 + 2][dl]);
    pk.w = f2bf(tl[cg*12 + q*4 + 3][dl]);
    *(ushort4*)(dp + q*4) = pk;
  }
}

// ---------------- weight prep (layered via blockIdx.y) ----------------
template<int M, int K, bool LNF, bool BIAS>
__global__ void k_prepw(const float* __restrict__ W, const float* __restrict__ lnw,
      const float* __restrict__ lnb, const float* __restrict__ bias,
      u16* __restrict__ Wb, float* __restrict__ s1, float* __restrict__ cadd){
  int lay = blockIdx.y;
  W += (size_t)lay*M*K;
  Wb += (size_t)lay*SLOTF*2;
  s1 += (size_t)lay*SLOTF;
  cadd += (size_t)lay*SLOTF;
  int m = blockIdx.x*64 + threadIdx.x;
  if (m >= M) return;
  float s1v = 0.f, sbv = 0.f;
  for (int c = 0; c < K; ++c){
    float wv = W[(size_t)m*K + c];
    float wf = LNF ? wv*lnw[lay*K + c] : wv;
    u16 h = f2bf(wf);
    Wb[(size_t)m*K + c] = h;
    s1v += bf2f(h);
    if (LNF) sbv = fmaf(wv, lnb[lay*K + c], sbv);
  }
  if (BIAS) sbv += bias[lay*M + m];
  s1[m] = s1v;
  cadd[m] = sbv;
}

// ---------------- MFMA GEMM (M=96,K=96): LDS B tile, global A (L1-resident) ----------------
template<bool LNF, bool RES, bool WF32, bool WBF, bool STATS>
__global__ __launch_bounds__(256) void k_gmm2(
    const u16* __restrict__ Wb, const u16* __restrict__ inT,
    float* __restrict__ outF, u16* __restrict__ outT,
    const float* __restrict__ s1v, const float* __restrict__ cadd,
    const float* __restrict__ res,
    const float* __restrict__ stI, float* __restrict__ stO){
  __shared__ u16 bt[128*104];
  int tid = threadIdx.x, lane = tid & 63, wid = tid >> 6;
  int l0 = blockIdx.x*128;
  int lr = lane & 15, lg = lane >> 4;
  const int4* bsrc = (const int4*)(inT + (size_t)l0*104);
  for (int i = tid; i < 1664; i += 256) ((int4*)bt)[i] = bsrc[i];
  __syncthreads();
  f32x4 acc[6][2];
  #pragma unroll
  for (int mf = 0; mf < 6; ++mf){ acc[mf][0] = (f32x4){0,0,0,0}; acc[mf][1] = (f32x4){0,0,0,0}; }
  #pragma unroll
  for (int ks = 0; ks < 3; ++ks){
    bf16x8 af[6];
    #pragma unroll
    for (int mf = 0; mf < 6; ++mf)
      af[mf] = *(const bf16x8*)(Wb + (size_t)(mf*16 + lr)*96 + ks*32 + lg*8);
    bf16x8 bfr[2];
    #pragma unroll
    for (int ls = 0; ls < 2; ++ls)
      bfr[ls] = *(const bf16x8*)&bt[(wid*32 + ls*16 + lr)*104 + ks*32 + lg*8];
    #pragma unroll
    for (int mf = 0; mf < 6; ++mf)
      #pragma unroll
      for (int ls = 0; ls < 2; ++ls)
        acc[mf][ls] = __builtin_amdgcn_mfma_f32_16x16x32_bf16(af[mf], bfr[ls], acc[mf][ls], 0, 0, 0);
  }
  #pragma unroll
  for (int ls = 0; ls < 2; ++ls){
    int l = l0 + wid*32 + ls*16 + lr;
    int b = l >> 14, lb = l & (LL-1);
    float mu = 0.f, rs = 0.f;
    if (LNF){ mu = stI[l]; rs = stI[(size_t)BT*LL + l]; }
    float ssum = 0.f, ssq = 0.f;
    #pragma unroll
    for (int mf = 0; mf < 6; ++mf){
      float o[4];
      #pragma unroll
      for (int r = 0; r < 4; ++r){
        int mm = mf*16 + lg*4 + r;
        float vv = acc[mf][ls][r];
        if (LNF) vv = fmaf(rs, vv, fmaf(-mu*rs, s1v[mm], cadd[mm]));
        else     vv += cadd[mm];
        if (RES) vv += res[((size_t)b*96 + mm)*LL + lb];
        if (WF32) outF[((size_t)b*96 + mm)*LL + lb] = vv;
        if (STATS){ ssum += vv; ssq += vv*vv; }
        o[r] = vv;
      }
      if (WBF){
        ushort4 pk;
        pk.x = f2bf(o[0]); pk.y = f2bf(o[1]); pk.z = f2bf(o[2]); pk.w = f2bf(o[3]);
        *(ushort4*)(outT + (size_t)l*104 + mf*16 + lg*4) = pk;
      }
    }
    if (STATS){
      ssum += __shfl_xor(ssum, 16); ssq += __shfl_xor(ssq, 16);
      ssum += __shfl_xor(ssum, 32); ssq += __shfl_xor(ssq, 32);
      if (lane < 16){
        float mu2 = ssum*(1.f/CC);
        float var = ssq*(1.f/CC) - mu2*mu2;
        stO[l] = mu2;
        stO[(size_t)BT*LL + l] = rsqrtf(var + 1e-5f);
      }
    }
  }
}

// ---------------- fused MLP v3: 8 waves/block, 16 px/wave, LDS hidden relayout ----------------
__global__ __launch_bounds__(512, 4) void k_mlp(
    const u16* __restrict__ Wb1, const u16* __restrict__ Wb2,
    const u16* __restrict__ XT, float* __restrict__ X, u16* __restrict__ XTout,
    const float* __restrict__ s11, const float* __restrict__ c1,
    const float* __restrict__ c2,
    const float* __restrict__ stI, float* __restrict__ stO){
  __shared__ u16 bt[128*104];
  __shared__ u16 hs[128*104];
  int tid = threadIdx.x, lane = tid & 63, wid = tid >> 6;   // wid 0..7
  int l0 = blockIdx.x*128;
  int lr = lane & 15, lg = lane >> 4;
  const int4* bsrc = (const int4*)(XT + (size_t)l0*104);
  for (int i = tid; i < 1664; i += 512) ((int4*)bt)[i] = bsrc[i];

  int l = l0 + wid*16 + lr;                    // this lane's pixel
  float mu = stI[l];
  float rs = stI[(size_t)BT*LL + l];
  float nmr = -mu*rs;
  __syncthreads();

  int hrow = (wid*16 + lr)*104;
  f32x4 acc2[6];
  #pragma unroll
  for (int mf = 0; mf < 6; ++mf) acc2[mf] = (f32x4){0,0,0,0};

  for (int cc = 0; cc < 4; ++cc){
    // fc1 chunk (96 hidden rows) over K=96
    f32x4 acc1[6];
    #pragma unroll
    for (int mf = 0; mf < 6; ++mf) acc1[mf] = (f32x4){0,0,0,0};
    #pragma unroll
    for (int ks = 0; ks < 3; ++ks){
      bf16x8 af[6];
      #pragma unroll
      for (int mf = 0; mf < 6; ++mf)
        af[mf] = *(const bf16x8*)(Wb1 + (size_t)(cc*96 + mf*16 + lr)*96 + ks*32 + lg*8);
      bf16x8 bfr = *(const bf16x8*)&bt[hrow + ks*32 + lg*8];
      #pragma unroll
      for (int mf = 0; mf < 6; ++mf)
        acc1[mf] = __builtin_amdgcn_mfma_f32_16x16x32_bf16(af[mf], bfr, acc1[mf], 0, 0, 0);
    }
    // LN-affine + GELU + bf16-pack -> hs (own wave's 16-px stripe; no barrier needed)
    #pragma unroll
    for (int mf = 0; mf < 6; ++mf){
      float4 sv = *(const float4*)&s11[cc*96 + mf*16 + lg*4];
      float4 cv = *(const float4*)&c1 [cc*96 + mf*16 + lg*4];
      float g0 = gelu_f(fmaf(rs, acc1[mf][0], fmaf(nmr, sv.x, cv.x)));
      float g1 = gelu_f(fmaf(rs, acc1[mf][1], fmaf(nmr, sv.y, cv.y)));
      float g2 = gelu_f(fmaf(rs, acc1[mf][2], fmaf(nmr, sv.z, cv.z)));
      float g3 = gelu_f(fmaf(rs, acc1[mf][3], fmaf(nmr, sv.w, cv.w)));
      uint2 pw;
      pw.x = pk_bf16(g0, g1);
      pw.y = pk_bf16(g2, g3);
      *(uint2*)&hs[hrow + mf*16 + lg*4] = pw;
    }
    // fc2 partial over this 96-chunk
    #pragma unroll
    for (int ks = 0; ks < 3; ++ks){
      bf16x8 a2[6];
      #pragma unroll
      for (int mf2 = 0; mf2 < 6; ++mf2)
        a2[mf2] = *(const bf16x8*)(Wb2 + (size_t)(mf2*16 + lr)*384 + cc*96 + ks*32 + lg*8);
      bf16x8 bfr2 = *(const bf16x8*)&hs[hrow + ks*32 + lg*8];
      #pragma unroll
      for (int mf2 = 0; mf2 < 6; ++mf2)
        acc2[mf2] = __builtin_amdgcn_mfma_f32_16x16x32_bf16(a2[mf2], bfr2, acc2[mf2], 0, 0, 0);
    }
  }
  // epilogue: + c2 + residual -> X f32, XT bf16, stats
  {
    int b = l >> 14, lb = l & (LL-1);
    float ssum = 0.f, ssq = 0.f;
    #pragma unroll
    for (int mf = 0; mf < 6; ++mf){
      float o[4];
      #pragma unroll
      for (int r = 0; r < 4; ++r){
        int mm = mf*16 + lg*4 + r;
        float vv = acc2[mf][r] + c2[mm];
        vv += X[((size_t)b*96 + mm)*LL + lb];
        X[((size_t)b*96 + mm)*LL + lb] = vv;
        ssum += vv; ssq += vv*vv;
        o[r] = vv;
      }
      ushort4 pk;
      pk.x = f2bf(o[0]); pk.y = f2bf(o[1]); pk.z = f2bf(o[2]); pk.w = f2bf(o[3]);
      *(ushort4*)(XTout + (size_t)l*104 + mf*16 + lg*4) = pk;
    }
    ssum += __shfl_xor(ssum, 16); ssq += __shfl_xor(ssq, 16);
    ssum += __shfl_xor(ssum, 32); ssq += __shfl_xor(ssq, 32);
    if (lane < 16){
      float mu2 = ssum*(1.f/CC);
      float var = ssq*(1.f/CC) - mu2*mu2;
      stO[l] = mu2;
      stO[(size_t)BT*LL + l] = rsqrtf(var + 1e-5f);
    }
  }
}

// ---------------- depthwise 3x3 + SiLU, fused transpose (writes v and vT) ----------------
__global__ __launch_bounds__(256) void k_dwconv_silu_t(const float* __restrict__ u,
      float* __restrict__ v, float* __restrict__ vT, const float* __restrict__ cw){
  __shared__ float tl[32][33];
  int bc = blockIdx.z;
  int c = bc % CC;
  int w0 = blockIdx.x*32, h0 = blockIdx.y*32;
  const float* up = u + (size_t)bc*LL;
  const float* k9 = cw + c*9;
  int t = threadIdx.x;
  int wl = (t & 7)*4, hl = t >> 3;
  int h = h0 + hl, w = w0 + wl;
  float acc[4] = {0.f,0.f,0.f,0.f};
  #pragma unroll
  for (int dh = -1; dh <= 1; ++dh){
    int h2 = h + dh;
    if (h2 < 0 || h2 >= HH) continue;
    const float* row = up + (size_t)h2*WW + w;
    float4 m = *(const float4*)row;
    float lft = (w > 0) ? row[-1] : 0.f;
    float rgt = (w + 4 < WW) ? row[4] : 0.f;
    float k0 = k9[(dh+1)*3], k1 = k9[(dh+1)*3+1], k2 = k9[(dh+1)*3+2];
    acc[0] += lft*k0 + m.x*k1 + m.y*k2;
    acc[1] += m.x*k0 + m.y*k1 + m.z*k2;
    acc[2] += m.y*k0 + m.z*k1 + m.w*k2;
    acc[3] += m.z*k0 + m.w*k1 + rgt*k2;
  }
  float4 ov;
  float* po = (float*)&ov;
  #pragma unroll
  for (int j = 0; j < 4; ++j){
    float a = acc[j];
    float e = __expf(-a);
    float s = a * __builtin_amdgcn_rcpf(1.f + e);
    po[j] = s;
    tl[wl + j][hl] = s;
  }
  *(float4*)&v[(size_t)bc*LL + (size_t)h*WW + w] = ov;
  __syncthreads();
  int ww = t >> 3, hh4 = (t & 7)*4;
  float4 o2 = make_float4(tl[ww][hh4], tl[ww][hh4+1], tl[ww][hh4+2], tl[ww][hh4+3]);
  *(float4*)&vT[(size_t)bc*LL + (size_t)(w0 + ww)*HH + h0 + hh4] = o2;
}

// ---------------- x-projection (both sources in one launch) ----------------
__global__ void k_xproj(const float* __restrict__ v, const float* __restrict__ vT,
                        float* __restrict__ G, const float* __restrict__ xpw){
  int which = blockIdx.y;
  const float* src = which ? vT : v;
  int kA = which ? 1 : 0, kB = which ? 3 : 2;
  size_t i = (size_t)blockIdx.x*256 + threadIdx.x;
  if (i >= (size_t)BT*LL) return;
  int b = (int)(i / LL), l = (int)(i % LL);
  const float* sp = src + (size_t)b*CC*LL + l;
  const float* wA = xpw + (size_t)kA*8*CC;
  const float* wB = xpw + (size_t)kB*8*CC;
  float aA[8], aB[8];
  #pragma unroll
  for (int d = 0; d < 8; ++d){ aA[d] = 0.f; aB[d] = 0.f; }
  for (int c = 0; c < CC; ++c){
    float xv = sp[(size_t)c*LL];
    #pragma unroll
    for (int d = 0; d < 8; ++d){
      aA[d] = fmaf(wA[d*CC + c], xv, aA[d]);
      aB[d] = fmaf(wB[d*CC + c], xv, aB[d]);
    }
  }
  float* gA = G + (((size_t)b*KD + kA)*8)*LL + l;
  float* gB = G + (((size_t)b*KD + kB)*8)*LL + l;
  #pragma unroll
  for (int d = 0; d < 8; ++d){ gA[(size_t)d*LL] = aA[d]; gB[(size_t)d*LL] = aB[d]; }
}

// ---------------- tile-parallel selective scan (fwd+rev in one launch) ----------------
__device__ __forceinline__ void ld4(const float* p, float* o){
  float4 t = *(const float4*)p; o[0]=t.x; o[1]=t.y; o[2]=t.z; o[3]=t.w;
}
__device__ __forceinline__ void rev4(float* a){
  float t0 = a[0]; a[0] = a[3]; a[3] = t0;
  float t1 = a[1]; a[1] = a[2]; a[2] = t1;
}

__global__ __launch_bounds__(256) void k_scan3(const float* __restrict__ G,
                       const float* __restrict__ v, const float* __restrict__ vT,
                       float* __restrict__ Y,
                       const float* __restrict__ dtw_, const float* __restrict__ dtb_,
                       const float* __restrict__ Alog_, const float* __restrict__ Ds_){
  const size_t SZ = (size_t)BT*CC*LL;
  int wid = threadIdx.x >> 6, lane = threadIdx.x & 63;
  int tile = blockIdx.x*4 + wid;
  int sy = blockIdx.y;
  bool rev = (blockIdx.z != 0);
  int c = sy % CC; int t2 = sy / CC; int kk = t2 & 1; int b = t2 >> 1;
  int k = (rev ? 2 : 0) + kk;
  const float* src = (kk ? vT : v) + ((size_t)b*CC + c)*LL;
  const float* g = G + (((size_t)b*KD + k)*8)*LL;
  float dtw[RR];
  #pragma unroll
  for (int r = 0; r < RR; ++r) dtw[r] = dtw_[((size_t)k*CC + c)*RR + r];
  float dtb = dtb_[k*CC + c];
  float A  = -__expf(Alog_[k*CC + c]);
  float Dv = Ds_[k*CC + c];
  float* yout = Y + (size_t)k*SZ + ((size_t)b*CC + c)*LL;

  int lstore0 = tile*512;
  float carry = 0.f;
  for (int p = 0; p < 3; ++p){
    int base = lstore0 - 256 + p*256;
    if (base < 0) continue;
    int l = base + (lane<<2);
    int ga = rev ? (LL-4-l) : l;
    float r0[4], r1[4], r2[4], r3[4], r4[4], r5[4], g6b[4], g7b[4], xb[4];
    ld4(g + 0*(size_t)LL + ga, r0);
    ld4(g + 1*(size_t)LL + ga, r1);
    ld4(g + 2*(size_t)LL + ga, r2);
    ld4(g + 3*(size_t)LL + ga, r3);
    ld4(g + 4*(size_t)LL + ga, r4);
    ld4(g + 5*(size_t)LL + ga, r5);
    ld4(g + 6*(size_t)LL + ga, g6b);
    ld4(g + 7*(size_t)LL + ga, g7b);
    ld4(src + ga, xb);
    if (rev){
      rev4(r0); rev4(r1); rev4(r2); rev4(r3); rev4(r4); rev4(r5);
      rev4(g6b); rev4(g7b); rev4(xb);
    }
    float av[4], bt[4];
    #pragma unroll
    for (int i = 0; i < 4; ++i){
      float dsum = dtb;
      dsum = fmaf(r0[i], dtw[0], dsum);
      dsum = fmaf(r1[i], dtw[1], dsum);
      dsum = fmaf(r2[i], dtw[2], dsum);
      dsum = fmaf(r3[i], dtw[3], dsum);
      dsum = fmaf(r4[i], dtw[4], dsum);
      dsum = fmaf(r5[i], dtw[5], dsum);
      float sp = __logf(1.f + __expf(dsum));
      float delta = (dsum > 20.f) ? dsum : sp;
      av[i] = __expf(delta * A);
      bt[i] = delta * g6b[i] * xb[i];
    }
    float P = av[0], Q = bt[0];
    #pragma unroll
    for (int i = 1; i < 4; ++i){ Q = fmaf(av[i], Q, bt[i]); P *= av[i]; }
    #pragma unroll
    for (int off = 1; off < 64; off <<= 1){
      float Pp = __shfl_up(P, (unsigned)off);
      float Qp = __shfl_up(Q, (unsigned)off);
      if (lane >= off){ Q = fmaf(P, Qp, Q); P *= Pp; }
    }
    float Pe = __shfl_up(P, 1u), Qe = __shfl_up(Q, 1u);
    if (lane == 0){ Pe = 1.f; Qe = 0.f; }
    float h = fmaf(Pe, carry, Qe);
    float ys[4];
    #pragma unroll
    for (int i = 0; i < 4; ++i){
      h = fmaf(av[i], h, bt[i]);
      ys[i] = fmaf(g7b[i], h, Dv*xb[i]);
    }
    carry = __shfl(h, 63);
    if (p > 0){
      if (rev) rev4(ys);
      *(float4*)&yout[ga] = make_float4(ys[0], ys[1], ys[2], ys[3]);
    }
  }
}

// ---------------- combine: z = (y0+y2) + transpose(y1+y3) ----------------
__global__ void k_combine4(const float* __restrict__ Y, float* __restrict__ z){
  const size_t SZ = (size_t)BT*CC*LL;
  __shared__ float tile[32][33];
  int bc = blockIdx.z;
  const float* y1p = Y + SZ   + (size_t)bc*LL;
  const float* y3p = Y + 3*SZ + (size_t)bc*LL;
  int w0 = blockIdx.x*32, h0 = blockIdx.y*32;
  int tx = threadIdx.x, ty = threadIdx.y;
  #pragma unroll
  for (int kk = 0; kk < 4; ++kk){
    int w = w0 + ty + kk*8;
    size_t idx = (size_t)w*HH + h0 + tx;
    tile[ty + kk*8][tx] = y1p[idx] + y3p[idx];
  }
  __syncthreads();
  const float* y0p = Y +        (size_t)bc*LL;
  const float* y2p = Y + 2*SZ + (size_t)bc*LL;
  float* zp = z + (size_t)bc*LL;
  #pragma unroll
  for (int kk = 0; kk < 4; ++kk){
    int h = h0 + ty + kk*8;
    size_t idx = (size_t)h*WW + w0 + tx;
    zp[idx] = y0p[idx] + y2p[idx] + tile[tx][ty + kk*8];
  }
}

// ---------------- final output split/average ----------------
__global__ void k_output(const float* __restrict__ X, float* __restrict__ out){
  size_t i = (size_t)blockIdx.x*256 + threadIdx.x;
  size_t half = (size_t)2*CC*HH*128;
  if (i >= half) return;
  int w = i % 128; size_t r = i / 128;
  int h = r % HH; size_t bc = r / HH;
  size_t fwd = (bc*HH + h)*WW;
  size_t bwd = ((bc + (size_t)2*CC)*HH + h)*WW;
  out[i]        = 0.5f*(X[fwd + w]       + X[bwd + (WW-1-w)]);
  out[half + i] = 0.5f*(X[fwd + 128 + w] + X[bwd + (127 - w)]);
}

extern "C" void kernel_launch(void* const* d_in, const int* in_sizes, int n_in,
                              void* d_out, int out_size, void* d_ws, size_t ws_size,
                              hipStream_t stream){
  const float* x0        = (const float*)d_in[0];
  const float* x1        = (const float*)d_in[1];
  const float* norm_w    = (const float*)d_in[2];
  const float* norm_b    = (const float*)d_in[3];
  const float* in_proj_w = (const float*)d_in[4];
  const float* conv_w    = (const float*)d_in[5];
  const float* x_proj_w  = (const float*)d_in[6];
  const float* dt_w      = (const float*)d_in[7];
  const float* dt_b      = (const float*)d_in[8];
  const float* A_logs    = (const float*)d_in[9];
  const float* Ds        = (const float*)d_in[10];
  const float* out_norm_w= (const float*)d_in[11];
  const float* out_norm_b= (const float*)d_in[12];
  const float* out_proj_w= (const float*)d_in[13];
  const float* norm2_w   = (const float*)d_in[14];
  const float* norm2_b   = (const float*)d_in[15];
  const float* fc1_w     = (const float*)d_in[16];
  const float* fc1_b     = (const float*)d_in[17];
  const float* fc2_w     = (const float*)d_in[18];
  const float* fc2_b     = (const float*)d_in[19];

  const size_t SZ = (size_t)BT*CC*LL;            // 6,291,456 floats
  float* X  = (float*)d_ws;
  float* t  = X + SZ;
  float* u  = t + SZ;
  float* G  = u + SZ;                            // BT*KD*8*LL floats
  float* v  = G + (size_t)BT*KD*8*LL;
  float* vT = v + SZ;
  float* Y  = vT + SZ;                           // 4 contiguous SZ buffers
  u16*   XT  = (u16*)Y;                          // bf16T [BT*LL][104] (phase-disjoint w/ Y0)
  u16*   tT  = (u16*)u;                          // bf16T of t (u dead by then)
  float* ext = Y + 4*SZ;
  float* stats_X = ext;                          // 2*BT*LL
  float* stats_t = stats_X + 2*(size_t)BT*LL;
  float* wsl     = stats_t + 2*(size_t)BT*LL;    // weight slots: NLAY * SLOTF floats

  float* p0 = wsl;
  u16*  WbI0 = (u16*)p0;          float* s1I0 = p0 + 4608;  float* cI0 = p0 + 4704;
  u16*  WbO0 = (u16*)(p0+4800);   float* s1O0 = p0 + 9408;  float* cO0 = p0 + 9504;
  u16*  Wb10 = (u16*)(p0+9600);   float* s110 = p0 + 28032; float* c10 = p0 + 28416;
  u16*  Wb20 = (u16*)(p0+28800);  float* s120 = p0 + 47232; float* c20 = p0 + 47328;

  k_prepw<96,96,true,false><<<dim3(2,NLAY),64,0,stream>>>(in_proj_w, norm_w, norm_b, nullptr, WbI0, s1I0, cI0);
  k_prepw<96,96,true,false><<<dim3(2,NLAY),64,0,stream>>>(out_proj_w, out_norm_w, out_norm_b, nullptr, WbO0, s1O0, cO0);
  k_prepw<384,96,true,true><<<dim3(6,NLAY),64,0,stream>>>(fc1_w, norm2_w, norm2_b, fc1_b, Wb10, s110, c10);
  k_prepw<96,384,false,true><<<dim3(2,NLAY),64,0,stream>>>(fc2_w, nullptr, nullptr, fc2_b, Wb20, s120, c20);

  k_build<<<(2*CC*HH*WW + 255)/256, 256, 0, stream>>>(x0, x1, X);
  k_pack<true><<<dim3(LL/32, BT), 256, 0, stream>>>(X, XT, stats_X);

  for (int lay = 0; lay < NLAY; ++lay){
    size_t so = (size_t)lay*SLOTF;
    const u16* WbI = WbI0 + so*2; const float* s1I = s1I0 + so; const float* cI = cI0 + so;
    const u16* WbO = WbO0 + so*2; const float* s1O = s1O0 + so; const float* cO = cO0 + so;
    const u16* Wb1 = Wb10 + so*2; const float* s11 = s110 + so; const float* c1 = c10 + so;
    const u16* Wb2 = Wb20 + so*2; const float* c2 = c20 + so;
    const float* cw  = conv_w    + (size_t)lay*CC*9;
    const float* xpw = x_proj_w  + (size_t)lay*KD*8*CC;
    const float* dw  = dt_w      + (size_t)lay*KD*CC*RR;
    const float* db  = dt_b      + (size_t)lay*KD*CC;
    const float* Al  = A_logs    + (size_t)lay*KD*CC;
    const float* Dp  = Ds        + (size_t)lay*KD*CC;

    // in_proj (LN fused): u = W' * X
    k_gmm2<true,false,true,false,false><<<dim3(BT*LL/128),256,0,stream>>>(
        WbI, XT, u, nullptr, s1I, cI, nullptr, stats_X, nullptr);
    k_dwconv_silu_t<<<dim3(8,2,BT*CC), 256, 0, stream>>>(u, v, vT, cw);
    k_xproj<<<dim3(BT*LL/256, 2), 256, 0, stream>>>(v, vT, G, xpw);
    k_scan3<<<dim3(8,768,2), 256, 0, stream>>>(G, v, vT, Y, dw, db, Al, Dp);
    k_combine4<<<dim3(8,2,BT*CC), dim3(32,8), 0, stream>>>(Y, t);
    k_pack<true><<<dim3(LL/32, BT), 256, 0, stream>>>(t, tT, stats_t);
    // out_proj (LN fused) + residual -> X (f32 + XT bf16 + stats_X)
    k_gmm2<true,true,true,true,true><<<dim3(BT*LL/128),256,0,stream>>>(
        WbO, tT, X, XT, s1O, cO, X, stats_t, stats_X);
    // fused MLP
    k_mlp<<<dim3(BT*LL/128),512,0,stream>>>(
        Wb1, Wb2, XT, X, XT, s11, c1, c2, stats_X, stats_X);
  }

  k_output<<<(unsigned)(((size_t)2*CC*HH*128 + 255)/256), 256, 0, stream>>>(X, (float*)d_out);
}

// Round 8
// 469.550 us; speedup vs baseline: 10.4259x; 1.0961x over previous
//
#include <hip/hip_runtime.h>
#include <cstdint>
#include <cstddef>

#define BT 4
#define CC 96
#define HH 64
#define WW 256
#define LL (HH*WW)    // 16384
#define KD 4
#define RR 6
#define NLAY 2
#define C4 (4*CC)     // 384
#define SLOTF 47424   // per-layer weight-slot stride in float units

typedef unsigned short u16;
typedef __attribute__((ext_vector_type(8))) short bf16x8;
typedef __attribute__((ext_vector_type(4))) float f32x4;

__device__ __forceinline__ u16 f2bf(float f){
  unsigned u = __float_as_uint(f);
  unsigned r = (u + 0x7FFFu + ((u >> 16) & 1u)) >> 16;
  return (u16)r;
}
__device__ __forceinline__ float bf2f(u16 h){
  return __uint_as_float(((unsigned)h) << 16);
}
__device__ __forceinline__ unsigned pk_bf16(float lo, float hi){
  unsigned r;
  asm volatile("v_cvt_pk_bf16_f32 %0, %1, %2" : "=v"(r) : "v"(lo), "v"(hi));
  return r;
}
// tanh-approx GELU, division-free: 0.5v(1+tanh u) = v*(1 - 1/(e^{2u}+1))
__device__ __forceinline__ float gelu_f(float v){
  float t = v*v;
  float u = v*fmaf(0.0356774081f, t, 0.7978845608f);
  float e2 = __expf(2.f*u);
  float r = __builtin_amdgcn_rcpf(e2 + 1.f);
  return fmaf(-v, r, v);
}

// ---------------- build batched input ----------------
__global__ void k_build(const float* __restrict__ x0, const float* __restrict__ x1,
                        float* __restrict__ X){
  size_t i = (size_t)blockIdx.x*256 + threadIdx.x;
  size_t tot = (size_t)2*CC*HH*WW;
  if (i >= tot) return;
  int w = i % WW; size_t r = i / WW;
  int h = r % HH; size_t bc = r / HH;
  float val;
  if (w < 128) val = x0[(bc*HH + h)*128 + w];
  else         val = x1[(bc*HH + h)*128 + (w-128)];
  X[i] = val;
  size_t ib = ((bc + (size_t)2*CC)*HH + h)*WW + (WW-1-w);
  X[ib] = val;
}

// ---------------- pack f32 [b][c][l] -> bf16T [b*LL+l][104] (+ LN stats) ----------------
template<bool ST>
__global__ __launch_bounds__(256) void k_pack(const float* __restrict__ src,
      u16* __restrict__ dst, float* __restrict__ st){
  __shared__ float tl[CC][33];
  int tid = threadIdx.x;
  int l0 = blockIdx.x*32, b = blockIdx.y;
  for (int e = tid; e < CC*32; e += 256){
    int c = e >> 5, dl = e & 31;
    tl[c][dl] = src[((size_t)b*CC + c)*LL + l0 + dl];
  }
  __syncthreads();
  if (ST && tid < 32){
    float s = 0.f, ss = 0.f;
    for (int c = 0; c < CC; ++c){ float vv = tl[c][tid]; s += vv; ss += vv*vv; }
    float mu = s*(1.f/CC);
    float var = ss*(1.f/CC) - mu*mu;
    st[(size_t)b*LL + l0 + tid] = mu;
    st[(size_t)BT*LL + (size_t)b*LL + l0 + tid] = rsqrtf(var + 1e-5f);
  }
  int dl = tid >> 3, cg = tid & 7;
  u16* dp = dst + ((size_t)b*LL + l0 + dl)*104 + cg*12;
  #pragma unroll
  for (int q = 0; q < 3; ++q){
    ushort4 pk;
    pk.x = f2bf(tl[cg*12 + q*4 + 0][dl]);
    pk.y = f2bf(tl[cg*12 + q*4 + 1][dl]);
    pk.z = f2bf(tl[cg*12 + q*4 + 2][dl]);
    pk.w = f2bf(tl[cg*12 + q*4 + 3][dl]);
    *(ushort4*)(dp + q*4) = pk;
  }
}

// ---------------- weight prep: swizzle into MFMA-fragment order ----------------
// fragment f stores 64 lanes x 8 u16 contiguous (1KB). lane = lg*16+lr.
// element (m,c): rowfrag=m>>4, lr=m&15, colfrag=c>>5, lg=(c>>3)&3, j=c&7.
// order: FC1ORD ? f=(rowfrag/6)*18 + colfrag*6 + rowfrag%6  (fc1: cc outer)
//               : f=colfrag*(M/16) + rowfrag                 (proj/fc2: k outer)
template<int M, int K, bool FC1ORD, bool LNF, bool BIAS>
__global__ void k_prepw(const float* __restrict__ W, const float* __restrict__ lnw,
      const float* __restrict__ lnb, const float* __restrict__ bias,
      u16* __restrict__ Wb, float* __restrict__ s1, float* __restrict__ cadd){
  int lay = blockIdx.y;
  W += (size_t)lay*M*K;
  Wb += (size_t)lay*SLOTF*2;
  s1 += (size_t)lay*SLOTF;
  cadd += (size_t)lay*SLOTF;
  int m = blockIdx.x*64 + threadIdx.x;
  if (m >= M) return;
  int rowfrag = m >> 4, lr = m & 15;
  float s1v = 0.f, sbv = 0.f;
  for (int c = 0; c < K; ++c){
    float wv = W[(size_t)m*K + c];
    float wf = LNF ? wv*lnw[lay*K + c] : wv;
    u16 h = f2bf(wf);
    int colfrag = c >> 5, lg = (c >> 3) & 3, j = c & 7;
    int f;
    if (FC1ORD) f = (rowfrag/6)*18 + colfrag*6 + (rowfrag % 6);
    else        f = colfrag*(M/16) + rowfrag;
    Wb[(size_t)(f*64 + lg*16 + lr)*8 + j] = h;
    s1v += bf2f(h);
    if (LNF) sbv = fmaf(wv, lnb[lay*K + c], sbv);
  }
  if (BIAS) sbv += bias[lay*M + m];
  s1[m] = s1v;
  cadd[m] = sbv;
}

// ---------------- MFMA GEMM (M=96,K=96): LDS B tile, coalesced swizzled weights ----------------
template<bool LNF, bool RES, bool WF32, bool WBF, bool STATS>
__global__ __launch_bounds__(256) void k_gmm2(
    const u16* __restrict__ Wb, const u16* __restrict__ inT,
    float* __restrict__ outF, u16* __restrict__ outT,
    const float* __restrict__ s1v, const float* __restrict__ cadd,
    const float* __restrict__ res,
    const float* __restrict__ stI, float* __restrict__ stO){
  __shared__ u16 bt[128*104];
  int tid = threadIdx.x, lane = tid & 63, wid = tid >> 6;
  int l0 = blockIdx.x*128;
  int lr = lane & 15, lg = lane >> 4;
  const int4* bsrc = (const int4*)(inT + (size_t)l0*104);
  for (int i = tid; i < 1664; i += 256) ((int4*)bt)[i] = bsrc[i];
  __syncthreads();
  f32x4 acc[6][2];
  #pragma unroll
  for (int mf = 0; mf < 6; ++mf){ acc[mf][0] = (f32x4){0,0,0,0}; acc[mf][1] = (f32x4){0,0,0,0}; }
  #pragma unroll
  for (int ks = 0; ks < 3; ++ks){
    bf16x8 af[6];
    #pragma unroll
    for (int mf = 0; mf < 6; ++mf)
      af[mf] = *(const bf16x8*)(Wb + (size_t)((ks*6 + mf)*64 + lane)*8);
    bf16x8 bfr[2];
    #pragma unroll
    for (int ls = 0; ls < 2; ++ls)
      bfr[ls] = *(const bf16x8*)&bt[(wid*32 + ls*16 + lr)*104 + ks*32 + lg*8];
    #pragma unroll
    for (int mf = 0; mf < 6; ++mf)
      #pragma unroll
      for (int ls = 0; ls < 2; ++ls)
        acc[mf][ls] = __builtin_amdgcn_mfma_f32_16x16x32_bf16(af[mf], bfr[ls], acc[mf][ls], 0, 0, 0);
  }
  #pragma unroll
  for (int ls = 0; ls < 2; ++ls){
    int l = l0 + wid*32 + ls*16 + lr;
    int b = l >> 14, lb = l & (LL-1);
    float mu = 0.f, rs = 0.f;
    if (LNF){ mu = stI[l]; rs = stI[(size_t)BT*LL + l]; }
    float ssum = 0.f, ssq = 0.f;
    #pragma unroll
    for (int mf = 0; mf < 6; ++mf){
      float o[4];
      #pragma unroll
      for (int r = 0; r < 4; ++r){
        int mm = mf*16 + lg*4 + r;
        float vv = acc[mf][ls][r];
        if (LNF) vv = fmaf(rs, vv, fmaf(-mu*rs, s1v[mm], cadd[mm]));
        else     vv += cadd[mm];
        if (RES) vv += res[((size_t)b*96 + mm)*LL + lb];
        if (WF32) outF[((size_t)b*96 + mm)*LL + lb] = vv;
        if (STATS){ ssum += vv; ssq += vv*vv; }
        o[r] = vv;
      }
      if (WBF){
        ushort4 pk;
        pk.x = f2bf(o[0]); pk.y = f2bf(o[1]); pk.z = f2bf(o[2]); pk.w = f2bf(o[3]);
        *(ushort4*)(outT + (size_t)l*104 + mf*16 + lg*4) = pk;
      }
    }
    if (STATS){
      ssum += __shfl_xor(ssum, 16); ssq += __shfl_xor(ssq, 16);
      ssum += __shfl_xor(ssum, 32); ssq += __shfl_xor(ssq, 32);
      if (lane < 16){
        float mu2 = ssum*(1.f/CC);
        float var = ssq*(1.f/CC) - mu2*mu2;
        stO[l] = mu2;
        stO[(size_t)BT*LL + l] = rsqrtf(var + 1e-5f);
      }
    }
  }
}

// ---------------- fused MLP v4: 8 waves/block, coalesced swizzled weights ----------------
__global__ __launch_bounds__(512, 4) void k_mlp(
    const u16* __restrict__ Wb1, const u16* __restrict__ Wb2,
    const u16* __restrict__ XT, float* __restrict__ X, u16* __restrict__ XTout,
    const float* __restrict__ s11, const float* __restrict__ c1,
    const float* __restrict__ c2,
    const float* __restrict__ stI, float* __restrict__ stO){
  __shared__ u16 bt[128*104];
  __shared__ u16 hs[128*104];
  int tid = threadIdx.x, lane = tid & 63, wid = tid >> 6;   // wid 0..7
  int l0 = blockIdx.x*128;
  int lr = lane & 15, lg = lane >> 4;
  const int4* bsrc = (const int4*)(XT + (size_t)l0*104);
  for (int i = tid; i < 1664; i += 512) ((int4*)bt)[i] = bsrc[i];

  int l = l0 + wid*16 + lr;                    // this lane's pixel
  float mu = stI[l];
  float rs = stI[(size_t)BT*LL + l];
  float nmr = -mu*rs;
  __syncthreads();

  int hrow = (wid*16 + lr)*104;
  f32x4 acc2[6];
  #pragma unroll
  for (int mf = 0; mf < 6; ++mf) acc2[mf] = (f32x4){0,0,0,0};

  for (int cc = 0; cc < 4; ++cc){
    // fc1 chunk (96 hidden rows) over K=96
    f32x4 acc1[6];
    #pragma unroll
    for (int mf = 0; mf < 6; ++mf) acc1[mf] = (f32x4){0,0,0,0};
    #pragma unroll
    for (int ks = 0; ks < 3; ++ks){
      bf16x8 af[6];
      #pragma unroll
      for (int mf = 0; mf < 6; ++mf)
        af[mf] = *(const bf16x8*)(Wb1 + (size_t)((cc*18 + ks*6 + mf)*64 + lane)*8);
      bf16x8 bfr = *(const bf16x8*)&bt[hrow + ks*32 + lg*8];
      #pragma unroll
      for (int mf = 0; mf < 6; ++mf)
        acc1[mf] = __builtin_amdgcn_mfma_f32_16x16x32_bf16(af[mf], bfr, acc1[mf], 0, 0, 0);
    }
    // LN-affine + GELU + bf16-pack -> hs (own wave's 16-px stripe; no barrier needed)
    #pragma unroll
    for (int mf = 0; mf < 6; ++mf){
      float4 sv = *(const float4*)&s11[cc*96 + mf*16 + lg*4];
      float4 cv = *(const float4*)&c1 [cc*96 + mf*16 + lg*4];
      float g0 = gelu_f(fmaf(rs, acc1[mf][0], fmaf(nmr, sv.x, cv.x)));
      float g1 = gelu_f(fmaf(rs, acc1[mf][1], fmaf(nmr, sv.y, cv.y)));
      float g2 = gelu_f(fmaf(rs, acc1[mf][2], fmaf(nmr, sv.z, cv.z)));
      float g3 = gelu_f(fmaf(rs, acc1[mf][3], fmaf(nmr, sv.w, cv.w)));
      uint2 pw;
      pw.x = pk_bf16(g0, g1);
      pw.y = pk_bf16(g2, g3);
      *(uint2*)&hs[hrow + mf*16 + lg*4] = pw;
    }
    // fc2 partial over this 96-chunk
    #pragma unroll
    for (int ks = 0; ks < 3; ++ks){
      bf16x8 a2[6];
      #pragma unroll
      for (int mf2 = 0; mf2 < 6; ++mf2)
        a2[mf2] = *(const bf16x8*)(Wb2 + (size_t)(((cc*3 + ks)*6 + mf2)*64 + lane)*8);
      bf16x8 bfr2 = *(const bf16x8*)&hs[hrow + ks*32 + lg*8];
      #pragma unroll
      for (int mf2 = 0; mf2 < 6; ++mf2)
        acc2[mf2] = __builtin_amdgcn_mfma_f32_16x16x32_bf16(a2[mf2], bfr2, acc2[mf2], 0, 0, 0);
    }
  }
  // epilogue: + c2 + residual -> X f32, XT bf16, stats
  {
    int b = l >> 14, lb = l & (LL-1);
    float ssum = 0.f, ssq = 0.f;
    #pragma unroll
    for (int mf = 0; mf < 6; ++mf){
      float o[4];
      #pragma unroll
      for (int r = 0; r < 4; ++r){
        int mm = mf*16 + lg*4 + r;
        float vv = acc2[mf][r] + c2[mm];
        vv += X[((size_t)b*96 + mm)*LL + lb];
        X[((size_t)b*96 + mm)*LL + lb] = vv;
        ssum += vv; ssq += vv*vv;
        o[r] = vv;
      }
      ushort4 pk;
      pk.x = f2bf(o[0]); pk.y = f2bf(o[1]); pk.z = f2bf(o[2]); pk.w = f2bf(o[3]);
      *(ushort4*)(XTout + (size_t)l*104 + mf*16 + lg*4) = pk;
    }
    ssum += __shfl_xor(ssum, 16); ssq += __shfl_xor(ssq, 16);
    ssum += __shfl_xor(ssum, 32); ssq += __shfl_xor(ssq, 32);
    if (lane < 16){
      float mu2 = ssum*(1.f/CC);
      float var = ssq*(1.f/CC) - mu2*mu2;
      stO[l] = mu2;
      stO[(size_t)BT*LL + l] = rsqrtf(var + 1e-5f);
    }
  }
}

// ---------------- depthwise 3x3 + SiLU, fused transpose (writes v and vT) ----------------
__global__ __launch_bounds__(256) void k_dwconv_silu_t(const float* __restrict__ u,
      float* __restrict__ v, float* __restrict__ vT, const float* __restrict__ cw){
  __shared__ float tl[32][33];
  int bc = blockIdx.z;
  int c = bc % CC;
  int w0 = blockIdx.x*32, h0 = blockIdx.y*32;
  const float* up = u + (size_t)bc*LL;
  const float* k9 = cw + c*9;
  int t = threadIdx.x;
  int wl = (t & 7)*4, hl = t >> 3;
  int h = h0 + hl, w = w0 + wl;
  float acc[4] = {0.f,0.f,0.f,0.f};
  #pragma unroll
  for (int dh = -1; dh <= 1; ++dh){
    int h2 = h + dh;
    if (h2 < 0 || h2 >= HH) continue;
    const float* row = up + (size_t)h2*WW + w;
    float4 m = *(const float4*)row;
    float lft = (w > 0) ? row[-1] : 0.f;
    float rgt = (w + 4 < WW) ? row[4] : 0.f;
    float k0 = k9[(dh+1)*3], k1 = k9[(dh+1)*3+1], k2 = k9[(dh+1)*3+2];
    acc[0] += lft*k0 + m.x*k1 + m.y*k2;
    acc[1] += m.x*k0 + m.y*k1 + m.z*k2;
    acc[2] += m.y*k0 + m.z*k1 + m.w*k2;
    acc[3] += m.z*k0 + m.w*k1 + rgt*k2;
  }
  float4 ov;
  float* po = (float*)&ov;
  #pragma unroll
  for (int j = 0; j < 4; ++j){
    float a = acc[j];
    float e = __expf(-a);
    float s = a * __builtin_amdgcn_rcpf(1.f + e);
    po[j] = s;
    tl[wl + j][hl] = s;
  }
  *(float4*)&v[(size_t)bc*LL + (size_t)h*WW + w] = ov;
  __syncthreads();
  int ww = t >> 3, hh4 = (t & 7)*4;
  float4 o2 = make_float4(tl[ww][hh4], tl[ww][hh4+1], tl[ww][hh4+2], tl[ww][hh4+3]);
  *(float4*)&vT[(size_t)bc*LL + (size_t)(w0 + ww)*HH + h0 + hh4] = o2;
}

// ---------------- x-projection (both sources in one launch) ----------------
__global__ void k_xproj(const float* __restrict__ v, const float* __restrict__ vT,
                        float* __restrict__ G, const float* __restrict__ xpw){
  int which = blockIdx.y;
  const float* src = which ? vT : v;
  int kA = which ? 1 : 0, kB = which ? 3 : 2;
  size_t i = (size_t)blockIdx.x*256 + threadIdx.x;
  if (i >= (size_t)BT*LL) return;
  int b = (int)(i / LL), l = (int)(i % LL);
  const float* sp = src + (size_t)b*CC*LL + l;
  const float* wA = xpw + (size_t)kA*8*CC;
  const float* wB = xpw + (size_t)kB*8*CC;
  float aA[8], aB[8];
  #pragma unroll
  for (int d = 0; d < 8; ++d){ aA[d] = 0.f; aB[d] = 0.f; }
  for (int c = 0; c < CC; ++c){
    float xv = sp[(size_t)c*LL];
    #pragma unroll
    for (int d = 0; d < 8; ++d){
      aA[d] = fmaf(wA[d*CC + c], xv, aA[d]);
      aB[d] = fmaf(wB[d*CC + c], xv, aB[d]);
    }
  }
  float* gA = G + (((size_t)b*KD + kA)*8)*LL + l;
  float* gB = G + (((size_t)b*KD + kB)*8)*LL + l;
  #pragma unroll
  for (int d = 0; d < 8; ++d){ gA[(size_t)d*LL] = aA[d]; gB[(size_t)d*LL] = aB[d]; }
}

// ---------------- tile-parallel selective scan (fwd+rev in one launch) ----------------
__device__ __forceinline__ void ld4(const float* p, float* o){
  float4 t = *(const float4*)p; o[0]=t.x; o[1]=t.y; o[2]=t.z; o[3]=t.w;
}
__device__ __forceinline__ void rev4(float* a){
  float t0 = a[0]; a[0] = a[3]; a[3] = t0;
  float t1 = a[1]; a[1] = a[2]; a[2] = t1;
}

__global__ __launch_bounds__(256) void k_scan3(const float* __restrict__ G,
                       const float* __restrict__ v, const float* __restrict__ vT,
                       float* __restrict__ Y,
                       const float* __restrict__ dtw_, const float* __restrict__ dtb_,
                       const float* __restrict__ Alog_, const float* __restrict__ Ds_){
  const size_t SZ = (size_t)BT*CC*LL;
  int wid = threadIdx.x >> 6, lane = threadIdx.x & 63;
  int tile = blockIdx.x*4 + wid;
  int sy = blockIdx.y;
  bool rev = (blockIdx.z != 0);
  int c = sy % CC; int t2 = sy / CC; int kk = t2 & 1; int b = t2 >> 1;
  int k = (rev ? 2 : 0) + kk;
  const float* src = (kk ? vT : v) + ((size_t)b*CC + c)*LL;
  const float* g = G + (((size_t)b*KD + k)*8)*LL;
  float dtw[RR];
  #pragma unroll
  for (int r = 0; r < RR; ++r) dtw[r] = dtw_[((size_t)k*CC + c)*RR + r];
  float dtb = dtb_[k*CC + c];
  float A  = -__expf(Alog_[k*CC + c]);
  float Dv = Ds_[k*CC + c];
  float* yout = Y + (size_t)k*SZ + ((size_t)b*CC + c)*LL;

  int lstore0 = tile*512;
  float carry = 0.f;
  for (int p = 0; p < 3; ++p){
    int base = lstore0 - 256 + p*256;
    if (base < 0) continue;
    int l = base + (lane<<2);
    int ga = rev ? (LL-4-l) : l;
    float r0[4], r1[4], r2[4], r3[4], r4[4], r5[4], g6b[4], g7b[4], xb[4];
    ld4(g + 0*(size_t)LL + ga, r0);
    ld4(g + 1*(size_t)LL + ga, r1);
    ld4(g + 2*(size_t)LL + ga, r2);
    ld4(g + 3*(size_t)LL + ga, r3);
    ld4(g + 4*(size_t)LL + ga, r4);
    ld4(g + 5*(size_t)LL + ga, r5);
    ld4(g + 6*(size_t)LL + ga, g6b);
    ld4(g + 7*(size_t)LL + ga, g7b);
    ld4(src + ga, xb);
    if (rev){
      rev4(r0); rev4(r1); rev4(r2); rev4(r3); rev4(r4); rev4(r5);
      rev4(g6b); rev4(g7b); rev4(xb);
    }
    float av[4], bt[4];
    #pragma unroll
    for (int i = 0; i < 4; ++i){
      float dsum = dtb;
      dsum = fmaf(r0[i], dtw[0], dsum);
      dsum = fmaf(r1[i], dtw[1], dsum);
      dsum = fmaf(r2[i], dtw[2], dsum);
      dsum = fmaf(r3[i], dtw[3], dsum);
      dsum = fmaf(r4[i], dtw[4], dsum);
      dsum = fmaf(r5[i], dtw[5], dsum);
      float sp = __logf(1.f + __expf(dsum));
      float delta = (dsum > 20.f) ? dsum : sp;
      av[i] = __expf(delta * A);
      bt[i] = delta * g6b[i] * xb[i];
    }
    float P = av[0], Q = bt[0];
    #pragma unroll
    for (int i = 1; i < 4; ++i){ Q = fmaf(av[i], Q, bt[i]); P *= av[i]; }
    #pragma unroll
    for (int off = 1; off < 64; off <<= 1){
      float Pp = __shfl_up(P, (unsigned)off);
      float Qp = __shfl_up(Q, (unsigned)off);
      if (lane >= off){ Q = fmaf(P, Qp, Q); P *= Pp; }
    }
    float Pe = __shfl_up(P, 1u), Qe = __shfl_up(Q, 1u);
    if (lane == 0){ Pe = 1.f; Qe = 0.f; }
    float h = fmaf(Pe, carry, Qe);
    float ys[4];
    #pragma unroll
    for (int i = 0; i < 4; ++i){
      h = fmaf(av[i], h, bt[i]);
      ys[i] = fmaf(g7b[i], h, Dv*xb[i]);
    }
    carry = __shfl(h, 63);
    if (p > 0){
      if (rev) rev4(ys);
      *(float4*)&yout[ga] = make_float4(ys[0], ys[1], ys[2], ys[3]);
    }
  }
}

// ---------------- combine: z = (y0+y2) + transpose(y1+y3) ----------------
__global__ void k_combine4(const float* __restrict__ Y, float* __restrict__ z){
  const size_t SZ = (size_t)BT*CC*LL;
  __shared__ float tile[32][33];
  int bc = blockIdx.z;
  const float* y1p = Y + SZ   + (size_t)bc*LL;
  const float* y3p = Y + 3*SZ + (size_t)bc*LL;
  int w0 = blockIdx.x*32, h0 = blockIdx.y*32;
  int tx = threadIdx.x, ty = threadIdx.y;
  #pragma unroll
  for (int kk = 0; kk < 4; ++kk){
    int w = w0 + ty + kk*8;
    size_t idx = (size_t)w*HH + h0 + tx;
    tile[ty + kk*8][tx] = y1p[idx] + y3p[idx];
  }
  __syncthreads();
  const float* y0p = Y +        (size_t)bc*LL;
  const float* y2p = Y + 2*SZ + (size_t)bc*LL;
  float* zp = z + (size_t)bc*LL;
  #pragma unroll
  for (int kk = 0; kk < 4; ++kk){
    int h = h0 + ty + kk*8;
    size_t idx = (size_t)h*WW + w0 + tx;
    zp[idx] = y0p[idx] + y2p[idx] + tile[tx][ty + kk*8];
  }
}

// ---------------- final output split/average ----------------
__global__ void k_output(const float* __restrict__ X, float* __restrict__ out){
  size_t i = (size_t)blockIdx.x*256 + threadIdx.x;
  size_t half = (size_t)2*CC*HH*128;
  if (i >= half) return;
  int w = i % 128; size_t r = i / 128;
  int h = r % HH; size_t bc = r / HH;
  size_t fwd = (bc*HH + h)*WW;
  size_t bwd = ((bc + (size_t)2*CC)*HH + h)*WW;
  out[i]        = 0.5f*(X[fwd + w]       + X[bwd + (WW-1-w)]);
  out[half + i] = 0.5f*(X[fwd + 128 + w] + X[bwd + (127 - w)]);
}

extern "C" void kernel_launch(void* const* d_in, const int* in_sizes, int n_in,
                              void* d_out, int out_size, void* d_ws, size_t ws_size,
                              hipStream_t stream){
  const float* x0        = (const float*)d_in[0];
  const float* x1        = (const float*)d_in[1];
  const float* norm_w    = (const float*)d_in[2];
  const float* norm_b    = (const float*)d_in[3];
  const float* in_proj_w = (const float*)d_in[4];
  const float* conv_w    = (const float*)d_in[5];
  const float* x_proj_w  = (const float*)d_in[6];
  const float* dt_w      = (const float*)d_in[7];
  const float* dt_b      = (const float*)d_in[8];
  const float* A_logs    = (const float*)d_in[9];
  const float* Ds        = (const float*)d_in[10];
  const float* out_norm_w= (const float*)d_in[11];
  const float* out_norm_b= (const float*)d_in[12];
  const float* out_proj_w= (const float*)d_in[13];
  const float* norm2_w   = (const float*)d_in[14];
  const float* norm2_b   = (const float*)d_in[15];
  const float* fc1_w     = (const float*)d_in[16];
  const float* fc1_b     = (const float*)d_in[17];
  const float* fc2_w     = (const float*)d_in[18];
  const float* fc2_b     = (const float*)d_in[19];

  const size_t SZ = (size_t)BT*CC*LL;            // 6,291,456 floats
  float* X  = (float*)d_ws;
  float* t  = X + SZ;
  float* u  = t + SZ;
  float* G  = u + SZ;                            // BT*KD*8*LL floats
  float* v  = G + (size_t)BT*KD*8*LL;
  float* vT = v + SZ;
  float* Y  = vT + SZ;                           // 4 contiguous SZ buffers
  u16*   XT  = (u16*)Y;                          // bf16T [BT*LL][104] (phase-disjoint w/ Y0)
  u16*   tT  = (u16*)u;                          // bf16T of t (u dead by then)
  float* ext = Y + 4*SZ;
  float* stats_X = ext;                          // 2*BT*LL
  float* stats_t = stats_X + 2*(size_t)BT*LL;
  float* wsl     = stats_t + 2*(size_t)BT*LL;    // weight slots: NLAY * SLOTF floats

  float* p0 = wsl;
  u16*  WbI0 = (u16*)p0;          float* s1I0 = p0 + 4608;  float* cI0 = p0 + 4704;
  u16*  WbO0 = (u16*)(p0+4800);   float* s1O0 = p0 + 9408;  float* cO0 = p0 + 9504;
  u16*  Wb10 = (u16*)(p0+9600);   float* s110 = p0 + 28032; float* c10 = p0 + 28416;
  u16*  Wb20 = (u16*)(p0+28800);  float* s120 = p0 + 47232; float* c20 = p0 + 47328;

  k_prepw<96,96,false,true,false><<<dim3(2,NLAY),64,0,stream>>>(in_proj_w, norm_w, norm_b, nullptr, WbI0, s1I0, cI0);
  k_prepw<96,96,false,true,false><<<dim3(2,NLAY),64,0,stream>>>(out_proj_w, out_norm_w, out_norm_b, nullptr, WbO0, s1O0, cO0);
  k_prepw<384,96,true,true,true><<<dim3(6,NLAY),64,0,stream>>>(fc1_w, norm2_w, norm2_b, fc1_b, Wb10, s110, c10);
  k_prepw<96,384,false,false,true><<<dim3(2,NLAY),64,0,stream>>>(fc2_w, nullptr, nullptr, fc2_b, Wb20, s120, c20);

  k_build<<<(2*CC*HH*WW + 255)/256, 256, 0, stream>>>(x0, x1, X);
  k_pack<true><<<dim3(LL/32, BT), 256, 0, stream>>>(X, XT, stats_X);

  for (int lay = 0; lay < NLAY; ++lay){
    size_t so = (size_t)lay*SLOTF;
    const u16* WbI = WbI0 + so*2; const float* s1I = s1I0 + so; const float* cI = cI0 + so;
    const u16* WbO = WbO0 + so*2; const float* s1O = s1O0 + so; const float* cO = cO0 + so;
    const u16* Wb1 = Wb10 + so*2; const float* s11 = s110 + so; const float* c1 = c10 + so;
    const u16* Wb2 = Wb20 + so*2; const float* c2 = c20 + so;
    const float* cw  = conv_w    + (size_t)lay*CC*9;
    const float* xpw = x_proj_w  + (size_t)lay*KD*8*CC;
    const float* dw  = dt_w      + (size_t)lay*KD*CC*RR;
    const float* db  = dt_b      + (size_t)lay*KD*CC;
    const float* Al  = A_logs    + (size_t)lay*KD*CC;
    const float* Dp  = Ds        + (size_t)lay*KD*CC;

    // in_proj (LN fused): u = W' * X
    k_gmm2<true,false,true,false,false><<<dim3(BT*LL/128),256,0,stream>>>(
        WbI, XT, u, nullptr, s1I, cI, nullptr, stats_X, nullptr);
    k_dwconv_silu_t<<<dim3(8,2,BT*CC), 256, 0, stream>>>(u, v, vT, cw);
    k_xproj<<<dim3(BT*LL/256, 2), 256, 0, stream>>>(v, vT, G, xpw);
    k_scan3<<<dim3(8,768,2), 256, 0, stream>>>(G, v, vT, Y, dw, db, Al, Dp);
    k_combine4<<<dim3(8,2,BT*CC), dim3(32,8), 0, stream>>>(Y, t);
    k_pack<true><<<dim3(LL/32, BT), 256, 0, stream>>>(t, tT, stats_t);
    // out_proj (LN fused) + residual -> X (f32 + XT bf16 + stats_X)
    k_gmm2<true,true,true,true,true><<<dim3(BT*LL/128),256,0,stream>>>(
        WbO, tT, X, XT, s1O, cO, X, stats_t, stats_X);
    // fused MLP
    k_mlp<<<dim3(BT*LL/128),512,0,stream>>>(
        Wb1, Wb2, XT, X, XT, s11, c1, c2, stats_X, stats_X);
  }

  k_output<<<(unsigned)(((size_t)2*CC*HH*128 + 255)/256), 256, 0, stream>>>(X, (float*)d_out);
}

// Round 9
// 466.592 us; speedup vs baseline: 10.4920x; 1.0063x over previous
//
#include <hip/hip_runtime.h>
#include <cstdint>
#include <cstddef>

#define BT 4
#define CC 96
#define HH 64
#define WW 256
#define LL (HH*WW)    // 16384
#define KD 4
#define RR 6
#define NLAY 2
#define C4 (4*CC)     // 384
#define SLOTF 47424   // per-layer weight-slot stride in float units
#define STPW 2048     // scan: stored elems per wave

typedef unsigned short u16;
typedef __attribute__((ext_vector_type(8))) short bf16x8;
typedef __attribute__((ext_vector_type(4))) float f32x4;

__device__ __forceinline__ u16 f2bf(float f){
  unsigned u = __float_as_uint(f);
  unsigned r = (u + 0x7FFFu + ((u >> 16) & 1u)) >> 16;
  return (u16)r;
}
__device__ __forceinline__ float bf2f(u16 h){
  return __uint_as_float(((unsigned)h) << 16);
}
__device__ __forceinline__ unsigned pk_bf16(float lo, float hi){
  unsigned r;
  asm volatile("v_cvt_pk_bf16_f32 %0, %1, %2" : "=v"(r) : "v"(lo), "v"(hi));
  return r;
}
__device__ __forceinline__ float fexp2(float x){
  float r; asm("v_exp_f32 %0, %1" : "=v"(r) : "v"(x)); return r;
}
__device__ __forceinline__ float flog2(float x){
  float r; asm("v_log_f32 %0, %1" : "=v"(r) : "v"(x)); return r;
}
// tanh-approx GELU, division-free
__device__ __forceinline__ float gelu_f(float v){
  float t = v*v;
  float u = v*fmaf(0.0356774081f, t, 0.7978845608f);
  float e2 = __expf(2.f*u);
  float r = __builtin_amdgcn_rcpf(e2 + 1.f);
  return fmaf(-v, r, v);
}

// ---------------- build batched input ----------------
__global__ void k_build(const float* __restrict__ x0, const float* __restrict__ x1,
                        float* __restrict__ X){
  size_t i = (size_t)blockIdx.x*256 + threadIdx.x;
  size_t tot = (size_t)2*CC*HH*WW;
  if (i >= tot) return;
  int w = i % WW; size_t r = i / WW;
  int h = r % HH; size_t bc = r / HH;
  float val;
  if (w < 128) val = x0[(bc*HH + h)*128 + w];
  else         val = x1[(bc*HH + h)*128 + (w-128)];
  X[i] = val;
  size_t ib = ((bc + (size_t)2*CC)*HH + h)*WW + (WW-1-w);
  X[ib] = val;
}

// ---------------- pack f32 [b][c][l] -> bf16T [b*LL+l][104] (+ LN stats) ----------------
template<bool ST>
__global__ __launch_bounds__(256) void k_pack(const float* __restrict__ src,
      u16* __restrict__ dst, float* __restrict__ st){
  __shared__ float tl[CC][33];
  int tid = threadIdx.x;
  int l0 = blockIdx.x*32, b = blockIdx.y;
  for (int e = tid; e < CC*32; e += 256){
    int c = e >> 5, dl = e & 31;
    tl[c][dl] = src[((size_t)b*CC + c)*LL + l0 + dl];
  }
  __syncthreads();
  if (ST && tid < 32){
    float s = 0.f, ss = 0.f;
    for (int c = 0; c < CC; ++c){ float vv = tl[c][tid]; s += vv; ss += vv*vv; }
    float mu = s*(1.f/CC);
    float var = ss*(1.f/CC) - mu*mu;
    st[(size_t)b*LL + l0 + tid] = mu;
    st[(size_t)BT*LL + (size_t)b*LL + l0 + tid] = rsqrtf(var + 1e-5f);
  }
  int dl = tid >> 3, cg = tid & 7;
  u16* dp = dst + ((size_t)b*LL + l0 + dl)*104 + cg*12;
  #pragma unroll
  for (int q = 0; q < 3; ++q){
    ushort4 pk;
    pk.x = f2bf(tl[cg*12 + q*4 + 0][dl]);
    pk.y = f2bf(tl[cg*12 + q*4 + 1][dl]);
    pk.z = f2bf(tl[cg*12 + q*4 + 2][dl]);
    pk.w = f2bf(tl[cg*12 + q*4 + 3][dl]);
    *(ushort4*)(dp + q*4) = pk;
  }
}

// ---------------- weight prep: swizzle into MFMA-fragment order ----------------
template<int M, int K, bool FC1ORD, bool LNF, bool BIAS>
__global__ void k_prepw(const float* __restrict__ W, const float* __restrict__ lnw,
      const float* __restrict__ lnb, const float* __restrict__ bias,
      u16* __restrict__ Wb, float* __restrict__ s1, float* __restrict__ cadd){
  int lay = blockIdx.y;
  W += (size_t)lay*M*K;
  Wb += (size_t)lay*SLOTF*2;
  s1 += (size_t)lay*SLOTF;
  cadd += (size_t)lay*SLOTF;
  int m = blockIdx.x*64 + threadIdx.x;
  if (m >= M) return;
  int rowfrag = m >> 4, lr = m & 15;
  float s1v = 0.f, sbv = 0.f;
  for (int c = 0; c < K; ++c){
    float wv = W[(size_t)m*K + c];
    float wf = LNF ? wv*lnw[lay*K + c] : wv;
    u16 h = f2bf(wf);
    int colfrag = c >> 5, lg = (c >> 3) & 3, j = c & 7;
    int f;
    if (FC1ORD) f = (rowfrag/6)*18 + colfrag*6 + (rowfrag % 6);
    else        f = colfrag*(M/16) + rowfrag;
    Wb[(size_t)(f*64 + lg*16 + lr)*8 + j] = h;
    s1v += bf2f(h);
    if (LNF) sbv = fmaf(wv, lnb[lay*K + c], sbv);
  }
  if (BIAS) sbv += bias[lay*M + m];
  s1[m] = s1v;
  cadd[m] = sbv;
}

// ---------------- MFMA GEMM (M=96,K=96): 64px/block, LDS B, swizzled weights ----------------
template<bool LNF, bool RES, bool WF32, bool WBF, bool STATS>
__global__ __launch_bounds__(256) void k_gmm2(
    const u16* __restrict__ Wb, const u16* __restrict__ inT,
    float* __restrict__ outF, u16* __restrict__ outT,
    const float* __restrict__ s1v, const float* __restrict__ cadd,
    const float* __restrict__ res,
    const float* __restrict__ stI, float* __restrict__ stO){
  __shared__ u16 bt[64*104];
  int tid = threadIdx.x, lane = tid & 63, wid = tid >> 6;
  int l0 = blockIdx.x*64;
  int lr = lane & 15, lg = lane >> 4;
  const int4* bsrc = (const int4*)(inT + (size_t)l0*104);
  for (int i = tid; i < 832; i += 256) ((int4*)bt)[i] = bsrc[i];
  __syncthreads();
  f32x4 acc[6];
  #pragma unroll
  for (int mf = 0; mf < 6; ++mf) acc[mf] = (f32x4){0,0,0,0};
  int brow = (wid*16 + lr)*104;
  #pragma unroll
  for (int ks = 0; ks < 3; ++ks){
    bf16x8 af[6];
    #pragma unroll
    for (int mf = 0; mf < 6; ++mf)
      af[mf] = *(const bf16x8*)(Wb + (size_t)((ks*6 + mf)*64 + lane)*8);
    bf16x8 bfr = *(const bf16x8*)&bt[brow + ks*32 + lg*8];
    #pragma unroll
    for (int mf = 0; mf < 6; ++mf)
      acc[mf] = __builtin_amdgcn_mfma_f32_16x16x32_bf16(af[mf], bfr, acc[mf], 0, 0, 0);
  }
  {
    int l = l0 + wid*16 + lr;
    int b = l >> 14, lb = l & (LL-1);
    float mu = 0.f, rs = 0.f;
    if (LNF){ mu = stI[l]; rs = stI[(size_t)BT*LL + l]; }
    float ssum = 0.f, ssq = 0.f;
    #pragma unroll
    for (int mf = 0; mf < 6; ++mf){
      float o[4];
      #pragma unroll
      for (int r = 0; r < 4; ++r){
        int mm = mf*16 + lg*4 + r;
        float vv = acc[mf][r];
        if (LNF) vv = fmaf(rs, vv, fmaf(-mu*rs, s1v[mm], cadd[mm]));
        else     vv += cadd[mm];
        if (RES) vv += res[((size_t)b*96 + mm)*LL + lb];
        if (WF32) outF[((size_t)b*96 + mm)*LL + lb] = vv;
        if (STATS){ ssum += vv; ssq += vv*vv; }
        o[r] = vv;
      }
      if (WBF){
        ushort4 pk;
        pk.x = f2bf(o[0]); pk.y = f2bf(o[1]); pk.z = f2bf(o[2]); pk.w = f2bf(o[3]);
        *(ushort4*)(outT + (size_t)l*104 + mf*16 + lg*4) = pk;
      }
    }
    if (STATS){
      ssum += __shfl_xor(ssum, 16); ssq += __shfl_xor(ssq, 16);
      ssum += __shfl_xor(ssum, 32); ssq += __shfl_xor(ssq, 32);
      if (lane < 16){
        float mu2 = ssum*(1.f/CC);
        float var = ssq*(1.f/CC) - mu2*mu2;
        stO[l] = mu2;
        stO[(size_t)BT*LL + l] = rsqrtf(var + 1e-5f);
      }
    }
  }
}

// ---------------- fused MLP v4: 8 waves/block, coalesced swizzled weights ----------------
__global__ __launch_bounds__(512, 4) void k_mlp(
    const u16* __restrict__ Wb1, const u16* __restrict__ Wb2,
    const u16* __restrict__ XT, float* __restrict__ X, u16* __restrict__ XTout,
    const float* __restrict__ s11, const float* __restrict__ c1,
    const float* __restrict__ c2,
    const float* __restrict__ stI, float* __restrict__ stO){
  __shared__ u16 bt[128*104];
  __shared__ u16 hs[128*104];
  int tid = threadIdx.x, lane = tid & 63, wid = tid >> 6;   // wid 0..7
  int l0 = blockIdx.x*128;
  int lr = lane & 15, lg = lane >> 4;
  const int4* bsrc = (const int4*)(XT + (size_t)l0*104);
  for (int i = tid; i < 1664; i += 512) ((int4*)bt)[i] = bsrc[i];

  int l = l0 + wid*16 + lr;                    // this lane's pixel
  float mu = stI[l];
  float rs = stI[(size_t)BT*LL + l];
  float nmr = -mu*rs;
  __syncthreads();

  int hrow = (wid*16 + lr)*104;
  f32x4 acc2[6];
  #pragma unroll
  for (int mf = 0; mf < 6; ++mf) acc2[mf] = (f32x4){0,0,0,0};

  for (int cc = 0; cc < 4; ++cc){
    f32x4 acc1[6];
    #pragma unroll
    for (int mf = 0; mf < 6; ++mf) acc1[mf] = (f32x4){0,0,0,0};
    #pragma unroll
    for (int ks = 0; ks < 3; ++ks){
      bf16x8 af[6];
      #pragma unroll
      for (int mf = 0; mf < 6; ++mf)
        af[mf] = *(const bf16x8*)(Wb1 + (size_t)((cc*18 + ks*6 + mf)*64 + lane)*8);
      bf16x8 bfr = *(const bf16x8*)&bt[hrow + ks*32 + lg*8];
      #pragma unroll
      for (int mf = 0; mf < 6; ++mf)
        acc1[mf] = __builtin_amdgcn_mfma_f32_16x16x32_bf16(af[mf], bfr, acc1[mf], 0, 0, 0);
    }
    #pragma unroll
    for (int mf = 0; mf < 6; ++mf){
      float4 sv = *(const float4*)&s11[cc*96 + mf*16 + lg*4];
      float4 cv = *(const float4*)&c1 [cc*96 + mf*16 + lg*4];
      float g0 = gelu_f(fmaf(rs, acc1[mf][0], fmaf(nmr, sv.x, cv.x)));
      float g1 = gelu_f(fmaf(rs, acc1[mf][1], fmaf(nmr, sv.y, cv.y)));
      float g2 = gelu_f(fmaf(rs, acc1[mf][2], fmaf(nmr, sv.z, cv.z)));
      float g3 = gelu_f(fmaf(rs, acc1[mf][3], fmaf(nmr, sv.w, cv.w)));
      uint2 pw;
      pw.x = pk_bf16(g0, g1);
      pw.y = pk_bf16(g2, g3);
      *(uint2*)&hs[hrow + mf*16 + lg*4] = pw;
    }
    #pragma unroll
    for (int ks = 0; ks < 3; ++ks){
      bf16x8 a2[6];
      #pragma unroll
      for (int mf2 = 0; mf2 < 6; ++mf2)
        a2[mf2] = *(const bf16x8*)(Wb2 + (size_t)(((cc*3 + ks)*6 + mf2)*64 + lane)*8);
      bf16x8 bfr2 = *(const bf16x8*)&hs[hrow + ks*32 + lg*8];
      #pragma unroll
      for (int mf2 = 0; mf2 < 6; ++mf2)
        acc2[mf2] = __builtin_amdgcn_mfma_f32_16x16x32_bf16(a2[mf2], bfr2, acc2[mf2], 0, 0, 0);
    }
  }
  {
    int b = l >> 14, lb = l & (LL-1);
    float ssum = 0.f, ssq = 0.f;
    #pragma unroll
    for (int mf = 0; mf < 6; ++mf){
      float o[4];
      #pragma unroll
      for (int r = 0; r < 4; ++r){
        int mm = mf*16 + lg*4 + r;
        float vv = acc2[mf][r] + c2[mm];
        vv += X[((size_t)b*96 + mm)*LL + lb];
        X[((size_t)b*96 + mm)*LL + lb] = vv;
        ssum += vv; ssq += vv*vv;
        o[r] = vv;
      }
      ushort4 pk;
      pk.x = f2bf(o[0]); pk.y = f2bf(o[1]); pk.z = f2bf(o[2]); pk.w = f2bf(o[3]);
      *(ushort4*)(XTout + (size_t)l*104 + mf*16 + lg*4) = pk;
    }
    ssum += __shfl_xor(ssum, 16); ssq += __shfl_xor(ssq, 16);
    ssum += __shfl_xor(ssum, 32); ssq += __shfl_xor(ssq, 32);
    if (lane < 16){
      float mu2 = ssum*(1.f/CC);
      float var = ssq*(1.f/CC) - mu2*mu2;
      stO[l] = mu2;
      stO[(size_t)BT*LL + l] = rsqrtf(var + 1e-5f);
    }
  }
}

// ---------------- depthwise 3x3 + SiLU, fused transpose (writes v and vT) ----------------
__global__ __launch_bounds__(256) void k_dwconv_silu_t(const float* __restrict__ u,
      float* __restrict__ v, float* __restrict__ vT, const float* __restrict__ cw){
  __shared__ float tl[32][33];
  int bc = blockIdx.z;
  int c = bc % CC;
  int w0 = blockIdx.x*32, h0 = blockIdx.y*32;
  const float* up = u + (size_t)bc*LL;
  const float* k9 = cw + c*9;
  int t = threadIdx.x;
  int wl = (t & 7)*4, hl = t >> 3;
  int h = h0 + hl, w = w0 + wl;
  float acc[4] = {0.f,0.f,0.f,0.f};
  #pragma unroll
  for (int dh = -1; dh <= 1; ++dh){
    int h2 = h + dh;
    if (h2 < 0 || h2 >= HH) continue;
    const float* row = up + (size_t)h2*WW + w;
    float4 m = *(const float4*)row;
    float lft = (w > 0) ? row[-1] : 0.f;
    float rgt = (w + 4 < WW) ? row[4] : 0.f;
    float k0 = k9[(dh+1)*3], k1 = k9[(dh+1)*3+1], k2 = k9[(dh+1)*3+2];
    acc[0] += lft*k0 + m.x*k1 + m.y*k2;
    acc[1] += m.x*k0 + m.y*k1 + m.z*k2;
    acc[2] += m.y*k0 + m.z*k1 + m.w*k2;
    acc[3] += m.z*k0 + m.w*k1 + rgt*k2;
  }
  float4 ov;
  float* po = (float*)&ov;
  #pragma unroll
  for (int j = 0; j < 4; ++j){
    float a = acc[j];
    float e = __expf(-a);
    float s = a * __builtin_amdgcn_rcpf(1.f + e);
    po[j] = s;
    tl[wl + j][hl] = s;
  }
  *(float4*)&v[(size_t)bc*LL + (size_t)h*WW + w] = ov;
  __syncthreads();
  int ww = t >> 3, hh4 = (t & 7)*4;
  float4 o2 = make_float4(tl[ww][hh4], tl[ww][hh4+1], tl[ww][hh4+2], tl[ww][hh4+3]);
  *(float4*)&vT[(size_t)bc*LL + (size_t)(w0 + ww)*HH + h0 + hh4] = o2;
}

// ---------------- x-projection (both sources in one launch) ----------------
__global__ void k_xproj(const float* __restrict__ v, const float* __restrict__ vT,
                        float* __restrict__ G, const float* __restrict__ xpw){
  int which = blockIdx.y;
  const float* src = which ? vT : v;
  int kA = which ? 1 : 0, kB = which ? 3 : 2;
  size_t i = (size_t)blockIdx.x*256 + threadIdx.x;
  if (i >= (size_t)BT*LL) return;
  int b = (int)(i / LL), l = (int)(i % LL);
  const float* sp = src + (size_t)b*CC*LL + l;
  const float* wA = xpw + (size_t)kA*8*CC;
  const float* wB = xpw + (size_t)kB*8*CC;
  float aA[8], aB[8];
  #pragma unroll
  for (int d = 0; d < 8; ++d){ aA[d] = 0.f; aB[d] = 0.f; }
  for (int c = 0; c < CC; ++c){
    float xv = sp[(size_t)c*LL];
    #pragma unroll
    for (int d = 0; d < 8; ++d){
      aA[d] = fmaf(wA[d*CC + c], xv, aA[d]);
      aB[d] = fmaf(wB[d*CC + c], xv, aB[d]);
    }
  }
  float* gA = G + (((size_t)b*KD + kA)*8)*LL + l;
  float* gB = G + (((size_t)b*KD + kB)*8)*LL + l;
  #pragma unroll
  for (int d = 0; d < 8; ++d){ gA[(size_t)d*LL] = aA[d]; gB[(size_t)d*LL] = aB[d]; }
}

// ---------------- tile-parallel selective scan v4: 2048/wave, exp2-domain ----------------
__device__ __forceinline__ void ld4(const float* p, float* o){
  float4 t = *(const float4*)p; o[0]=t.x; o[1]=t.y; o[2]=t.z; o[3]=t.w;
}
__device__ __forceinline__ void rev4(float* a){
  float t0 = a[0]; a[0] = a[3]; a[3] = t0;
  float t1 = a[1]; a[1] = a[2]; a[2] = t1;
}

__global__ __launch_bounds__(256) void k_scan3(const float* __restrict__ G,
                       const float* __restrict__ v, const float* __restrict__ vT,
                       float* __restrict__ Y,
                       const float* __restrict__ dtw_, const float* __restrict__ dtb_,
                       const float* __restrict__ Alog_, const float* __restrict__ Ds_){
  const size_t SZ = (size_t)BT*CC*LL;
  const float LOG2E = 1.4426950408889634f, LN2 = 0.6931471805599453f;
  int wid = threadIdx.x >> 6, lane = threadIdx.x & 63;
  int tile = blockIdx.x*4 + wid;               // 0..7
  int sy = blockIdx.y;
  bool rev = (blockIdx.z != 0);
  int c = sy % CC; int t2 = sy / CC; int kk = t2 & 1; int b = t2 >> 1;
  int k = (rev ? 2 : 0) + kk;
  const float* src = (kk ? vT : v) + ((size_t)b*CC + c)*LL;
  const float* g = G + (((size_t)b*KD + k)*8)*LL;
  float dtw[RR];
  #pragma unroll
  for (int r = 0; r < RR; ++r) dtw[r] = dtw_[((size_t)k*CC + c)*RR + r];
  float dtb = dtb_[k*CC + c];
  float A  = -__expf(Alog_[k*CC + c]);
  float Dv = Ds_[k*CC + c];
  float* yout = Y + (size_t)k*SZ + ((size_t)b*CC + c)*LL;

  int lstore0 = tile*STPW;
  float carry = 0.f;
  for (int p = 0; p < 1 + STPW/256; ++p){
    int base = lstore0 - 256 + p*256;
    if (base < 0) continue;                    // tile 0: no warm-up
    bool st = (base >= lstore0);
    int l = base + (lane<<2);
    int ga = rev ? (LL-4-l) : l;
    float r0[4], r1[4], r2[4], r3[4], r4[4], r5[4], g6b[4], g7b[4], xb[4];
    ld4(g + 0*(size_t)LL + ga, r0);
    ld4(g + 1*(size_t)LL + ga, r1);
    ld4(g + 2*(size_t)LL + ga, r2);
    ld4(g + 3*(size_t)LL + ga, r3);
    ld4(g + 4*(size_t)LL + ga, r4);
    ld4(g + 5*(size_t)LL + ga, r5);
    ld4(g + 6*(size_t)LL + ga, g6b);
    if (st) ld4(g + 7*(size_t)LL + ga, g7b);
    else { g7b[0]=0.f; g7b[1]=0.f; g7b[2]=0.f; g7b[3]=0.f; }
    ld4(src + ga, xb);
    if (rev){
      rev4(r0); rev4(r1); rev4(r2); rev4(r3); rev4(r4); rev4(r5);
      rev4(g6b); rev4(g7b); rev4(xb);
    }
    float av[4], bt[4];
    #pragma unroll
    for (int i = 0; i < 4; ++i){
      float dsum = dtb;
      dsum = fmaf(r0[i], dtw[0], dsum);
      dsum = fmaf(r1[i], dtw[1], dsum);
      dsum = fmaf(r2[i], dtw[2], dsum);
      dsum = fmaf(r3[i], dtw[3], dsum);
      dsum = fmaf(r4[i], dtw[4], dsum);
      dsum = fmaf(r5[i], dtw[5], dsum);
      // softplus in log2 domain: y = log2(1+2^(d*log2e)); delta = y*ln2; a = 2^(A*y)
      float dl2 = dsum*LOG2E;
      float y = flog2(1.f + fexp2(dl2));
      y = (dsum > 20.f) ? dl2 : y;
      float delta = y*LN2;
      av[i] = fexp2(A*y);
      bt[i] = delta * g6b[i] * xb[i];
    }
    float P = av[0], Q = bt[0];
    #pragma unroll
    for (int i = 1; i < 4; ++i){ Q = fmaf(av[i], Q, bt[i]); P *= av[i]; }
    #pragma unroll
    for (int off = 1; off < 64; off <<= 1){
      float Pp = __shfl_up(P, (unsigned)off);
      float Qp = __shfl_up(Q, (unsigned)off);
      if (lane >= off){ Q = fmaf(P, Qp, Q); P *= Pp; }
    }
    float Pe = __shfl_up(P, 1u), Qe = __shfl_up(Q, 1u);
    if (lane == 0){ Pe = 1.f; Qe = 0.f; }
    float h = fmaf(Pe, carry, Qe);
    if (st){
      float ys[4];
      #pragma unroll
      for (int i = 0; i < 4; ++i){
        h = fmaf(av[i], h, bt[i]);
        ys[i] = fmaf(g7b[i], h, Dv*xb[i]);
      }
      carry = __shfl(h, 63);
      if (rev) rev4(ys);
      *(float4*)&yout[ga] = make_float4(ys[0], ys[1], ys[2], ys[3]);
    } else {
      #pragma unroll
      for (int i = 0; i < 4; ++i) h = fmaf(av[i], h, bt[i]);
      carry = __shfl(h, 63);
    }
  }
}

// ---------------- combine: z = (y0+y2) + transpose(y1+y3) ----------------
__global__ void k_combine4(const float* __restrict__ Y, float* __restrict__ z){
  const size_t SZ = (size_t)BT*CC*LL;
  __shared__ float tile[32][33];
  int bc = blockIdx.z;
  const float* y1p = Y + SZ   + (size_t)bc*LL;
  const float* y3p = Y + 3*SZ + (size_t)bc*LL;
  int w0 = blockIdx.x*32, h0 = blockIdx.y*32;
  int tx = threadIdx.x, ty = threadIdx.y;
  #pragma unroll
  for (int kk = 0; kk < 4; ++kk){
    int w = w0 + ty + kk*8;
    size_t idx = (size_t)w*HH + h0 + tx;
    tile[ty + kk*8][tx] = y1p[idx] + y3p[idx];
  }
  __syncthreads();
  const float* y0p = Y +        (size_t)bc*LL;
  const float* y2p = Y + 2*SZ + (size_t)bc*LL;
  float* zp = z + (size_t)bc*LL;
  #pragma unroll
  for (int kk = 0; kk < 4; ++kk){
    int h = h0 + ty + kk*8;
    size_t idx = (size_t)h*WW + w0 + tx;
    zp[idx] = y0p[idx] + y2p[idx] + tile[tx][ty + kk*8];
  }
}

// ---------------- final output split/average ----------------
__global__ void k_output(const float* __restrict__ X, float* __restrict__ out){
  size_t i = (size_t)blockIdx.x*256 + threadIdx.x;
  size_t half = (size_t)2*CC*HH*128;
  if (i >= half) return;
  int w = i % 128; size_t r = i / 128;
  int h = r % HH; size_t bc = r / HH;
  size_t fwd = (bc*HH + h)*WW;
  size_t bwd = ((bc + (size_t)2*CC)*HH + h)*WW;
  out[i]        = 0.5f*(X[fwd + w]       + X[bwd + (WW-1-w)]);
  out[half + i] = 0.5f*(X[fwd + 128 + w] + X[bwd + (127 - w)]);
}

extern "C" void kernel_launch(void* const* d_in, const int* in_sizes, int n_in,
                              void* d_out, int out_size, void* d_ws, size_t ws_size,
                              hipStream_t stream){
  const float* x0        = (const float*)d_in[0];
  const float* x1        = (const float*)d_in[1];
  const float* norm_w    = (const float*)d_in[2];
  const float* norm_b    = (const float*)d_in[3];
  const float* in_proj_w = (const float*)d_in[4];
  const float* conv_w    = (const float*)d_in[5];
  const float* x_proj_w  = (const float*)d_in[6];
  const float* dt_w      = (const float*)d_in[7];
  const float* dt_b      = (const float*)d_in[8];
  const float* A_logs    = (const float*)d_in[9];
  const float* Ds        = (const float*)d_in[10];
  const float* out_norm_w= (const float*)d_in[11];
  const float* out_norm_b= (const float*)d_in[12];
  const float* out_proj_w= (const float*)d_in[13];
  const float* norm2_w   = (const float*)d_in[14];
  const float* norm2_b   = (const float*)d_in[15];
  const float* fc1_w     = (const float*)d_in[16];
  const float* fc1_b     = (const float*)d_in[17];
  const float* fc2_w     = (const float*)d_in[18];
  const float* fc2_b     = (const float*)d_in[19];

  const size_t SZ = (size_t)BT*CC*LL;            // 6,291,456 floats
  float* X  = (float*)d_ws;
  float* t  = X + SZ;
  float* u  = t + SZ;
  float* G  = u + SZ;                            // BT*KD*8*LL floats
  float* v  = G + (size_t)BT*KD*8*LL;
  float* vT = v + SZ;
  float* Y  = vT + SZ;                           // 4 contiguous SZ buffers
  u16*   XT  = (u16*)Y;                          // bf16T [BT*LL][104] (phase-disjoint w/ Y0)
  u16*   tT  = (u16*)u;                          // bf16T of t (u dead by then)
  float* ext = Y + 4*SZ;
  float* stats_X = ext;                          // 2*BT*LL
  float* stats_t = stats_X + 2*(size_t)BT*LL;
  float* wsl     = stats_t + 2*(size_t)BT*LL;    // weight slots: NLAY * SLOTF floats

  float* p0 = wsl;
  u16*  WbI0 = (u16*)p0;          float* s1I0 = p0 + 4608;  float* cI0 = p0 + 4704;
  u16*  WbO0 = (u16*)(p0+4800);   float* s1O0 = p0 + 9408;  float* cO0 = p0 + 9504;
  u16*  Wb10 = (u16*)(p0+9600);   float* s110 = p0 + 28032; float* c10 = p0 + 28416;
  u16*  Wb20 = (u16*)(p0+28800);  float* s120 = p0 + 47232; float* c20 = p0 + 47328;

  k_prepw<96,96,false,true,false><<<dim3(2,NLAY),64,0,stream>>>(in_proj_w, norm_w, norm_b, nullptr, WbI0, s1I0, cI0);
  k_prepw<96,96,false,true,false><<<dim3(2,NLAY),64,0,stream>>>(out_proj_w, out_norm_w, out_norm_b, nullptr, WbO0, s1O0, cO0);
  k_prepw<384,96,true,true,true><<<dim3(6,NLAY),64,0,stream>>>(fc1_w, norm2_w, norm2_b, fc1_b, Wb10, s110, c10);
  k_prepw<96,384,false,false,true><<<dim3(2,NLAY),64,0,stream>>>(fc2_w, nullptr, nullptr, fc2_b, Wb20, s120, c20);

  k_build<<<(2*CC*HH*WW + 255)/256, 256, 0, stream>>>(x0, x1, X);
  k_pack<true><<<dim3(LL/32, BT), 256, 0, stream>>>(X, XT, stats_X);

  for (int lay = 0; lay < NLAY; ++lay){
    size_t so = (size_t)lay*SLOTF;
    const u16* WbI = WbI0 + so*2; const float* s1I = s1I0 + so; const float* cI = cI0 + so;
    const u16* WbO = WbO0 + so*2; const float* s1O = s1O0 + so; const float* cO = cO0 + so;
    const u16* Wb1 = Wb10 + so*2; const float* s11 = s110 + so; const float* c1 = c10 + so;
    const u16* Wb2 = Wb20 + so*2; const float* c2 = c20 + so;
    const float* cw  = conv_w    + (size_t)lay*CC*9;
    const float* xpw = x_proj_w  + (size_t)lay*KD*8*CC;
    const float* dw  = dt_w      + (size_t)lay*KD*CC*RR;
    const float* db  = dt_b      + (size_t)lay*KD*CC;
    const float* Al  = A_logs    + (size_t)lay*KD*CC;
    const float* Dp  = Ds        + (size_t)lay*KD*CC;

    // in_proj (LN fused): u = W' * X
    k_gmm2<true,false,true,false,false><<<dim3(BT*LL/64),256,0,stream>>>(
        WbI, XT, u, nullptr, s1I, cI, nullptr, stats_X, nullptr);
    k_dwconv_silu_t<<<dim3(8,2,BT*CC), 256, 0, stream>>>(u, v, vT, cw);
    k_xproj<<<dim3(BT*LL/256, 2), 256, 0, stream>>>(v, vT, G, xpw);
    k_scan3<<<dim3(2,768,2), 256, 0, stream>>>(G, v, vT, Y, dw, db, Al, Dp);
    k_combine4<<<dim3(8,2,BT*CC), dim3(32,8), 0, stream>>>(Y, t);
    k_pack<true><<<dim3(LL/32, BT), 256, 0, stream>>>(t, tT, stats_t);
    // out_proj (LN fused) + residual -> X (f32 + XT bf16 + stats_X)
    k_gmm2<true,true,true,true,true><<<dim3(BT*LL/64),256,0,stream>>>(
        WbO, tT, X, XT, s1O, cO, X, stats_t, stats_X);
    // fused MLP
    k_mlp<<<dim3(BT*LL/128),512,0,stream>>>(
        Wb1, Wb2, XT, X, XT, s11, c1, c2, stats_X, stats_X);
  }

  k_output<<<(unsigned)(((size_t)2*CC*HH*128 + 255)/256), 256, 0, stream>>>(X, (float*)d_out);
}

// Round 10
// 422.318 us; speedup vs baseline: 11.5919x; 1.1048x over previous
//
#include <hip/hip_runtime.h>
#include <cstdint>
#include <cstddef>

#define BT 4
#define CC 96
#define HH 64
#define WW 256
#define LL (HH*WW)    // 16384
#define KD 4
#define RR 6
#define NLAY 2
#define C4 (4*CC)     // 384
#define SLOTF 47424   // per-layer weight-slot stride in float units
#define STPW 2048     // scan: stored elems per wave

typedef unsigned short u16;
typedef __attribute__((ext_vector_type(8))) short bf16x8;
typedef __attribute__((ext_vector_type(4))) float f32x4;

__device__ __forceinline__ u16 f2bf(float f){
  unsigned u = __float_as_uint(f);
  unsigned r = (u + 0x7FFFu + ((u >> 16) & 1u)) >> 16;
  return (u16)r;
}
__device__ __forceinline__ float bf2f(u16 h){
  return __uint_as_float(((unsigned)h) << 16);
}
__device__ __forceinline__ unsigned pk_bf16(float lo, float hi){
  unsigned r;
  asm volatile("v_cvt_pk_bf16_f32 %0, %1, %2" : "=v"(r) : "v"(lo), "v"(hi));
  return r;
}
__device__ __forceinline__ float fexp2(float x){
  float r; asm("v_exp_f32 %0, %1" : "=v"(r) : "v"(x)); return r;
}
__device__ __forceinline__ float flog2(float x){
  float r; asm("v_log_f32 %0, %1" : "=v"(r) : "v"(x)); return r;
}
// tanh-approx GELU, division-free
__device__ __forceinline__ float gelu_f(float v){
  float t = v*v;
  float u = v*fmaf(0.0356774081f, t, 0.7978845608f);
  float e2 = __expf(2.f*u);
  float r = __builtin_amdgcn_rcpf(e2 + 1.f);
  return fmaf(-v, r, v);
}

// ---------------- build batched input ----------------
__global__ void k_build(const float* __restrict__ x0, const float* __restrict__ x1,
                        float* __restrict__ X){
  size_t i = (size_t)blockIdx.x*256 + threadIdx.x;
  size_t tot = (size_t)2*CC*HH*WW;
  if (i >= tot) return;
  int w = i % WW; size_t r = i / WW;
  int h = r % HH; size_t bc = r / HH;
  float val;
  if (w < 128) val = x0[(bc*HH + h)*128 + w];
  else         val = x1[(bc*HH + h)*128 + (w-128)];
  X[i] = val;
  size_t ib = ((bc + (size_t)2*CC)*HH + h)*WW + (WW-1-w);
  X[ib] = val;
}

// ---------------- pack [b][c][l] -> bf16T [b*LL+l][104] (+ LN stats), f32 or bf16 src ----------------
template<bool ST, typename T>
__global__ __launch_bounds__(256) void k_pack(const T* __restrict__ src,
      u16* __restrict__ dst, float* __restrict__ st){
  __shared__ float tl[CC][33];
  int tid = threadIdx.x;
  int l0 = blockIdx.x*32, b = blockIdx.y;
  for (int e = tid; e < CC*32; e += 256){
    int c = e >> 5, dl = e & 31;
    T raw = src[((size_t)b*CC + c)*LL + l0 + dl];
    float vv;
    if constexpr (sizeof(T) == 2) vv = bf2f((u16)raw); else vv = (float)raw;
    tl[c][dl] = vv;
  }
  __syncthreads();
  if (ST && tid < 32){
    float s = 0.f, ss = 0.f;
    for (int c = 0; c < CC; ++c){ float vv = tl[c][tid]; s += vv; ss += vv*vv; }
    float mu = s*(1.f/CC);
    float var = ss*(1.f/CC) - mu*mu;
    st[(size_t)b*LL + l0 + tid] = mu;
    st[(size_t)BT*LL + (size_t)b*LL + l0 + tid] = rsqrtf(var + 1e-5f);
  }
  int dl = tid >> 3, cg = tid & 7;
  u16* dp = dst + ((size_t)b*LL + l0 + dl)*104 + cg*12;
  #pragma unroll
  for (int q = 0; q < 3; ++q){
    ushort4 pk;
    pk.x = f2bf(tl[cg*12 + q*4 + 0][dl]);
    pk.y = f2bf(tl[cg*12 + q*4 + 1][dl]);
    pk.z = f2bf(tl[cg*12 + q*4 + 2][dl]);
    pk.w = f2bf(tl[cg*12 + q*4 + 3][dl]);
    *(ushort4*)(dp + q*4) = pk;
  }
}

// ---------------- weight prep: swizzle into MFMA-fragment order ----------------
template<int M, int K, bool FC1ORD, bool LNF, bool BIAS>
__global__ void k_prepw(const float* __restrict__ W, const float* __restrict__ lnw,
      const float* __restrict__ lnb, const float* __restrict__ bias,
      u16* __restrict__ Wb, float* __restrict__ s1, float* __restrict__ cadd){
  int lay = blockIdx.y;
  W += (size_t)lay*M*K;
  Wb += (size_t)lay*SLOTF*2;
  s1 += (size_t)lay*SLOTF;
  cadd += (size_t)lay*SLOTF;
  int m = blockIdx.x*64 + threadIdx.x;
  if (m >= M) return;
  int rowfrag = m >> 4, lr = m & 15;
  float s1v = 0.f, sbv = 0.f;
  for (int c = 0; c < K; ++c){
    float wv = W[(size_t)m*K + c];
    float wf = LNF ? wv*lnw[lay*K + c] : wv;
    u16 h = f2bf(wf);
    int colfrag = c >> 5, lg = (c >> 3) & 3, j = c & 7;
    int f;
    if (FC1ORD) f = (rowfrag/6)*18 + colfrag*6 + (rowfrag % 6);
    else        f = colfrag*(M/16) + rowfrag;
    Wb[(size_t)(f*64 + lg*16 + lr)*8 + j] = h;
    s1v += bf2f(h);
    if (LNF) sbv = fmaf(wv, lnb[lay*K + c], sbv);
  }
  if (BIAS) sbv += bias[lay*M + m];
  s1[m] = s1v;
  cadd[m] = sbv;
}

// ---------------- MFMA GEMM (M=96,K=96): 128px/block, LDS B, swizzled weights ----------------
template<bool LNF, bool RES, bool WF32, bool WBF, bool STATS>
__global__ __launch_bounds__(256) void k_gmm2(
    const u16* __restrict__ Wb, const u16* __restrict__ inT,
    float* __restrict__ outF, u16* __restrict__ outT,
    const float* __restrict__ s1v, const float* __restrict__ cadd,
    const float* __restrict__ res,
    const float* __restrict__ stI, float* __restrict__ stO){
  __shared__ u16 bt[128*104];
  int tid = threadIdx.x, lane = tid & 63, wid = tid >> 6;
  int l0 = blockIdx.x*128;
  int lr = lane & 15, lg = lane >> 4;
  const int4* bsrc = (const int4*)(inT + (size_t)l0*104);
  for (int i = tid; i < 1664; i += 256) ((int4*)bt)[i] = bsrc[i];
  __syncthreads();
  f32x4 acc[6][2];
  #pragma unroll
  for (int mf = 0; mf < 6; ++mf){ acc[mf][0] = (f32x4){0,0,0,0}; acc[mf][1] = (f32x4){0,0,0,0}; }
  #pragma unroll
  for (int ks = 0; ks < 3; ++ks){
    bf16x8 af[6];
    #pragma unroll
    for (int mf = 0; mf < 6; ++mf)
      af[mf] = *(const bf16x8*)(Wb + (size_t)((ks*6 + mf)*64 + lane)*8);
    bf16x8 bfr[2];
    #pragma unroll
    for (int ls = 0; ls < 2; ++ls)
      bfr[ls] = *(const bf16x8*)&bt[(wid*32 + ls*16 + lr)*104 + ks*32 + lg*8];
    #pragma unroll
    for (int mf = 0; mf < 6; ++mf)
      #pragma unroll
      for (int ls = 0; ls < 2; ++ls)
        acc[mf][ls] = __builtin_amdgcn_mfma_f32_16x16x32_bf16(af[mf], bfr[ls], acc[mf][ls], 0, 0, 0);
  }
  #pragma unroll
  for (int ls = 0; ls < 2; ++ls){
    int l = l0 + wid*32 + ls*16 + lr;
    int b = l >> 14, lb = l & (LL-1);
    float mu = 0.f, rs = 0.f;
    if (LNF){ mu = stI[l]; rs = stI[(size_t)BT*LL + l]; }
    float ssum = 0.f, ssq = 0.f;
    #pragma unroll
    for (int mf = 0; mf < 6; ++mf){
      float o[4];
      #pragma unroll
      for (int r = 0; r < 4; ++r){
        int mm = mf*16 + lg*4 + r;
        float vv = acc[mf][ls][r];
        if (LNF) vv = fmaf(rs, vv, fmaf(-mu*rs, s1v[mm], cadd[mm]));
        else     vv += cadd[mm];
        if (RES) vv += res[((size_t)b*96 + mm)*LL + lb];
        if (WF32) outF[((size_t)b*96 + mm)*LL + lb] = vv;
        if (STATS){ ssum += vv; ssq += vv*vv; }
        o[r] = vv;
      }
      if (WBF){
        ushort4 pk;
        pk.x = f2bf(o[0]); pk.y = f2bf(o[1]); pk.z = f2bf(o[2]); pk.w = f2bf(o[3]);
        *(ushort4*)(outT + (size_t)l*104 + mf*16 + lg*4) = pk;
      }
    }
    if (STATS){
      ssum += __shfl_xor(ssum, 16); ssq += __shfl_xor(ssq, 16);
      ssum += __shfl_xor(ssum, 32); ssq += __shfl_xor(ssq, 32);
      if (lane < 16){
        float mu2 = ssum*(1.f/CC);
        float var = ssq*(1.f/CC) - mu2*mu2;
        stO[l] = mu2;
        stO[(size_t)BT*LL + l] = rsqrtf(var + 1e-5f);
      }
    }
  }
}

// ---------------- fused MLP v4: 8 waves/block, coalesced swizzled weights ----------------
__global__ __launch_bounds__(512, 4) void k_mlp(
    const u16* __restrict__ Wb1, const u16* __restrict__ Wb2,
    const u16* __restrict__ XT, float* __restrict__ X, u16* __restrict__ XTout,
    const float* __restrict__ s11, const float* __restrict__ c1,
    const float* __restrict__ c2,
    const float* __restrict__ stI, float* __restrict__ stO){
  __shared__ u16 bt[128*104];
  __shared__ u16 hs[128*104];
  int tid = threadIdx.x, lane = tid & 63, wid = tid >> 6;   // wid 0..7
  int l0 = blockIdx.x*128;
  int lr = lane & 15, lg = lane >> 4;
  const int4* bsrc = (const int4*)(XT + (size_t)l0*104);
  for (int i = tid; i < 1664; i += 512) ((int4*)bt)[i] = bsrc[i];

  int l = l0 + wid*16 + lr;                    // this lane's pixel
  float mu = stI[l];
  float rs = stI[(size_t)BT*LL + l];
  float nmr = -mu*rs;
  __syncthreads();

  int hrow = (wid*16 + lr)*104;
  f32x4 acc2[6];
  #pragma unroll
  for (int mf = 0; mf < 6; ++mf) acc2[mf] = (f32x4){0,0,0,0};

  for (int cc = 0; cc < 4; ++cc){
    f32x4 acc1[6];
    #pragma unroll
    for (int mf = 0; mf < 6; ++mf) acc1[mf] = (f32x4){0,0,0,0};
    #pragma unroll
    for (int ks = 0; ks < 3; ++ks){
      bf16x8 af[6];
      #pragma unroll
      for (int mf = 0; mf < 6; ++mf)
        af[mf] = *(const bf16x8*)(Wb1 + (size_t)((cc*18 + ks*6 + mf)*64 + lane)*8);
      bf16x8 bfr = *(const bf16x8*)&bt[hrow + ks*32 + lg*8];
      #pragma unroll
      for (int mf = 0; mf < 6; ++mf)
        acc1[mf] = __builtin_amdgcn_mfma_f32_16x16x32_bf16(af[mf], bfr, acc1[mf], 0, 0, 0);
    }
    #pragma unroll
    for (int mf = 0; mf < 6; ++mf){
      float4 sv = *(const float4*)&s11[cc*96 + mf*16 + lg*4];
      float4 cv = *(const float4*)&c1 [cc*96 + mf*16 + lg*4];
      float g0 = gelu_f(fmaf(rs, acc1[mf][0], fmaf(nmr, sv.x, cv.x)));
      float g1 = gelu_f(fmaf(rs, acc1[mf][1], fmaf(nmr, sv.y, cv.y)));
      float g2 = gelu_f(fmaf(rs, acc1[mf][2], fmaf(nmr, sv.z, cv.z)));
      float g3 = gelu_f(fmaf(rs, acc1[mf][3], fmaf(nmr, sv.w, cv.w)));
      uint2 pw;
      pw.x = pk_bf16(g0, g1);
      pw.y = pk_bf16(g2, g3);
      *(uint2*)&hs[hrow + mf*16 + lg*4] = pw;
    }
    #pragma unroll
    for (int ks = 0; ks < 3; ++ks){
      bf16x8 a2[6];
      #pragma unroll
      for (int mf2 = 0; mf2 < 6; ++mf2)
        a2[mf2] = *(const bf16x8*)(Wb2 + (size_t)(((cc*3 + ks)*6 + mf2)*64 + lane)*8);
      bf16x8 bfr2 = *(const bf16x8*)&hs[hrow + ks*32 + lg*8];
      #pragma unroll
      for (int mf2 = 0; mf2 < 6; ++mf2)
        acc2[mf2] = __builtin_amdgcn_mfma_f32_16x16x32_bf16(a2[mf2], bfr2, acc2[mf2], 0, 0, 0);
    }
  }
  {
    int b = l >> 14, lb = l & (LL-1);
    float ssum = 0.f, ssq = 0.f;
    #pragma unroll
    for (int mf = 0; mf < 6; ++mf){
      float o[4];
      #pragma unroll
      for (int r = 0; r < 4; ++r){
        int mm = mf*16 + lg*4 + r;
        float vv = acc2[mf][r] + c2[mm];
        vv += X[((size_t)b*96 + mm)*LL + lb];
        X[((size_t)b*96 + mm)*LL + lb] = vv;
        ssum += vv; ssq += vv*vv;
        o[r] = vv;
      }
      ushort4 pk;
      pk.x = f2bf(o[0]); pk.y = f2bf(o[1]); pk.z = f2bf(o[2]); pk.w = f2bf(o[3]);
      *(ushort4*)(XTout + (size_t)l*104 + mf*16 + lg*4) = pk;
    }
    ssum += __shfl_xor(ssum, 16); ssq += __shfl_xor(ssq, 16);
    ssum += __shfl_xor(ssum, 32); ssq += __shfl_xor(ssq, 32);
    if (lane < 16){
      float mu2 = ssum*(1.f/CC);
      float var = ssq*(1.f/CC) - mu2*mu2;
      stO[l] = mu2;
      stO[(size_t)BT*LL + l] = rsqrtf(var + 1e-5f);
    }
  }
}

// ---------------- depthwise 3x3 + SiLU, fused transpose (writes v and vT) ----------------
__global__ __launch_bounds__(256) void k_dwconv_silu_t(const float* __restrict__ u,
      float* __restrict__ v, float* __restrict__ vT, const float* __restrict__ cw){
  __shared__ float tl[32][33];
  int bc = blockIdx.z;
  int c = bc % CC;
  int w0 = blockIdx.x*32, h0 = blockIdx.y*32;
  const float* up = u + (size_t)bc*LL;
  const float* k9 = cw + c*9;
  int t = threadIdx.x;
  int wl = (t & 7)*4, hl = t >> 3;
  int h = h0 + hl, w = w0 + wl;
  float acc[4] = {0.f,0.f,0.f,0.f};
  #pragma unroll
  for (int dh = -1; dh <= 1; ++dh){
    int h2 = h + dh;
    if (h2 < 0 || h2 >= HH) continue;
    const float* row = up + (size_t)h2*WW + w;
    float4 m = *(const float4*)row;
    float lft = (w > 0) ? row[-1] : 0.f;
    float rgt = (w + 4 < WW) ? row[4] : 0.f;
    float k0 = k9[(dh+1)*3], k1 = k9[(dh+1)*3+1], k2 = k9[(dh+1)*3+2];
    acc[0] += lft*k0 + m.x*k1 + m.y*k2;
    acc[1] += m.x*k0 + m.y*k1 + m.z*k2;
    acc[2] += m.y*k0 + m.z*k1 + m.w*k2;
    acc[3] += m.z*k0 + m.w*k1 + rgt*k2;
  }
  float4 ov;
  float* po = (float*)&ov;
  #pragma unroll
  for (int j = 0; j < 4; ++j){
    float a = acc[j];
    float e = __expf(-a);
    float s = a * __builtin_amdgcn_rcpf(1.f + e);
    po[j] = s;
    tl[wl + j][hl] = s;
  }
  *(float4*)&v[(size_t)bc*LL + (size_t)h*WW + w] = ov;
  __syncthreads();
  int ww = t >> 3, hh4 = (t & 7)*4;
  float4 o2 = make_float4(tl[ww][hh4], tl[ww][hh4+1], tl[ww][hh4+2], tl[ww][hh4+3]);
  *(float4*)&vT[(size_t)bc*LL + (size_t)(w0 + ww)*HH + h0 + hh4] = o2;
}

// ---------------- x-projection (both sources in one launch) ----------------
__global__ void k_xproj(const float* __restrict__ v, const float* __restrict__ vT,
                        float* __restrict__ G, const float* __restrict__ xpw){
  int which = blockIdx.y;
  const float* src = which ? vT : v;
  int kA = which ? 1 : 0, kB = which ? 3 : 2;
  size_t i = (size_t)blockIdx.x*256 + threadIdx.x;
  if (i >= (size_t)BT*LL) return;
  int b = (int)(i / LL), l = (int)(i % LL);
  const float* sp = src + (size_t)b*CC*LL + l;
  const float* wA = xpw + (size_t)kA*8*CC;
  const float* wB = xpw + (size_t)kB*8*CC;
  float aA[8], aB[8];
  #pragma unroll
  for (int d = 0; d < 8; ++d){ aA[d] = 0.f; aB[d] = 0.f; }
  for (int c = 0; c < CC; ++c){
    float xv = sp[(size_t)c*LL];
    #pragma unroll
    for (int d = 0; d < 8; ++d){
      aA[d] = fmaf(wA[d*CC + c], xv, aA[d]);
      aB[d] = fmaf(wB[d*CC + c], xv, aB[d]);
    }
  }
  float* gA = G + (((size_t)b*KD + kA)*8)*LL + l;
  float* gB = G + (((size_t)b*KD + kB)*8)*LL + l;
  #pragma unroll
  for (int d = 0; d < 8; ++d){ gA[(size_t)d*LL] = aA[d]; gB[(size_t)d*LL] = aB[d]; }
}

// ---------------- tile-parallel selective scan: 2048/wave, exp2-domain, bf16 out ----------------
__device__ __forceinline__ void ld4(const float* p, float* o){
  float4 t = *(const float4*)p; o[0]=t.x; o[1]=t.y; o[2]=t.z; o[3]=t.w;
}
__device__ __forceinline__ void rev4(float* a){
  float t0 = a[0]; a[0] = a[3]; a[3] = t0;
  float t1 = a[1]; a[1] = a[2]; a[2] = t1;
}

__global__ __launch_bounds__(256) void k_scan3(const float* __restrict__ G,
                       const float* __restrict__ v, const float* __restrict__ vT,
                       u16* __restrict__ Y,
                       const float* __restrict__ dtw_, const float* __restrict__ dtb_,
                       const float* __restrict__ Alog_, const float* __restrict__ Ds_){
  const size_t SZ = (size_t)BT*CC*LL;
  const float LOG2E = 1.4426950408889634f, LN2 = 0.6931471805599453f;
  int wid = threadIdx.x >> 6, lane = threadIdx.x & 63;
  int tile = blockIdx.x*4 + wid;               // 0..7
  int sy = blockIdx.y;
  bool rev = (blockIdx.z != 0);
  int c = sy % CC; int t2 = sy / CC; int kk = t2 & 1; int b = t2 >> 1;
  int k = (rev ? 2 : 0) + kk;
  const float* src = (kk ? vT : v) + ((size_t)b*CC + c)*LL;
  const float* g = G + (((size_t)b*KD + k)*8)*LL;
  float dtw[RR];
  #pragma unroll
  for (int r = 0; r < RR; ++r) dtw[r] = dtw_[((size_t)k*CC + c)*RR + r];
  float dtb = dtb_[k*CC + c];
  float A  = -__expf(Alog_[k*CC + c]);
  float Dv = Ds_[k*CC + c];
  u16* yout = Y + (size_t)k*SZ + ((size_t)b*CC + c)*LL;

  int lstore0 = tile*STPW;
  float carry = 0.f;
  for (int p = 0; p < 1 + STPW/256; ++p){
    int base = lstore0 - 256 + p*256;
    if (base < 0) continue;                    // tile 0: no warm-up
    bool st = (base >= lstore0);
    int l = base + (lane<<2);
    int ga = rev ? (LL-4-l) : l;
    float r0[4], r1[4], r2[4], r3[4], r4[4], r5[4], g6b[4], g7b[4], xb[4];
    ld4(g + 0*(size_t)LL + ga, r0);
    ld4(g + 1*(size_t)LL + ga, r1);
    ld4(g + 2*(size_t)LL + ga, r2);
    ld4(g + 3*(size_t)LL + ga, r3);
    ld4(g + 4*(size_t)LL + ga, r4);
    ld4(g + 5*(size_t)LL + ga, r5);
    ld4(g + 6*(size_t)LL + ga, g6b);
    if (st) ld4(g + 7*(size_t)LL + ga, g7b);
    else { g7b[0]=0.f; g7b[1]=0.f; g7b[2]=0.f; g7b[3]=0.f; }
    ld4(src + ga, xb);
    if (rev){
      rev4(r0); rev4(r1); rev4(r2); rev4(r3); rev4(r4); rev4(r5);
      rev4(g6b); rev4(g7b); rev4(xb);
    }
    float av[4], bt[4];
    #pragma unroll
    for (int i = 0; i < 4; ++i){
      float dsum = dtb;
      dsum = fmaf(r0[i], dtw[0], dsum);
      dsum = fmaf(r1[i], dtw[1], dsum);
      dsum = fmaf(r2[i], dtw[2], dsum);
      dsum = fmaf(r3[i], dtw[3], dsum);
      dsum = fmaf(r4[i], dtw[4], dsum);
      dsum = fmaf(r5[i], dtw[5], dsum);
      float dl2 = dsum*LOG2E;
      float y = flog2(1.f + fexp2(dl2));
      y = (dsum > 20.f) ? dl2 : y;
      float delta = y*LN2;
      av[i] = fexp2(A*y);
      bt[i] = delta * g6b[i] * xb[i];
    }
    float P = av[0], Q = bt[0];
    #pragma unroll
    for (int i = 1; i < 4; ++i){ Q = fmaf(av[i], Q, bt[i]); P *= av[i]; }
    #pragma unroll
    for (int off = 1; off < 64; off <<= 1){
      float Pp = __shfl_up(P, (unsigned)off);
      float Qp = __shfl_up(Q, (unsigned)off);
      if (lane >= off){ Q = fmaf(P, Qp, Q); P *= Pp; }
    }
    float Pe = __shfl_up(P, 1u), Qe = __shfl_up(Q, 1u);
    if (lane == 0){ Pe = 1.f; Qe = 0.f; }
    float h = fmaf(Pe, carry, Qe);
    if (st){
      float ys[4];
      #pragma unroll
      for (int i = 0; i < 4; ++i){
        h = fmaf(av[i], h, bt[i]);
        ys[i] = fmaf(g7b[i], h, Dv*xb[i]);
      }
      carry = __shfl(h, 63);
      if (rev) rev4(ys);
      uint2 pw;
      pw.x = pk_bf16(ys[0], ys[1]);
      pw.y = pk_bf16(ys[2], ys[3]);
      *(uint2*)&yout[ga] = pw;
    } else {
      #pragma unroll
      for (int i = 0; i < 4; ++i) h = fmaf(av[i], h, bt[i]);
      carry = __shfl(h, 63);
    }
  }
}

// ---------------- combine v2 (bf16 in/out): z = (y0+y2) + transpose(y1+y3) ----------------
__global__ __launch_bounds__(256) void k_combine4(const u16* __restrict__ Y, u16* __restrict__ z){
  const size_t SZ = (size_t)BT*CC*LL;
  __shared__ float tl[64][65];
  int bc = blockIdx.z;
  int w0 = blockIdx.x*64;
  int t = threadIdx.x;
  const u16* y1p = Y + SZ   + (size_t)bc*LL;
  const u16* y3p = Y + 3*SZ + (size_t)bc*LL;
  {
    int wl = t >> 2;            // 0..63
    int h0 = (t & 3)*16;        // 0,16,32,48
    size_t base = (size_t)(w0 + wl)*HH + h0;
    #pragma unroll
    for (int j = 0; j < 4; ++j){
      ushort4 a = *(const ushort4*)&y1p[base + j*4];
      ushort4 bq = *(const ushort4*)&y3p[base + j*4];
      tl[wl][h0 + j*4 + 0] = bf2f(a.x) + bf2f(bq.x);
      tl[wl][h0 + j*4 + 1] = bf2f(a.y) + bf2f(bq.y);
      tl[wl][h0 + j*4 + 2] = bf2f(a.z) + bf2f(bq.z);
      tl[wl][h0 + j*4 + 3] = bf2f(a.w) + bf2f(bq.w);
    }
  }
  __syncthreads();
  const u16* y0p = Y +        (size_t)bc*LL;
  const u16* y2p = Y + 2*SZ + (size_t)bc*LL;
  u16* zp = z + (size_t)bc*LL;
  {
    int h = t >> 2;             // 0..63
    int wq = (t & 3)*16;        // 0,16,32,48
    #pragma unroll
    for (int j = 0; j < 4; ++j){
      int wl = wq + j*4;
      size_t idx = (size_t)h*WW + w0 + wl;
      ushort4 a = *(const ushort4*)&y0p[idx];
      ushort4 bq = *(const ushort4*)&y2p[idx];
      ushort4 o;
      o.x = f2bf(bf2f(a.x) + bf2f(bq.x) + tl[wl+0][h]);
      o.y = f2bf(bf2f(a.y) + bf2f(bq.y) + tl[wl+1][h]);
      o.z = f2bf(bf2f(a.z) + bf2f(bq.z) + tl[wl+2][h]);
      o.w = f2bf(bf2f(a.w) + bf2f(bq.w) + tl[wl+3][h]);
      *(ushort4*)&zp[idx] = o;
    }
  }
}

// ---------------- final output split/average ----------------
__global__ void k_output(const float* __restrict__ X, float* __restrict__ out){
  size_t i = (size_t)blockIdx.x*256 + threadIdx.x;
  size_t half = (size_t)2*CC*HH*128;
  if (i >= half) return;
  int w = i % 128; size_t r = i / 128;
  int h = r % HH; size_t bc = r / HH;
  size_t fwd = (bc*HH + h)*WW;
  size_t bwd = ((bc + (size_t)2*CC)*HH + h)*WW;
  out[i]        = 0.5f*(X[fwd + w]       + X[bwd + (WW-1-w)]);
  out[half + i] = 0.5f*(X[fwd + 128 + w] + X[bwd + (127 - w)]);
}

extern "C" void kernel_launch(void* const* d_in, const int* in_sizes, int n_in,
                              void* d_out, int out_size, void* d_ws, size_t ws_size,
                              hipStream_t stream){
  const float* x0        = (const float*)d_in[0];
  const float* x1        = (const float*)d_in[1];
  const float* norm_w    = (const float*)d_in[2];
  const float* norm_b    = (const float*)d_in[3];
  const float* in_proj_w = (const float*)d_in[4];
  const float* conv_w    = (const float*)d_in[5];
  const float* x_proj_w  = (const float*)d_in[6];
  const float* dt_w      = (const float*)d_in[7];
  const float* dt_b      = (const float*)d_in[8];
  const float* A_logs    = (const float*)d_in[9];
  const float* Ds        = (const float*)d_in[10];
  const float* out_norm_w= (const float*)d_in[11];
  const float* out_norm_b= (const float*)d_in[12];
  const float* out_proj_w= (const float*)d_in[13];
  const float* norm2_w   = (const float*)d_in[14];
  const float* norm2_b   = (const float*)d_in[15];
  const float* fc1_w     = (const float*)d_in[16];
  const float* fc1_b     = (const float*)d_in[17];
  const float* fc2_w     = (const float*)d_in[18];
  const float* fc2_b     = (const float*)d_in[19];

  const size_t SZ = (size_t)BT*CC*LL;            // 6,291,456 floats
  float* X  = (float*)d_ws;
  float* t  = X + SZ;
  float* u  = t + SZ;
  float* G  = u + SZ;                            // BT*KD*8*LL floats
  float* v  = G + (size_t)BT*KD*8*LL;
  float* vT = v + SZ;
  float* Yf = vT + SZ;                           // region: 4*SZ floats (bf16 Y uses half)
  u16*   Yb = (u16*)Yf;                          // 4 contiguous SZ-u16 buffers
  u16*   XT = (u16*)Yf;                          // bf16T [BT*LL][104] (phase-disjoint w/ Yb)
  u16*   tB = (u16*)t;                           // bf16 t plane [b][c][l]
  u16*   tT = (u16*)u;                           // bf16T of t (u dead by then)
  float* ext = Yf + 4*SZ;
  float* stats_X = ext;                          // 2*BT*LL
  float* stats_t = stats_X + 2*(size_t)BT*LL;
  float* wsl     = stats_t + 2*(size_t)BT*LL;    // weight slots: NLAY * SLOTF floats

  float* p0 = wsl;
  u16*  WbI0 = (u16*)p0;          float* s1I0 = p0 + 4608;  float* cI0 = p0 + 4704;
  u16*  WbO0 = (u16*)(p0+4800);   float* s1O0 = p0 + 9408;  float* cO0 = p0 + 9504;
  u16*  Wb10 = (u16*)(p0+9600);   float* s110 = p0 + 28032; float* c10 = p0 + 28416;
  u16*  Wb20 = (u16*)(p0+28800);  float* s120 = p0 + 47232; float* c20 = p0 + 47328;

  k_prepw<96,96,false,true,false><<<dim3(2,NLAY),64,0,stream>>>(in_proj_w, norm_w, norm_b, nullptr, WbI0, s1I0, cI0);
  k_prepw<96,96,false,true,false><<<dim3(2,NLAY),64,0,stream>>>(out_proj_w, out_norm_w, out_norm_b, nullptr, WbO0, s1O0, cO0);
  k_prepw<384,96,true,true,true><<<dim3(6,NLAY),64,0,stream>>>(fc1_w, norm2_w, norm2_b, fc1_b, Wb10, s110, c10);
  k_prepw<96,384,false,false,true><<<dim3(2,NLAY),64,0,stream>>>(fc2_w, nullptr, nullptr, fc2_b, Wb20, s120, c20);

  k_build<<<(2*CC*HH*WW + 255)/256, 256, 0, stream>>>(x0, x1, X);
  k_pack<true,float><<<dim3(LL/32, BT), 256, 0, stream>>>(X, XT, stats_X);

  for (int lay = 0; lay < NLAY; ++lay){
    size_t so = (size_t)lay*SLOTF;
    const u16* WbI = WbI0 + so*2; const float* s1I = s1I0 + so; const float* cI = cI0 + so;
    const u16* WbO = WbO0 + so*2; const float* s1O = s1O0 + so; const float* cO = cO0 + so;
    const u16* Wb1 = Wb10 + so*2; const float* s11 = s110 + so; const float* c1 = c10 + so;
    const u16* Wb2 = Wb20 + so*2; const float* c2 = c20 + so;
    const float* cw  = conv_w    + (size_t)lay*CC*9;
    const float* xpw = x_proj_w  + (size_t)lay*KD*8*CC;
    const float* dw  = dt_w      + (size_t)lay*KD*CC*RR;
    const float* db  = dt_b      + (size_t)lay*KD*CC;
    const float* Al  = A_logs    + (size_t)lay*KD*CC;
    const float* Dp  = Ds        + (size_t)lay*KD*CC;

    // in_proj (LN fused): u = W' * X
    k_gmm2<true,false,true,false,false><<<dim3(BT*LL/128),256,0,stream>>>(
        WbI, XT, u, nullptr, s1I, cI, nullptr, stats_X, nullptr);
    k_dwconv_silu_t<<<dim3(8,2,BT*CC), 256, 0, stream>>>(u, v, vT, cw);
    k_xproj<<<dim3(BT*LL/256, 2), 256, 0, stream>>>(v, vT, G, xpw);
    k_scan3<<<dim3(2,768,2), 256, 0, stream>>>(G, v, vT, Yb, dw, db, Al, Dp);
    k_combine4<<<dim3(4,1,BT*CC), 256, 0, stream>>>(Yb, tB);
    k_pack<true,u16><<<dim3(LL/32, BT), 256, 0, stream>>>(tB, tT, stats_t);
    // out_proj (LN fused) + residual -> X (f32 + XT bf16 + stats_X)
    k_gmm2<true,true,true,true,true><<<dim3(BT*LL/128),256,0,stream>>>(
        WbO, tT, X, XT, s1O, cO, X, stats_t, stats_X);
    // fused MLP
    k_mlp<<<dim3(BT*LL/128),512,0,stream>>>(
        Wb1, Wb2, XT, X, XT, s11, c1, c2, stats_X, stats_X);
  }

  k_output<<<(unsigned)(((size_t)2*CC*HH*128 + 255)/256), 256, 0, stream>>>(X, (float*)d_out);
}

// Round 11
// 420.999 us; speedup vs baseline: 11.6282x; 1.0031x over previous
//
#include <hip/hip_runtime.h>
#include <cstdint>
#include <cstddef>

#define BT 4
#define CC 96
#define HH 64
#define WW 256
#define LL (HH*WW)    // 16384
#define KD 4
#define RR 6
#define NLAY 2
#define C4 (4*CC)     // 384
#define SLOTF 47424   // per-layer weight-slot stride in float units
#define STPW 2048     // scan: stored elems per wave

typedef unsigned short u16;
typedef __attribute__((ext_vector_type(8))) short bf16x8;
typedef __attribute__((ext_vector_type(4))) float f32x4;

__device__ __forceinline__ u16 f2bf(float f){
  unsigned u = __float_as_uint(f);
  unsigned r = (u + 0x7FFFu + ((u >> 16) & 1u)) >> 16;
  return (u16)r;
}
__device__ __forceinline__ float bf2f(u16 h){
  return __uint_as_float(((unsigned)h) << 16);
}
__device__ __forceinline__ unsigned pk_bf16(float lo, float hi){
  unsigned r;
  asm volatile("v_cvt_pk_bf16_f32 %0, %1, %2" : "=v"(r) : "v"(lo), "v"(hi));
  return r;
}
__device__ __forceinline__ float fexp2(float x){
  float r; asm("v_exp_f32 %0, %1" : "=v"(r) : "v"(x)); return r;
}
__device__ __forceinline__ float flog2(float x){
  float r; asm("v_log_f32 %0, %1" : "=v"(r) : "v"(x)); return r;
}
// tanh-approx GELU, division-free
__device__ __forceinline__ float gelu_f(float v){
  float t = v*v;
  float u = v*fmaf(0.0356774081f, t, 0.7978845608f);
  float e2 = __expf(2.f*u);
  float r = __builtin_amdgcn_rcpf(e2 + 1.f);
  return fmaf(-v, r, v);
}

// ---------------- build batched input ----------------
__global__ void k_build(const float* __restrict__ x0, const float* __restrict__ x1,
                        float* __restrict__ X){
  size_t i = (size_t)blockIdx.x*256 + threadIdx.x;
  size_t tot = (size_t)2*CC*HH*WW;
  if (i >= tot) return;
  int w = i % WW; size_t r = i / WW;
  int h = r % HH; size_t bc = r / HH;
  float val;
  if (w < 128) val = x0[(bc*HH + h)*128 + w];
  else         val = x1[(bc*HH + h)*128 + (w-128)];
  X[i] = val;
  size_t ib = ((bc + (size_t)2*CC)*HH + h)*WW + (WW-1-w);
  X[ib] = val;
}

// ---------------- pack [b][c][l] -> bf16T [b*LL+l][104] (+ LN stats), f32 or bf16 src ----------------
template<bool ST, typename T>
__global__ __launch_bounds__(256) void k_pack(const T* __restrict__ src,
      u16* __restrict__ dst, float* __restrict__ st){
  __shared__ float tl[CC][33];
  int tid = threadIdx.x;
  int l0 = blockIdx.x*32, b = blockIdx.y;
  for (int e = tid; e < CC*32; e += 256){
    int c = e >> 5, dl = e & 31;
    T raw = src[((size_t)b*CC + c)*LL + l0 + dl];
    float vv;
    if constexpr (sizeof(T) == 2) vv = bf2f((u16)raw); else vv = (float)raw;
    tl[c][dl] = vv;
  }
  __syncthreads();
  if (ST && tid < 32){
    float s = 0.f, ss = 0.f;
    for (int c = 0; c < CC; ++c){ float vv = tl[c][tid]; s += vv; ss += vv*vv; }
    float mu = s*(1.f/CC);
    float var = ss*(1.f/CC) - mu*mu;
    st[(size_t)b*LL + l0 + tid] = mu;
    st[(size_t)BT*LL + (size_t)b*LL + l0 + tid] = rsqrtf(var + 1e-5f);
  }
  int dl = tid >> 3, cg = tid & 7;
  u16* dp = dst + ((size_t)b*LL + l0 + dl)*104 + cg*12;
  #pragma unroll
  for (int q = 0; q < 3; ++q){
    ushort4 pk;
    pk.x = f2bf(tl[cg*12 + q*4 + 0][dl]);
    pk.y = f2bf(tl[cg*12 + q*4 + 1][dl]);
    pk.z = f2bf(tl[cg*12 + q*4 + 2][dl]);
    pk.w = f2bf(tl[cg*12 + q*4 + 3][dl]);
    *(ushort4*)(dp + q*4) = pk;
  }
}

// ---------------- weight prep: swizzle into MFMA-fragment order ----------------
template<int M, int K, bool FC1ORD, bool LNF, bool BIAS>
__global__ void k_prepw(const float* __restrict__ W, const float* __restrict__ lnw,
      const float* __restrict__ lnb, const float* __restrict__ bias,
      u16* __restrict__ Wb, float* __restrict__ s1, float* __restrict__ cadd){
  int lay = blockIdx.y;
  W += (size_t)lay*M*K;
  Wb += (size_t)lay*SLOTF*2;
  s1 += (size_t)lay*SLOTF;
  cadd += (size_t)lay*SLOTF;
  int m = blockIdx.x*64 + threadIdx.x;
  if (m >= M) return;
  int rowfrag = m >> 4, lr = m & 15;
  float s1v = 0.f, sbv = 0.f;
  for (int c = 0; c < K; ++c){
    float wv = W[(size_t)m*K + c];
    float wf = LNF ? wv*lnw[lay*K + c] : wv;
    u16 h = f2bf(wf);
    int colfrag = c >> 5, lg = (c >> 3) & 3, j = c & 7;
    int f;
    if (FC1ORD) f = (rowfrag/6)*18 + colfrag*6 + (rowfrag % 6);
    else        f = colfrag*(M/16) + rowfrag;
    Wb[(size_t)(f*64 + lg*16 + lr)*8 + j] = h;
    s1v += bf2f(h);
    if (LNF) sbv = fmaf(wv, lnb[lay*K + c], sbv);
  }
  if (BIAS) sbv += bias[lay*M + m];
  s1[m] = s1v;
  cadd[m] = sbv;
}

// ---------------- MFMA GEMM (M=96,K=96): 128px/block, LDS B, swizzled weights ----------------
template<bool LNF, bool RES, bool WF32, bool WBF, bool STATS, bool WPB>
__global__ __launch_bounds__(256) void k_gmm2(
    const u16* __restrict__ Wb, const u16* __restrict__ inT,
    float* __restrict__ outF, u16* __restrict__ outT,
    const float* __restrict__ s1v, const float* __restrict__ cadd,
    const float* __restrict__ res,
    const float* __restrict__ stI, float* __restrict__ stO,
    u16* __restrict__ outPB){
  __shared__ u16 bt[128*104];
  int tid = threadIdx.x, lane = tid & 63, wid = tid >> 6;
  int l0 = blockIdx.x*128;
  int lr = lane & 15, lg = lane >> 4;
  const int4* bsrc = (const int4*)(inT + (size_t)l0*104);
  for (int i = tid; i < 1664; i += 256) ((int4*)bt)[i] = bsrc[i];
  __syncthreads();
  f32x4 acc[6][2];
  #pragma unroll
  for (int mf = 0; mf < 6; ++mf){ acc[mf][0] = (f32x4){0,0,0,0}; acc[mf][1] = (f32x4){0,0,0,0}; }
  #pragma unroll
  for (int ks = 0; ks < 3; ++ks){
    bf16x8 af[6];
    #pragma unroll
    for (int mf = 0; mf < 6; ++mf)
      af[mf] = *(const bf16x8*)(Wb + (size_t)((ks*6 + mf)*64 + lane)*8);
    bf16x8 bfr[2];
    #pragma unroll
    for (int ls = 0; ls < 2; ++ls)
      bfr[ls] = *(const bf16x8*)&bt[(wid*32 + ls*16 + lr)*104 + ks*32 + lg*8];
    #pragma unroll
    for (int mf = 0; mf < 6; ++mf)
      #pragma unroll
      for (int ls = 0; ls < 2; ++ls)
        acc[mf][ls] = __builtin_amdgcn_mfma_f32_16x16x32_bf16(af[mf], bfr[ls], acc[mf][ls], 0, 0, 0);
  }
  #pragma unroll
  for (int ls = 0; ls < 2; ++ls){
    int l = l0 + wid*32 + ls*16 + lr;
    int b = l >> 14, lb = l & (LL-1);
    float mu = 0.f, rs = 0.f;
    if (LNF){ mu = stI[l]; rs = stI[(size_t)BT*LL + l]; }
    float ssum = 0.f, ssq = 0.f;
    #pragma unroll
    for (int mf = 0; mf < 6; ++mf){
      float o[4];
      #pragma unroll
      for (int r = 0; r < 4; ++r){
        int mm = mf*16 + lg*4 + r;
        float vv = acc[mf][ls][r];
        if (LNF) vv = fmaf(rs, vv, fmaf(-mu*rs, s1v[mm], cadd[mm]));
        else     vv += cadd[mm];
        if (RES) vv += res[((size_t)b*96 + mm)*LL + lb];
        if (WF32) outF[((size_t)b*96 + mm)*LL + lb] = vv;
        if (WPB)  outPB[((size_t)b*96 + mm)*LL + lb] = f2bf(vv);
        if (STATS){ ssum += vv; ssq += vv*vv; }
        o[r] = vv;
      }
      if (WBF){
        ushort4 pk;
        pk.x = f2bf(o[0]); pk.y = f2bf(o[1]); pk.z = f2bf(o[2]); pk.w = f2bf(o[3]);
        *(ushort4*)(outT + (size_t)l*104 + mf*16 + lg*4) = pk;
      }
    }
    if (STATS){
      ssum += __shfl_xor(ssum, 16); ssq += __shfl_xor(ssq, 16);
      ssum += __shfl_xor(ssum, 32); ssq += __shfl_xor(ssq, 32);
      if (lane < 16){
        float mu2 = ssum*(1.f/CC);
        float var = ssq*(1.f/CC) - mu2*mu2;
        stO[l] = mu2;
        stO[(size_t)BT*LL + l] = rsqrtf(var + 1e-5f);
      }
    }
  }
}

// ---------------- fused MLP v4: 8 waves/block, coalesced swizzled weights ----------------
__global__ __launch_bounds__(512, 4) void k_mlp(
    const u16* __restrict__ Wb1, const u16* __restrict__ Wb2,
    const u16* __restrict__ XT, float* __restrict__ X, u16* __restrict__ XTout,
    const float* __restrict__ s11, const float* __restrict__ c1,
    const float* __restrict__ c2,
    const float* __restrict__ stI, float* __restrict__ stO){
  __shared__ u16 bt[128*104];
  __shared__ u16 hs[128*104];
  int tid = threadIdx.x, lane = tid & 63, wid = tid >> 6;   // wid 0..7
  int l0 = blockIdx.x*128;
  int lr = lane & 15, lg = lane >> 4;
  const int4* bsrc = (const int4*)(XT + (size_t)l0*104);
  for (int i = tid; i < 1664; i += 512) ((int4*)bt)[i] = bsrc[i];

  int l = l0 + wid*16 + lr;                    // this lane's pixel
  float mu = stI[l];
  float rs = stI[(size_t)BT*LL + l];
  float nmr = -mu*rs;
  __syncthreads();

  int hrow = (wid*16 + lr)*104;
  f32x4 acc2[6];
  #pragma unroll
  for (int mf = 0; mf < 6; ++mf) acc2[mf] = (f32x4){0,0,0,0};

  for (int cc = 0; cc < 4; ++cc){
    f32x4 acc1[6];
    #pragma unroll
    for (int mf = 0; mf < 6; ++mf) acc1[mf] = (f32x4){0,0,0,0};
    #pragma unroll
    for (int ks = 0; ks < 3; ++ks){
      bf16x8 af[6];
      #pragma unroll
      for (int mf = 0; mf < 6; ++mf)
        af[mf] = *(const bf16x8*)(Wb1 + (size_t)((cc*18 + ks*6 + mf)*64 + lane)*8);
      bf16x8 bfr = *(const bf16x8*)&bt[hrow + ks*32 + lg*8];
      #pragma unroll
      for (int mf = 0; mf < 6; ++mf)
        acc1[mf] = __builtin_amdgcn_mfma_f32_16x16x32_bf16(af[mf], bfr, acc1[mf], 0, 0, 0);
    }
    #pragma unroll
    for (int mf = 0; mf < 6; ++mf){
      float4 sv = *(const float4*)&s11[cc*96 + mf*16 + lg*4];
      float4 cv = *(const float4*)&c1 [cc*96 + mf*16 + lg*4];
      float g0 = gelu_f(fmaf(rs, acc1[mf][0], fmaf(nmr, sv.x, cv.x)));
      float g1 = gelu_f(fmaf(rs, acc1[mf][1], fmaf(nmr, sv.y, cv.y)));
      float g2 = gelu_f(fmaf(rs, acc1[mf][2], fmaf(nmr, sv.z, cv.z)));
      float g3 = gelu_f(fmaf(rs, acc1[mf][3], fmaf(nmr, sv.w, cv.w)));
      uint2 pw;
      pw.x = pk_bf16(g0, g1);
      pw.y = pk_bf16(g2, g3);
      *(uint2*)&hs[hrow + mf*16 + lg*4] = pw;
    }
    #pragma unroll
    for (int ks = 0; ks < 3; ++ks){
      bf16x8 a2[6];
      #pragma unroll
      for (int mf2 = 0; mf2 < 6; ++mf2)
        a2[mf2] = *(const bf16x8*)(Wb2 + (size_t)(((cc*3 + ks)*6 + mf2)*64 + lane)*8);
      bf16x8 bfr2 = *(const bf16x8*)&hs[hrow + ks*32 + lg*8];
      #pragma unroll
      for (int mf2 = 0; mf2 < 6; ++mf2)
        acc2[mf2] = __builtin_amdgcn_mfma_f32_16x16x32_bf16(a2[mf2], bfr2, acc2[mf2], 0, 0, 0);
    }
  }
  {
    int b = l >> 14, lb = l & (LL-1);
    float ssum = 0.f, ssq = 0.f;
    #pragma unroll
    for (int mf = 0; mf < 6; ++mf){
      float o[4];
      #pragma unroll
      for (int r = 0; r < 4; ++r){
        int mm = mf*16 + lg*4 + r;
        float vv = acc2[mf][r] + c2[mm];
        vv += X[((size_t)b*96 + mm)*LL + lb];
        X[((size_t)b*96 + mm)*LL + lb] = vv;
        ssum += vv; ssq += vv*vv;
        o[r] = vv;
      }
      ushort4 pk;
      pk.x = f2bf(o[0]); pk.y = f2bf(o[1]); pk.z = f2bf(o[2]); pk.w = f2bf(o[3]);
      *(ushort4*)(XTout + (size_t)l*104 + mf*16 + lg*4) = pk;
    }
    ssum += __shfl_xor(ssum, 16); ssq += __shfl_xor(ssq, 16);
    ssum += __shfl_xor(ssum, 32); ssq += __shfl_xor(ssq, 32);
    if (lane < 16){
      float mu2 = ssum*(1.f/CC);
      float var = ssq*(1.f/CC) - mu2*mu2;
      stO[l] = mu2;
      stO[(size_t)BT*LL + l] = rsqrtf(var + 1e-5f);
    }
  }
}

// ---------------- depthwise 3x3 + SiLU (bf16 in/out), fused transpose ----------------
__global__ __launch_bounds__(256) void k_dwconv_silu_t(const u16* __restrict__ u,
      u16* __restrict__ v, u16* __restrict__ vT, const float* __restrict__ cw){
  __shared__ float tl[32][33];
  int bc = blockIdx.z;
  int c = bc % CC;
  int w0 = blockIdx.x*32, h0 = blockIdx.y*32;
  const u16* up = u + (size_t)bc*LL;
  const float* k9 = cw + c*9;
  int t = threadIdx.x;
  int wl = (t & 7)*4, hl = t >> 3;
  int h = h0 + hl, w = w0 + wl;
  float acc[4] = {0.f,0.f,0.f,0.f};
  #pragma unroll
  for (int dh = -1; dh <= 1; ++dh){
    int h2 = h + dh;
    if (h2 < 0 || h2 >= HH) continue;
    const u16* row = up + (size_t)h2*WW + w;
    ushort4 mq = *(const ushort4*)row;
    float m0 = bf2f(mq.x), m1 = bf2f(mq.y), m2 = bf2f(mq.z), m3 = bf2f(mq.w);
    float lft = (w > 0) ? bf2f(row[-1]) : 0.f;
    float rgt = (w + 4 < WW) ? bf2f(row[4]) : 0.f;
    float k0 = k9[(dh+1)*3], k1 = k9[(dh+1)*3+1], k2 = k9[(dh+1)*3+2];
    acc[0] += lft*k0 + m0*k1 + m1*k2;
    acc[1] += m0*k0 + m1*k1 + m2*k2;
    acc[2] += m1*k0 + m2*k1 + m3*k2;
    acc[3] += m2*k0 + m3*k1 + rgt*k2;
  }
  float s[4];
  #pragma unroll
  for (int j = 0; j < 4; ++j){
    float a = acc[j];
    float e = __expf(-a);
    s[j] = a * __builtin_amdgcn_rcpf(1.f + e);
    tl[wl + j][hl] = s[j];
  }
  uint2 pw;
  pw.x = pk_bf16(s[0], s[1]);
  pw.y = pk_bf16(s[2], s[3]);
  *(uint2*)&v[(size_t)bc*LL + (size_t)h*WW + w] = pw;
  __syncthreads();
  int ww = t >> 3, hh4 = (t & 7)*4;
  uint2 po;
  po.x = pk_bf16(tl[ww][hh4],   tl[ww][hh4+1]);
  po.y = pk_bf16(tl[ww][hh4+2], tl[ww][hh4+3]);
  *(uint2*)&vT[(size_t)bc*LL + (size_t)(w0 + ww)*HH + h0 + hh4] = po;
}

// ---------------- x-projection (bf16 src, both sources in one launch) ----------------
__global__ void k_xproj(const u16* __restrict__ v, const u16* __restrict__ vT,
                        float* __restrict__ G, const float* __restrict__ xpw){
  int which = blockIdx.y;
  const u16* src = which ? vT : v;
  int kA = which ? 1 : 0, kB = which ? 3 : 2;
  size_t i = (size_t)blockIdx.x*256 + threadIdx.x;
  if (i >= (size_t)BT*LL) return;
  int b = (int)(i / LL), l = (int)(i % LL);
  const u16* sp = src + (size_t)b*CC*LL + l;
  const float* wA = xpw + (size_t)kA*8*CC;
  const float* wB = xpw + (size_t)kB*8*CC;
  float aA[8], aB[8];
  #pragma unroll
  for (int d = 0; d < 8; ++d){ aA[d] = 0.f; aB[d] = 0.f; }
  for (int c = 0; c < CC; ++c){
    float xv = bf2f(sp[(size_t)c*LL]);
    #pragma unroll
    for (int d = 0; d < 8; ++d){
      aA[d] = fmaf(wA[d*CC + c], xv, aA[d]);
      aB[d] = fmaf(wB[d*CC + c], xv, aB[d]);
    }
  }
  float* gA = G + (((size_t)b*KD + kA)*8)*LL + l;
  float* gB = G + (((size_t)b*KD + kB)*8)*LL + l;
  #pragma unroll
  for (int d = 0; d < 8; ++d){ gA[(size_t)d*LL] = aA[d]; gB[(size_t)d*LL] = aB[d]; }
}

// ---------------- tile-parallel selective scan: 2048/wave, exp2-domain, bf16 in/out ----------------
__device__ __forceinline__ void ld4(const float* p, float* o){
  float4 t = *(const float4*)p; o[0]=t.x; o[1]=t.y; o[2]=t.z; o[3]=t.w;
}
__device__ __forceinline__ void ldb4(const u16* p, float* o){
  ushort4 t = *(const ushort4*)p;
  o[0]=bf2f(t.x); o[1]=bf2f(t.y); o[2]=bf2f(t.z); o[3]=bf2f(t.w);
}
__device__ __forceinline__ void rev4(float* a){
  float t0 = a[0]; a[0] = a[3]; a[3] = t0;
  float t1 = a[1]; a[1] = a[2]; a[2] = t1;
}

__global__ __launch_bounds__(256) void k_scan3(const float* __restrict__ G,
                       const u16* __restrict__ v, const u16* __restrict__ vT,
                       u16* __restrict__ Y,
                       const float* __restrict__ dtw_, const float* __restrict__ dtb_,
                       const float* __restrict__ Alog_, const float* __restrict__ Ds_){
  const size_t SZ = (size_t)BT*CC*LL;
  const float LOG2E = 1.4426950408889634f, LN2 = 0.6931471805599453f;
  int wid = threadIdx.x >> 6, lane = threadIdx.x & 63;
  int tile = blockIdx.x*4 + wid;               // 0..7
  int sy = blockIdx.y;
  bool rev = (blockIdx.z != 0);
  int c = sy % CC; int t2 = sy / CC; int kk = t2 & 1; int b = t2 >> 1;
  int k = (rev ? 2 : 0) + kk;
  const u16* src = (kk ? vT : v) + ((size_t)b*CC + c)*LL;
  const float* g = G + (((size_t)b*KD + k)*8)*LL;
  float dtw[RR];
  #pragma unroll
  for (int r = 0; r < RR; ++r) dtw[r] = dtw_[((size_t)k*CC + c)*RR + r];
  float dtb = dtb_[k*CC + c];
  float A  = -__expf(Alog_[k*CC + c]);
  float Dv = Ds_[k*CC + c];
  u16* yout = Y + (size_t)k*SZ + ((size_t)b*CC + c)*LL;

  int lstore0 = tile*STPW;
  float carry = 0.f;
  for (int p = 0; p < 1 + STPW/256; ++p){
    int base = lstore0 - 256 + p*256;
    if (base < 0) continue;                    // tile 0: no warm-up
    bool st = (base >= lstore0);
    int l = base + (lane<<2);
    int ga = rev ? (LL-4-l) : l;
    float r0[4], r1[4], r2[4], r3[4], r4[4], r5[4], g6b[4], g7b[4], xb[4];
    ld4(g + 0*(size_t)LL + ga, r0);
    ld4(g + 1*(size_t)LL + ga, r1);
    ld4(g + 2*(size_t)LL + ga, r2);
    ld4(g + 3*(size_t)LL + ga, r3);
    ld4(g + 4*(size_t)LL + ga, r4);
    ld4(g + 5*(size_t)LL + ga, r5);
    ld4(g + 6*(size_t)LL + ga, g6b);
    if (st) ld4(g + 7*(size_t)LL + ga, g7b);
    else { g7b[0]=0.f; g7b[1]=0.f; g7b[2]=0.f; g7b[3]=0.f; }
    ldb4(src + ga, xb);
    if (rev){
      rev4(r0); rev4(r1); rev4(r2); rev4(r3); rev4(r4); rev4(r5);
      rev4(g6b); rev4(g7b); rev4(xb);
    }
    float av[4], bt[4];
    #pragma unroll
    for (int i = 0; i < 4; ++i){
      float dsum = dtb;
      dsum = fmaf(r0[i], dtw[0], dsum);
      dsum = fmaf(r1[i], dtw[1], dsum);
      dsum = fmaf(r2[i], dtw[2], dsum);
      dsum = fmaf(r3[i], dtw[3], dsum);
      dsum = fmaf(r4[i], dtw[4], dsum);
      dsum = fmaf(r5[i], dtw[5], dsum);
      float dl2 = dsum*LOG2E;
      float y = flog2(1.f + fexp2(dl2));
      y = (dsum > 20.f) ? dl2 : y;
      float delta = y*LN2;
      av[i] = fexp2(A*y);
      bt[i] = delta * g6b[i] * xb[i];
    }
    float P = av[0], Q = bt[0];
    #pragma unroll
    for (int i = 1; i < 4; ++i){ Q = fmaf(av[i], Q, bt[i]); P *= av[i]; }
    #pragma unroll
    for (int off = 1; off < 64; off <<= 1){
      float Pp = __shfl_up(P, (unsigned)off);
      float Qp = __shfl_up(Q, (unsigned)off);
      if (lane >= off){ Q = fmaf(P, Qp, Q); P *= Pp; }
    }
    float Pe = __shfl_up(P, 1u), Qe = __shfl_up(Q, 1u);
    if (lane == 0){ Pe = 1.f; Qe = 0.f; }
    float h = fmaf(Pe, carry, Qe);
    if (st){
      float ys[4];
      #pragma unroll
      for (int i = 0; i < 4; ++i){
        h = fmaf(av[i], h, bt[i]);
        ys[i] = fmaf(g7b[i], h, Dv*xb[i]);
      }
      carry = __shfl(h, 63);
      if (rev) rev4(ys);
      uint2 pw;
      pw.x = pk_bf16(ys[0], ys[1]);
      pw.y = pk_bf16(ys[2], ys[3]);
      *(uint2*)&yout[ga] = pw;
    } else {
      #pragma unroll
      for (int i = 0; i < 4; ++i) h = fmaf(av[i], h, bt[i]);
      carry = __shfl(h, 63);
    }
  }
}

// ---------------- combine v2 (bf16 in/out): z = (y0+y2) + transpose(y1+y3) ----------------
__global__ __launch_bounds__(256) void k_combine4(const u16* __restrict__ Y, u16* __restrict__ z){
  const size_t SZ = (size_t)BT*CC*LL;
  __shared__ float tl[64][65];
  int bc = blockIdx.z;
  int w0 = blockIdx.x*64;
  int t = threadIdx.x;
  const u16* y1p = Y + SZ   + (size_t)bc*LL;
  const u16* y3p = Y + 3*SZ + (size_t)bc*LL;
  {
    int wl = t >> 2;            // 0..63
    int h0 = (t & 3)*16;        // 0,16,32,48
    size_t base = (size_t)(w0 + wl)*HH + h0;
    #pragma unroll
    for (int j = 0; j < 4; ++j){
      ushort4 a = *(const ushort4*)&y1p[base + j*4];
      ushort4 bq = *(const ushort4*)&y3p[base + j*4];
      tl[wl][h0 + j*4 + 0] = bf2f(a.x) + bf2f(bq.x);
      tl[wl][h0 + j*4 + 1] = bf2f(a.y) + bf2f(bq.y);
      tl[wl][h0 + j*4 + 2] = bf2f(a.z) + bf2f(bq.z);
      tl[wl][h0 + j*4 + 3] = bf2f(a.w) + bf2f(bq.w);
    }
  }
  __syncthreads();
  const u16* y0p = Y +        (size_t)bc*LL;
  const u16* y2p = Y + 2*SZ + (size_t)bc*LL;
  u16* zp = z + (size_t)bc*LL;
  {
    int h = t >> 2;             // 0..63
    int wq = (t & 3)*16;        // 0,16,32,48
    #pragma unroll
    for (int j = 0; j < 4; ++j){
      int wl = wq + j*4;
      size_t idx = (size_t)h*WW + w0 + wl;
      ushort4 a = *(const ushort4*)&y0p[idx];
      ushort4 bq = *(const ushort4*)&y2p[idx];
      ushort4 o;
      o.x = f2bf(bf2f(a.x) + bf2f(bq.x) + tl[wl+0][h]);
      o.y = f2bf(bf2f(a.y) + bf2f(bq.y) + tl[wl+1][h]);
      o.z = f2bf(bf2f(a.z) + bf2f(bq.z) + tl[wl+2][h]);
      o.w = f2bf(bf2f(a.w) + bf2f(bq.w) + tl[wl+3][h]);
      *(ushort4*)&zp[idx] = o;
    }
  }
}

// ---------------- final output split/average ----------------
__global__ void k_output(const float* __restrict__ X, float* __restrict__ out){
  size_t i = (size_t)blockIdx.x*256 + threadIdx.x;
  size_t half = (size_t)2*CC*HH*128;
  if (i >= half) return;
  int w = i % 128; size_t r = i / 128;
  int h = r % HH; size_t bc = r / HH;
  size_t fwd = (bc*HH + h)*WW;
  size_t bwd = ((bc + (size_t)2*CC)*HH + h)*WW;
  out[i]        = 0.5f*(X[fwd + w]       + X[bwd + (WW-1-w)]);
  out[half + i] = 0.5f*(X[fwd + 128 + w] + X[bwd + (127 - w)]);
}

extern "C" void kernel_launch(void* const* d_in, const int* in_sizes, int n_in,
                              void* d_out, int out_size, void* d_ws, size_t ws_size,
                              hipStream_t stream){
  const float* x0        = (const float*)d_in[0];
  const float* x1        = (const float*)d_in[1];
  const float* norm_w    = (const float*)d_in[2];
  const float* norm_b    = (const float*)d_in[3];
  const float* in_proj_w = (const float*)d_in[4];
  const float* conv_w    = (const float*)d_in[5];
  const float* x_proj_w  = (const float*)d_in[6];
  const float* dt_w      = (const float*)d_in[7];
  const float* dt_b      = (const float*)d_in[8];
  const float* A_logs    = (const float*)d_in[9];
  const float* Ds        = (const float*)d_in[10];
  const float* out_norm_w= (const float*)d_in[11];
  const float* out_norm_b= (const float*)d_in[12];
  const float* out_proj_w= (const float*)d_in[13];
  const float* norm2_w   = (const float*)d_in[14];
  const float* norm2_b   = (const float*)d_in[15];
  const float* fc1_w     = (const float*)d_in[16];
  const float* fc1_b     = (const float*)d_in[17];
  const float* fc2_w     = (const float*)d_in[18];
  const float* fc2_b     = (const float*)d_in[19];

  const size_t SZ = (size_t)BT*CC*LL;            // 6,291,456 floats
  float* X  = (float*)d_ws;
  float* t  = X + SZ;
  float* u  = t + SZ;
  float* G  = u + SZ;                            // BT*KD*8*LL floats
  float* v  = G + (size_t)BT*KD*8*LL;
  float* vT = v + SZ;
  float* Yf = vT + SZ;                           // region: 4*SZ floats
  u16*   Yb = (u16*)Yf;                          // 4 contiguous SZ-u16 buffers
  u16*   XT = (u16*)Yf;                          // bf16T [BT*LL][104] (phase-disjoint w/ Yb)
  u16*   uB = (u16*)u;                           // bf16 u plane [b][c][l]
  u16*   vB = (u16*)v;                           // bf16 v plane
  u16*   vTB= (u16*)vT;                          // bf16 vT plane
  u16*   tB = (u16*)t;                           // bf16 t plane [b][c][l]
  u16*   tT = (u16*)u;                           // bf16T of t (u dead by then)
  float* ext = Yf + 4*SZ;
  float* stats_X = ext;                          // 2*BT*LL
  float* stats_t = stats_X + 2*(size_t)BT*LL;
  float* wsl     = stats_t + 2*(size_t)BT*LL;    // weight slots: NLAY * SLOTF floats

  float* p0 = wsl;
  u16*  WbI0 = (u16*)p0;          float* s1I0 = p0 + 4608;  float* cI0 = p0 + 4704;
  u16*  WbO0 = (u16*)(p0+4800);   float* s1O0 = p0 + 9408;  float* cO0 = p0 + 9504;
  u16*  Wb10 = (u16*)(p0+9600);   float* s110 = p0 + 28032; float* c10 = p0 + 28416;
  u16*  Wb20 = (u16*)(p0+28800);  float* s120 = p0 + 47232; float* c20 = p0 + 47328;

  k_prepw<96,96,false,true,false><<<dim3(2,NLAY),64,0,stream>>>(in_proj_w, norm_w, norm_b, nullptr, WbI0, s1I0, cI0);
  k_prepw<96,96,false,true,false><<<dim3(2,NLAY),64,0,stream>>>(out_proj_w, out_norm_w, out_norm_b, nullptr, WbO0, s1O0, cO0);
  k_prepw<384,96,true,true,true><<<dim3(6,NLAY),64,0,stream>>>(fc1_w, norm2_w, norm2_b, fc1_b, Wb10, s110, c10);
  k_prepw<96,384,false,false,true><<<dim3(2,NLAY),64,0,stream>>>(fc2_w, nullptr, nullptr, fc2_b, Wb20, s120, c20);

  k_build<<<(2*CC*HH*WW + 255)/256, 256, 0, stream>>>(x0, x1, X);
  k_pack<true,float><<<dim3(LL/32, BT), 256, 0, stream>>>(X, XT, stats_X);

  for (int lay = 0; lay < NLAY; ++lay){
    size_t so = (size_t)lay*SLOTF;
    const u16* WbI = WbI0 + so*2; const float* s1I = s1I0 + so; const float* cI = cI0 + so;
    const u16* WbO = WbO0 + so*2; const float* s1O = s1O0 + so; const float* cO = cO0 + so;
    const u16* Wb1 = Wb10 + so*2; const float* s11 = s110 + so; const float* c1 = c10 + so;
    const u16* Wb2 = Wb20 + so*2; const float* c2 = c20 + so;
    const float* cw  = conv_w    + (size_t)lay*CC*9;
    const float* xpw = x_proj_w  + (size_t)lay*KD*8*CC;
    const float* dw  = dt_w      + (size_t)lay*KD*CC*RR;
    const float* db  = dt_b      + (size_t)lay*KD*CC;
    const float* Al  = A_logs    + (size_t)lay*KD*CC;
    const float* Dp  = Ds        + (size_t)lay*KD*CC;

    // in_proj (LN fused): uB = bf16(W' * X)
    k_gmm2<true,false,false,false,false,true><<<dim3(BT*LL/128),256,0,stream>>>(
        WbI, XT, nullptr, nullptr, s1I, cI, nullptr, stats_X, nullptr, uB);
    k_dwconv_silu_t<<<dim3(8,2,BT*CC), 256, 0, stream>>>(uB, vB, vTB, cw);
    k_xproj<<<dim3(BT*LL/256, 2), 256, 0, stream>>>(vB, vTB, G, xpw);
    k_scan3<<<dim3(2,768,2), 256, 0, stream>>>(G, vB, vTB, Yb, dw, db, Al, Dp);
    k_combine4<<<dim3(4,1,BT*CC), 256, 0, stream>>>(Yb, tB);
    k_pack<true,u16><<<dim3(LL/32, BT), 256, 0, stream>>>(tB, tT, stats_t);
    // out_proj (LN fused) + residual -> X (f32 + XT bf16 + stats_X)
    k_gmm2<true,true,true,true,true,false><<<dim3(BT*LL/128),256,0,stream>>>(
        WbO, tT, X, XT, s1O, cO, X, stats_t, stats_X, nullptr);
    // fused MLP
    k_mlp<<<dim3(BT*LL/128),512,0,stream>>>(
        Wb1, Wb2, XT, X, XT, s11, c1, c2, stats_X, stats_X);
  }

  k_output<<<(unsigned)(((size_t)2*CC*HH*128 + 255)/256), 256, 0, stream>>>(X, (float*)d_out);
}

// Round 13
// 403.430 us; speedup vs baseline: 12.1346x; 1.0435x over previous
//
#include <hip/hip_runtime.h>
#include <cstdint>
#include <cstddef>

#define BT 4
#define CC 96
#define HH 64
#define WW 256
#define LL (HH*WW)    // 16384
#define KD 4
#define RR 6
#define NLAY 2
#define C4 (4*CC)     // 384
#define SLOTF 47424   // per-layer weight-slot stride in float units
#define STPW 4096     // scan: stored elems per wave
#define WARM 512      // scan: warm-up elems

typedef unsigned short u16;
typedef __attribute__((ext_vector_type(8))) short bf16x8;
typedef __attribute__((ext_vector_type(4))) float f32x4;

__device__ __forceinline__ u16 f2bf(float f){
  unsigned u = __float_as_uint(f);
  unsigned r = (u + 0x7FFFu + ((u >> 16) & 1u)) >> 16;
  return (u16)r;
}
__device__ __forceinline__ float bf2f(u16 h){
  return __uint_as_float(((unsigned)h) << 16);
}
__device__ __forceinline__ unsigned pk_bf16(float lo, float hi){
  unsigned r;
  asm volatile("v_cvt_pk_bf16_f32 %0, %1, %2" : "=v"(r) : "v"(lo), "v"(hi));
  return r;
}
__device__ __forceinline__ float fexp2(float x){
  float r; asm("v_exp_f32 %0, %1" : "=v"(r) : "v"(x)); return r;
}
__device__ __forceinline__ float flog2(float x){
  float r; asm("v_log_f32 %0, %1" : "=v"(r) : "v"(x)); return r;
}
// tanh-approx GELU, division-free
__device__ __forceinline__ float gelu_f(float v){
  float t = v*v;
  float u = v*fmaf(0.0356774081f, t, 0.7978845608f);
  float e2 = __expf(2.f*u);
  float r = __builtin_amdgcn_rcpf(e2 + 1.f);
  return fmaf(-v, r, v);
}

// ---------------- build batched input ----------------
__global__ void k_build(const float* __restrict__ x0, const float* __restrict__ x1,
                        float* __restrict__ X){
  size_t i = (size_t)blockIdx.x*256 + threadIdx.x;
  size_t tot = (size_t)2*CC*HH*WW;
  if (i >= tot) return;
  int w = i % WW; size_t r = i / WW;
  int h = r % HH; size_t bc = r / HH;
  float val;
  if (w < 128) val = x0[(bc*HH + h)*128 + w];
  else         val = x1[(bc*HH + h)*128 + (w-128)];
  X[i] = val;
  size_t ib = ((bc + (size_t)2*CC)*HH + h)*WW + (WW-1-w);
  X[ib] = val;
}

// ---------------- pack [b][c][l] -> bf16T [b*LL+l][104] (+ LN stats), f32 or bf16 src ----------------
template<bool ST, typename T>
__global__ __launch_bounds__(256) void k_pack(const T* __restrict__ src,
      u16* __restrict__ dst, float* __restrict__ st){
  __shared__ float tl[CC][33];
  int tid = threadIdx.x;
  int l0 = blockIdx.x*32, b = blockIdx.y;
  for (int e = tid; e < CC*32; e += 256){
    int c = e >> 5, dl = e & 31;
    T raw = src[((size_t)b*CC + c)*LL + l0 + dl];
    float vv;
    if constexpr (sizeof(T) == 2) vv = bf2f((u16)raw); else vv = (float)raw;
    tl[c][dl] = vv;
  }
  __syncthreads();
  if (ST && tid < 32){
    float s = 0.f, ss = 0.f;
    for (int c = 0; c < CC; ++c){ float vv = tl[c][tid]; s += vv; ss += vv*vv; }
    float mu = s*(1.f/CC);
    float var = ss*(1.f/CC) - mu*mu;
    st[(size_t)b*LL + l0 + tid] = mu;
    st[(size_t)BT*LL + (size_t)b*LL + l0 + tid] = rsqrtf(var + 1e-5f);
  }
  int dl = tid >> 3, cg = tid & 7;
  u16* dp = dst + ((size_t)b*LL + l0 + dl)*104 + cg*12;
  #pragma unroll
  for (int q = 0; q < 3; ++q){
    ushort4 pk;
    pk.x = f2bf(tl[cg*12 + q*4 + 0][dl]);
    pk.y = f2bf(tl[cg*12 + q*4 + 1][dl]);
    pk.z = f2bf(tl[cg*12 + q*4 + 2][dl]);
    pk.w = f2bf(tl[cg*12 + q*4 + 3][dl]);
    *(ushort4*)(dp + q*4) = pk;
  }
}

// ---------------- weight prep: swizzle into MFMA-fragment order ----------------
template<int M, int K, bool FC1ORD, bool LNF, bool BIAS>
__global__ void k_prepw(const float* __restrict__ W, const float* __restrict__ lnw,
      const float* __restrict__ lnb, const float* __restrict__ bias,
      u16* __restrict__ Wb, float* __restrict__ s1, float* __restrict__ cadd){
  int lay = blockIdx.y;
  W += (size_t)lay*M*K;
  Wb += (size_t)lay*SLOTF*2;
  s1 += (size_t)lay*SLOTF;
  cadd += (size_t)lay*SLOTF;
  int m = blockIdx.x*64 + threadIdx.x;
  if (m >= M) return;
  int rowfrag = m >> 4, lr = m & 15;
  float s1v = 0.f, sbv = 0.f;
  for (int c = 0; c < K; ++c){
    float wv = W[(size_t)m*K + c];
    float wf = LNF ? wv*lnw[lay*K + c] : wv;
    u16 h = f2bf(wf);
    int colfrag = c >> 5, lg = (c >> 3) & 3, j = c & 7;
    int f;
    if (FC1ORD) f = (rowfrag/6)*18 + colfrag*6 + (rowfrag % 6);
    else        f = colfrag*(M/16) + rowfrag;
    Wb[(size_t)(f*64 + lg*16 + lr)*8 + j] = h;
    s1v += bf2f(h);
    if (LNF) sbv = fmaf(wv, lnb[lay*K + c], sbv);
  }
  if (BIAS) sbv += bias[lay*M + m];
  s1[m] = s1v;
  cadd[m] = sbv;
}

// ---------------- MFMA GEMM (M=96,K=96): 128px/block, LDS B, swizzled weights ----------------
template<bool LNF, bool RES, bool WF32, bool WBF, bool STATS, bool WPB>
__global__ __launch_bounds__(256) void k_gmm2(
    const u16* __restrict__ Wb, const u16* __restrict__ inT,
    float* __restrict__ outF, u16* __restrict__ outT,
    const float* __restrict__ s1v, const float* __restrict__ cadd,
    const float* __restrict__ res,
    const float* __restrict__ stI, float* __restrict__ stO,
    u16* __restrict__ outPB){
  __shared__ u16 bt[128*104];
  int tid = threadIdx.x, lane = tid & 63, wid = tid >> 6;
  int l0 = blockIdx.x*128;
  int lr = lane & 15, lg = lane >> 4;
  const int4* bsrc = (const int4*)(inT + (size_t)l0*104);
  for (int i = tid; i < 1664; i += 256) ((int4*)bt)[i] = bsrc[i];
  __syncthreads();
  f32x4 acc[6][2];
  #pragma unroll
  for (int mf = 0; mf < 6; ++mf){ acc[mf][0] = (f32x4){0,0,0,0}; acc[mf][1] = (f32x4){0,0,0,0}; }
  #pragma unroll
  for (int ks = 0; ks < 3; ++ks){
    bf16x8 af[6];
    #pragma unroll
    for (int mf = 0; mf < 6; ++mf)
      af[mf] = *(const bf16x8*)(Wb + (size_t)((ks*6 + mf)*64 + lane)*8);
    bf16x8 bfr[2];
    #pragma unroll
    for (int ls = 0; ls < 2; ++ls)
      bfr[ls] = *(const bf16x8*)&bt[(wid*32 + ls*16 + lr)*104 + ks*32 + lg*8];
    #pragma unroll
    for (int mf = 0; mf < 6; ++mf)
      #pragma unroll
      for (int ls = 0; ls < 2; ++ls)
        acc[mf][ls] = __builtin_amdgcn_mfma_f32_16x16x32_bf16(af[mf], bfr[ls], acc[mf][ls], 0, 0, 0);
  }
  #pragma unroll
  for (int ls = 0; ls < 2; ++ls){
    int l = l0 + wid*32 + ls*16 + lr;
    int b = l >> 14, lb = l & (LL-1);
    float mu = 0.f, rs = 0.f;
    if (LNF){ mu = stI[l]; rs = stI[(size_t)BT*LL + l]; }
    float ssum = 0.f, ssq = 0.f;
    #pragma unroll
    for (int mf = 0; mf < 6; ++mf){
      float o[4];
      #pragma unroll
      for (int r = 0; r < 4; ++r){
        int mm = mf*16 + lg*4 + r;
        float vv = acc[mf][ls][r];
        if (LNF) vv = fmaf(rs, vv, fmaf(-mu*rs, s1v[mm], cadd[mm]));
        else     vv += cadd[mm];
        if (RES) vv += res[((size_t)b*96 + mm)*LL + lb];
        if (WF32) outF[((size_t)b*96 + mm)*LL + lb] = vv;
        if (WPB)  outPB[((size_t)b*96 + mm)*LL + lb] = f2bf(vv);
        if (STATS){ ssum += vv; ssq += vv*vv; }
        o[r] = vv;
      }
      if (WBF){
        ushort4 pk;
        pk.x = f2bf(o[0]); pk.y = f2bf(o[1]); pk.z = f2bf(o[2]); pk.w = f2bf(o[3]);
        *(ushort4*)(outT + (size_t)l*104 + mf*16 + lg*4) = pk;
      }
    }
    if (STATS){
      ssum += __shfl_xor(ssum, 16); ssq += __shfl_xor(ssq, 16);
      ssum += __shfl_xor(ssum, 32); ssq += __shfl_xor(ssq, 32);
      if (lane < 16){
        float mu2 = ssum*(1.f/CC);
        float var = ssq*(1.f/CC) - mu2*mu2;
        stO[l] = mu2;
        stO[(size_t)BT*LL + l] = rsqrtf(var + 1e-5f);
      }
    }
  }
}

// ---------------- fused MLP v4: 8 waves/block, coalesced swizzled weights ----------------
__global__ __launch_bounds__(512, 4) void k_mlp(
    const u16* __restrict__ Wb1, const u16* __restrict__ Wb2,
    const u16* __restrict__ XT, float* __restrict__ X, u16* __restrict__ XTout,
    const float* __restrict__ s11, const float* __restrict__ c1,
    const float* __restrict__ c2,
    const float* __restrict__ stI, float* __restrict__ stO){
  __shared__ u16 bt[128*104];
  __shared__ u16 hs[128*104];
  int tid = threadIdx.x, lane = tid & 63, wid = tid >> 6;   // wid 0..7
  int l0 = blockIdx.x*128;
  int lr = lane & 15, lg = lane >> 4;
  const int4* bsrc = (const int4*)(XT + (size_t)l0*104);
  for (int i = tid; i < 1664; i += 512) ((int4*)bt)[i] = bsrc[i];

  int l = l0 + wid*16 + lr;                    // this lane's pixel
  float mu = stI[l];
  float rs = stI[(size_t)BT*LL + l];
  float nmr = -mu*rs;
  __syncthreads();

  int hrow = (wid*16 + lr)*104;
  f32x4 acc2[6];
  #pragma unroll
  for (int mf = 0; mf < 6; ++mf) acc2[mf] = (f32x4){0,0,0,0};

  for (int cc = 0; cc < 4; ++cc){
    f32x4 acc1[6];
    #pragma unroll
    for (int mf = 0; mf < 6; ++mf) acc1[mf] = (f32x4){0,0,0,0};
    #pragma unroll
    for (int ks = 0; ks < 3; ++ks){
      bf16x8 af[6];
      #pragma unroll
      for (int mf = 0; mf < 6; ++mf)
        af[mf] = *(const bf16x8*)(Wb1 + (size_t)((cc*18 + ks*6 + mf)*64 + lane)*8);
      bf16x8 bfr = *(const bf16x8*)&bt[hrow + ks*32 + lg*8];
      #pragma unroll
      for (int mf = 0; mf < 6; ++mf)
        acc1[mf] = __builtin_amdgcn_mfma_f32_16x16x32_bf16(af[mf], bfr, acc1[mf], 0, 0, 0);
    }
    #pragma unroll
    for (int mf = 0; mf < 6; ++mf){
      float4 sv = *(const float4*)&s11[cc*96 + mf*16 + lg*4];
      float4 cv = *(const float4*)&c1 [cc*96 + mf*16 + lg*4];
      float g0 = gelu_f(fmaf(rs, acc1[mf][0], fmaf(nmr, sv.x, cv.x)));
      float g1 = gelu_f(fmaf(rs, acc1[mf][1], fmaf(nmr, sv.y, cv.y)));
      float g2 = gelu_f(fmaf(rs, acc1[mf][2], fmaf(nmr, sv.z, cv.z)));
      float g3 = gelu_f(fmaf(rs, acc1[mf][3], fmaf(nmr, sv.w, cv.w)));
      uint2 pw;
      pw.x = pk_bf16(g0, g1);
      pw.y = pk_bf16(g2, g3);
      *(uint2*)&hs[hrow + mf*16 + lg*4] = pw;
    }
    #pragma unroll
    for (int ks = 0; ks < 3; ++ks){
      bf16x8 a2[6];
      #pragma unroll
      for (int mf2 = 0; mf2 < 6; ++mf2)
        a2[mf2] = *(const bf16x8*)(Wb2 + (size_t)(((cc*3 + ks)*6 + mf2)*64 + lane)*8);
      bf16x8 bfr2 = *(const bf16x8*)&hs[hrow + ks*32 + lg*8];
      #pragma unroll
      for (int mf2 = 0; mf2 < 6; ++mf2)
        acc2[mf2] = __builtin_amdgcn_mfma_f32_16x16x32_bf16(a2[mf2], bfr2, acc2[mf2], 0, 0, 0);
    }
  }
  {
    int b = l >> 14, lb = l & (LL-1);
    float ssum = 0.f, ssq = 0.f;
    #pragma unroll
    for (int mf = 0; mf < 6; ++mf){
      float o[4];
      #pragma unroll
      for (int r = 0; r < 4; ++r){
        int mm = mf*16 + lg*4 + r;
        float vv = acc2[mf][r] + c2[mm];
        vv += X[((size_t)b*96 + mm)*LL + lb];
        X[((size_t)b*96 + mm)*LL + lb] = vv;
        ssum += vv; ssq += vv*vv;
        o[r] = vv;
      }
      ushort4 pk;
      pk.x = f2bf(o[0]); pk.y = f2bf(o[1]); pk.z = f2bf(o[2]); pk.w = f2bf(o[3]);
      *(ushort4*)(XTout + (size_t)l*104 + mf*16 + lg*4) = pk;
    }
    ssum += __shfl_xor(ssum, 16); ssq += __shfl_xor(ssq, 16);
    ssum += __shfl_xor(ssum, 32); ssq += __shfl_xor(ssq, 32);
    if (lane < 16){
      float mu2 = ssum*(1.f/CC);
      float var = ssq*(1.f/CC) - mu2*mu2;
      stO[l] = mu2;
      stO[(size_t)BT*LL + l] = rsqrtf(var + 1e-5f);
    }
  }
}

// ---------------- depthwise 3x3 + SiLU (bf16 in/out), fused transpose ----------------
__global__ __launch_bounds__(256) void k_dwconv_silu_t(const u16* __restrict__ u,
      u16* __restrict__ v, u16* __restrict__ vT, const float* __restrict__ cw){
  __shared__ float tl[32][33];
  int bc = blockIdx.z;
  int c = bc % CC;
  int w0 = blockIdx.x*32, h0 = blockIdx.y*32;
  const u16* up = u + (size_t)bc*LL;
  const float* k9 = cw + c*9;
  int t = threadIdx.x;
  int wl = (t & 7)*4, hl = t >> 3;
  int h = h0 + hl, w = w0 + wl;
  float acc[4] = {0.f,0.f,0.f,0.f};
  #pragma unroll
  for (int dh = -1; dh <= 1; ++dh){
    int h2 = h + dh;
    if (h2 < 0 || h2 >= HH) continue;
    const u16* row = up + (size_t)h2*WW + w;
    ushort4 mq = *(const ushort4*)row;
    float m0 = bf2f(mq.x), m1 = bf2f(mq.y), m2 = bf2f(mq.z), m3 = bf2f(mq.w);
    float lft = (w > 0) ? bf2f(row[-1]) : 0.f;
    float rgt = (w + 4 < WW) ? bf2f(row[4]) : 0.f;
    float k0 = k9[(dh+1)*3], k1 = k9[(dh+1)*3+1], k2 = k9[(dh+1)*3+2];
    acc[0] += lft*k0 + m0*k1 + m1*k2;
    acc[1] += m0*k0 + m1*k1 + m2*k2;
    acc[2] += m1*k0 + m2*k1 + m3*k2;
    acc[3] += m2*k0 + m3*k1 + rgt*k2;
  }
  float s[4];
  #pragma unroll
  for (int j = 0; j < 4; ++j){
    float a = acc[j];
    float e = __expf(-a);
    s[j] = a * __builtin_amdgcn_rcpf(1.f + e);
    tl[wl + j][hl] = s[j];
  }
  uint2 pw;
  pw.x = pk_bf16(s[0], s[1]);
  pw.y = pk_bf16(s[2], s[3]);
  *(uint2*)&v[(size_t)bc*LL + (size_t)h*WW + w] = pw;
  __syncthreads();
  int ww = t >> 3, hh4 = (t & 7)*4;
  uint2 po;
  po.x = pk_bf16(tl[ww][hh4],   tl[ww][hh4+1]);
  po.y = pk_bf16(tl[ww][hh4+2], tl[ww][hh4+3]);
  *(uint2*)&vT[(size_t)bc*LL + (size_t)(w0 + ww)*HH + h0 + hh4] = po;
}

// ---------------- x-projection (bf16 src, bf16 G out) ----------------
__global__ void k_xproj(const u16* __restrict__ v, const u16* __restrict__ vT,
                        u16* __restrict__ G, const float* __restrict__ xpw){
  int which = blockIdx.y;
  const u16* src = which ? vT : v;
  int kA = which ? 1 : 0, kB = which ? 3 : 2;
  size_t i = (size_t)blockIdx.x*256 + threadIdx.x;
  if (i >= (size_t)BT*LL) return;
  int b = (int)(i / LL), l = (int)(i % LL);
  const u16* sp = src + (size_t)b*CC*LL + l;
  const float* wA = xpw + (size_t)kA*8*CC;
  const float* wB = xpw + (size_t)kB*8*CC;
  float aA[8], aB[8];
  #pragma unroll
  for (int d = 0; d < 8; ++d){ aA[d] = 0.f; aB[d] = 0.f; }
  for (int c = 0; c < CC; ++c){
    float xv = bf2f(sp[(size_t)c*LL]);
    #pragma unroll
    for (int d = 0; d < 8; ++d){
      aA[d] = fmaf(wA[d*CC + c], xv, aA[d]);
      aB[d] = fmaf(wB[d*CC + c], xv, aB[d]);
    }
  }
  u16* gA = G + (((size_t)b*KD + kA)*8)*LL + l;
  u16* gB = G + (((size_t)b*KD + kB)*8)*LL + l;
  #pragma unroll
  for (int d = 0; d < 8; ++d){ gA[(size_t)d*LL] = f2bf(aA[d]); gB[(size_t)d*LL] = f2bf(aB[d]); }
}

// ---------------- scan v5: 4096/wave, 8 elems/lane, bf16 G/src/out ----------------
__device__ __forceinline__ void ldbf8(const u16* p, float* o){
  uint4 t = *(const uint4*)p;
  o[0]=bf2f((u16)(t.x & 0xffff)); o[1]=bf2f((u16)(t.x >> 16));
  o[2]=bf2f((u16)(t.y & 0xffff)); o[3]=bf2f((u16)(t.y >> 16));
  o[4]=bf2f((u16)(t.z & 0xffff)); o[5]=bf2f((u16)(t.z >> 16));
  o[6]=bf2f((u16)(t.w & 0xffff)); o[7]=bf2f((u16)(t.w >> 16));
}
__device__ __forceinline__ void rev8(float* a){
  #pragma unroll
  for (int i = 0; i < 4; ++i){ float t0 = a[i]; a[i] = a[7-i]; a[7-i] = t0; }
}

__global__ __launch_bounds__(256) void k_scan3(const u16* __restrict__ G,
                       const u16* __restrict__ v, const u16* __restrict__ vT,
                       u16* __restrict__ Y,
                       const float* __restrict__ dtw_, const float* __restrict__ dtb_,
                       const float* __restrict__ Alog_, const float* __restrict__ Ds_){
  const size_t SZ = (size_t)BT*CC*LL;
  const float LOG2E = 1.4426950408889634f, LN2 = 0.6931471805599453f;
  int wid = threadIdx.x >> 6, lane = threadIdx.x & 63;
  int tile = wid;                              // 0..3 (4 tiles x 4096 = 16384)
  int sy = blockIdx.y;
  bool rev = (blockIdx.z != 0);
  int c = sy % CC; int t2 = sy / CC; int kk = t2 & 1; int b = t2 >> 1;
  int k = (rev ? 2 : 0) + kk;
  const u16* src = (kk ? vT : v) + ((size_t)b*CC + c)*LL;
  const u16* g = G + (((size_t)b*KD + k)*8)*LL;
  float dtw[RR];
  #pragma unroll
  for (int r = 0; r < RR; ++r) dtw[r] = dtw_[((size_t)k*CC + c)*RR + r];
  float dtb = dtb_[k*CC + c];
  float A  = -__expf(Alog_[k*CC + c]);
  float Dv = Ds_[k*CC + c];
  u16* yout = Y + (size_t)k*SZ + ((size_t)b*CC + c)*LL;

  int lstore0 = tile*STPW;
  float carry = 0.f;
  for (int p = 0; p < 1 + STPW/WARM; ++p){
    int base = lstore0 - WARM + p*WARM;
    if (base < 0) continue;                    // tile 0: no warm-up
    bool st = (base >= lstore0);
    int l = base + (lane<<3);
    int ga = rev ? (LL-8-l) : l;
    float dsum[8], g6b[8], g7b[8], xb[8];
    #pragma unroll
    for (int i = 0; i < 8; ++i) dsum[i] = dtb;
    #pragma unroll
    for (int r = 0; r < RR; ++r){
      float t8[8];
      ldbf8(g + (size_t)r*LL + ga, t8);
      #pragma unroll
      for (int i = 0; i < 8; ++i) dsum[i] = fmaf(t8[i], dtw[r], dsum[i]);
    }
    ldbf8(g + (size_t)6*LL + ga, g6b);
    if (st){
      ldbf8(g + (size_t)7*LL + ga, g7b);
    } else {
      #pragma unroll
      for (int i = 0; i < 8; ++i) g7b[i] = 0.f;
    }
    ldbf8(src + ga, xb);
    if (rev){ rev8(dsum); rev8(g6b); rev8(g7b); rev8(xb); }
    float av[8], bt[8];
    #pragma unroll
    for (int i = 0; i < 8; ++i){
      float dl2 = dsum[i]*LOG2E;
      float y = flog2(1.f + fexp2(dl2));
      y = (dsum[i] > 20.f) ? dl2 : y;
      float delta = y*LN2;
      av[i] = fexp2(A*y);
      bt[i] = delta * g6b[i] * xb[i];
    }
    float P = av[0], Q = bt[0];
    #pragma unroll
    for (int i = 1; i < 8; ++i){ Q = fmaf(av[i], Q, bt[i]); P *= av[i]; }
    #pragma unroll
    for (int off = 1; off < 64; off <<= 1){
      float Pp = __shfl_up(P, (unsigned)off);
      float Qp = __shfl_up(Q, (unsigned)off);
      if (lane >= off){ Q = fmaf(P, Qp, Q); P *= Pp; }
    }
    float Pe = __shfl_up(P, 1u), Qe = __shfl_up(Q, 1u);
    if (lane == 0){ Pe = 1.f; Qe = 0.f; }
    float h = fmaf(Pe, carry, Qe);
    if (st){
      float ys[8];
      #pragma unroll
      for (int i = 0; i < 8; ++i){
        h = fmaf(av[i], h, bt[i]);
        ys[i] = fmaf(g7b[i], h, Dv*xb[i]);
      }
      carry = __shfl(h, 63);
      if (rev) rev8(ys);
      uint4 pw;
      pw.x = pk_bf16(ys[0], ys[1]);
      pw.y = pk_bf16(ys[2], ys[3]);
      pw.z = pk_bf16(ys[4], ys[5]);
      pw.w = pk_bf16(ys[6], ys[7]);
      *(uint4*)&yout[ga] = pw;
    } else {
      #pragma unroll
      for (int i = 0; i < 8; ++i) h = fmaf(av[i], h, bt[i]);
      carry = __shfl(h, 63);
    }
  }
}

// ---------------- combine v2 (bf16 in/out): z = (y0+y2) + transpose(y1+y3) ----------------
__global__ __launch_bounds__(256) void k_combine4(const u16* __restrict__ Y, u16* __restrict__ z){
  const size_t SZ = (size_t)BT*CC*LL;
  __shared__ float tl[64][65];
  int bc = blockIdx.z;
  int w0 = blockIdx.x*64;
  int t = threadIdx.x;
  const u16* y1p = Y + SZ   + (size_t)bc*LL;
  const u16* y3p = Y + 3*SZ + (size_t)bc*LL;
  {
    int wl = t >> 2;            // 0..63
    int h0 = (t & 3)*16;        // 0,16,32,48
    size_t base = (size_t)(w0 + wl)*HH + h0;
    #pragma unroll
    for (int j = 0; j < 4; ++j){
      ushort4 a = *(const ushort4*)&y1p[base + j*4];
      ushort4 bq = *(const ushort4*)&y3p[base + j*4];
      tl[wl][h0 + j*4 + 0] = bf2f(a.x) + bf2f(bq.x);
      tl[wl][h0 + j*4 + 1] = bf2f(a.y) + bf2f(bq.y);
      tl[wl][h0 + j*4 + 2] = bf2f(a.z) + bf2f(bq.z);
      tl[wl][h0 + j*4 + 3] = bf2f(a.w) + bf2f(bq.w);
    }
  }
  __syncthreads();
  const u16* y0p = Y +        (size_t)bc*LL;
  const u16* y2p = Y + 2*SZ + (size_t)bc*LL;
  u16* zp = z + (size_t)bc*LL;
  {
    int h = t >> 2;             // 0..63
    int wq = (t & 3)*16;        // 0,16,32,48
    #pragma unroll
    for (int j = 0; j < 4; ++j){
      int wl = wq + j*4;
      size_t idx = (size_t)h*WW + w0 + wl;
      ushort4 a = *(const ushort4*)&y0p[idx];
      ushort4 bq = *(const ushort4*)&y2p[idx];
      ushort4 o;
      o.x = f2bf(bf2f(a.x) + bf2f(bq.x) + tl[wl+0][h]);
      o.y = f2bf(bf2f(a.y) + bf2f(bq.y) + tl[wl+1][h]);
      o.z = f2bf(bf2f(a.z) + bf2f(bq.z) + tl[wl+2][h]);
      o.w = f2bf(bf2f(a.w) + bf2f(bq.w) + tl[wl+3][h]);
      *(ushort4*)&zp[idx] = o;
    }
  }
}

// ---------------- final output split/average ----------------
__global__ void k_output(const float* __restrict__ X, float* __restrict__ out){
  size_t i = (size_t)blockIdx.x*256 + threadIdx.x;
  size_t half = (size_t)2*CC*HH*128;
  if (i >= half) return;
  int w = i % 128; size_t r = i / 128;
  int h = r % HH; size_t bc = r / HH;
  size_t fwd = (bc*HH + h)*WW;
  size_t bwd = ((bc + (size_t)2*CC)*HH + h)*WW;
  out[i]        = 0.5f*(X[fwd + w]       + X[bwd + (WW-1-w)]);
  out[half + i] = 0.5f*(X[fwd + 128 + w] + X[bwd + (127 - w)]);
}

extern "C" void kernel_launch(void* const* d_in, const int* in_sizes, int n_in,
                              void* d_out, int out_size, void* d_ws, size_t ws_size,
                              hipStream_t stream){
  const float* x0        = (const float*)d_in[0];
  const float* x1        = (const float*)d_in[1];
  const float* norm_w    = (const float*)d_in[2];
  const float* norm_b    = (const float*)d_in[3];
  const float* in_proj_w = (const float*)d_in[4];
  const float* conv_w    = (const float*)d_in[5];
  const float* x_proj_w  = (const float*)d_in[6];
  const float* dt_w      = (const float*)d_in[7];
  const float* dt_b      = (const float*)d_in[8];
  const float* A_logs    = (const float*)d_in[9];
  const float* Ds        = (const float*)d_in[10];
  const float* out_norm_w= (const float*)d_in[11];
  const float* out_norm_b= (const float*)d_in[12];
  const float* out_proj_w= (const float*)d_in[13];
  const float* norm2_w   = (const float*)d_in[14];
  const float* norm2_b   = (const float*)d_in[15];
  const float* fc1_w     = (const float*)d_in[16];
  const float* fc1_b     = (const float*)d_in[17];
  const float* fc2_w     = (const float*)d_in[18];
  const float* fc2_b     = (const float*)d_in[19];

  const size_t SZ = (size_t)BT*CC*LL;            // 6,291,456 floats
  float* X  = (float*)d_ws;
  float* t  = X + SZ;
  float* u  = t + SZ;
  float* G  = u + SZ;                            // BT*KD*8*LL floats (bf16 uses half)
  float* v  = G + (size_t)BT*KD*8*LL;
  float* vT = v + SZ;
  float* Yf = vT + SZ;                           // region: 4*SZ floats
  u16*   Gb = (u16*)G;                           // bf16 G planes
  u16*   Yb = (u16*)Yf;                          // 4 contiguous SZ-u16 buffers
  u16*   XT = (u16*)Yf;                          // bf16T [BT*LL][104] (phase-disjoint w/ Yb)
  u16*   uB = (u16*)u;                           // bf16 u plane [b][c][l]
  u16*   vB = (u16*)v;                           // bf16 v plane
  u16*   vTB= (u16*)vT;                          // bf16 vT plane
  u16*   tB = (u16*)t;                           // bf16 t plane [b][c][l]
  u16*   tT = (u16*)u;                           // bf16T of t (u dead by then)
  float* ext = Yf + 4*SZ;
  float* stats_X = ext;                          // 2*BT*LL
  float* stats_t = stats_X + 2*(size_t)BT*LL;
  float* wsl     = stats_t + 2*(size_t)BT*LL;    // weight slots: NLAY * SLOTF floats

  float* p0 = wsl;
  u16*  WbI0 = (u16*)p0;          float* s1I0 = p0 + 4608;  float* cI0 = p0 + 4704;
  u16*  WbO0 = (u16*)(p0+4800);   float* s1O0 = p0 + 9408;  float* cO0 = p0 + 9504;
  u16*  Wb10 = (u16*)(p0+9600);   float* s110 = p0 + 28032; float* c10 = p0 + 28416;
  u16*  Wb20 = (u16*)(p0+28800);  float* s120 = p0 + 47232; float* c20 = p0 + 47328;

  k_prepw<96,96,false,true,false><<<dim3(2,NLAY),64,0,stream>>>(in_proj_w, norm_w, norm_b, nullptr, WbI0, s1I0, cI0);
  k_prepw<96,96,false,true,false><<<dim3(2,NLAY),64,0,stream>>>(out_proj_w, out_norm_w, out_norm_b, nullptr, WbO0, s1O0, cO0);
  k_prepw<384,96,true,true,true><<<dim3(6,NLAY),64,0,stream>>>(fc1_w, norm2_w, norm2_b, fc1_b, Wb10, s110, c10);
  k_prepw<96,384,false,false,true><<<dim3(2,NLAY),64,0,stream>>>(fc2_w, nullptr, nullptr, fc2_b, Wb20, s120, c20);

  k_build<<<(2*CC*HH*WW + 255)/256, 256, 0, stream>>>(x0, x1, X);
  k_pack<true,float><<<dim3(LL/32, BT), 256, 0, stream>>>(X, XT, stats_X);

  for (int lay = 0; lay < NLAY; ++lay){
    size_t so = (size_t)lay*SLOTF;
    const u16* WbI = WbI0 + so*2; const float* s1I = s1I0 + so; const float* cI = cI0 + so;
    const u16* WbO = WbO0 + so*2; const float* s1O = s1O0 + so; const float* cO = cO0 + so;
    const u16* Wb1 = Wb10 + so*2; const float* s11 = s110 + so; const float* c1 = c10 + so;
    const u16* Wb2 = Wb20 + so*2; const float* c2 = c20 + so;
    const float* cw  = conv_w    + (size_t)lay*CC*9;
    const float* xpw = x_proj_w  + (size_t)lay*KD*8*CC;
    const float* dw  = dt_w      + (size_t)lay*KD*CC*RR;
    const float* db  = dt_b      + (size_t)lay*KD*CC;
    const float* Al  = A_logs    + (size_t)lay*KD*CC;
    const float* Dp  = Ds        + (size_t)lay*KD*CC;

    // in_proj (LN fused): uB = bf16(W' * X)
    k_gmm2<true,false,false,false,false,true><<<dim3(BT*LL/128),256,0,stream>>>(
        WbI, XT, nullptr, nullptr, s1I, cI, nullptr, stats_X, nullptr, uB);
    k_dwconv_silu_t<<<dim3(8,2,BT*CC), 256, 0, stream>>>(uB, vB, vTB, cw);
    k_xproj<<<dim3(BT*LL/256, 2), 256, 0, stream>>>(vB, vTB, Gb, xpw);
    k_scan3<<<dim3(1,768,2), 256, 0, stream>>>(Gb, vB, vTB, Yb, dw, db, Al, Dp);
    k_combine4<<<dim3(4,1,BT*CC), 256, 0, stream>>>(Yb, tB);
    k_pack<true,u16><<<dim3(LL/32, BT), 256, 0, stream>>>(tB, tT, stats_t);
    // out_proj (LN fused) + residual -> X (f32 + XT bf16 + stats_X)
    k_gmm2<true,true,true,true,true,false><<<dim3(BT*LL/128),256,0,stream>>>(
        WbO, tT, X, XT, s1O, cO, X, stats_t, stats_X, nullptr);
    // fused MLP
    k_mlp<<<dim3(BT*LL/128),512,0,stream>>>(
        Wb1, Wb2, XT, X, XT, s11, c1, c2, stats_X, stats_X);
  }

  k_output<<<(unsigned)(((size_t)2*CC*HH*128 + 255)/256), 256, 0, stream>>>(X, (float*)d_out);
}

// Round 14
// 360.097 us; speedup vs baseline: 13.5949x; 1.1203x over previous
//
#include <hip/hip_runtime.h>
#include <cstdint>
#include <cstddef>

#define BT 4
#define CC 96
#define HH 64
#define WW 256
#define LL (HH*WW)    // 16384
#define KD 4
#define RR 6
#define NLAY 2
#define C4 (4*CC)     // 384
#define SLOTF 47424   // per-layer weight-slot stride in float units
#define STPW 4096     // scan: stored elems per wave
#define WARM 512      // scan: warm-up elems

typedef unsigned short u16;
typedef __attribute__((ext_vector_type(8))) short bf16x8;
typedef __attribute__((ext_vector_type(4))) float f32x4;

__device__ __forceinline__ u16 f2bf(float f){
  unsigned u = __float_as_uint(f);
  unsigned r = (u + 0x7FFFu + ((u >> 16) & 1u)) >> 16;
  return (u16)r;
}
__device__ __forceinline__ float bf2f(u16 h){
  return __uint_as_float(((unsigned)h) << 16);
}
__device__ __forceinline__ unsigned pk_bf16(float lo, float hi){
  unsigned r;
  asm volatile("v_cvt_pk_bf16_f32 %0, %1, %2" : "=v"(r) : "v"(lo), "v"(hi));
  return r;
}
__device__ __forceinline__ float fexp2(float x){
  float r; asm("v_exp_f32 %0, %1" : "=v"(r) : "v"(x)); return r;
}
__device__ __forceinline__ float flog2(float x){
  float r; asm("v_log_f32 %0, %1" : "=v"(r) : "v"(x)); return r;
}
// tanh-approx GELU, division-free
__device__ __forceinline__ float gelu_f(float v){
  float t = v*v;
  float u = v*fmaf(0.0356774081f, t, 0.7978845608f);
  float e2 = __expf(2.f*u);
  float r = __builtin_amdgcn_rcpf(e2 + 1.f);
  return fmaf(-v, r, v);
}

// ---------------- build batched input (bf16 plane) ----------------
__global__ void k_build(const float* __restrict__ x0, const float* __restrict__ x1,
                        u16* __restrict__ X){
  size_t i = (size_t)blockIdx.x*256 + threadIdx.x;
  size_t tot = (size_t)2*CC*HH*WW;
  if (i >= tot) return;
  int w = i % WW; size_t r = i / WW;
  int h = r % HH; size_t bc = r / HH;
  float val;
  if (w < 128) val = x0[(bc*HH + h)*128 + w];
  else         val = x1[(bc*HH + h)*128 + (w-128)];
  u16 hv = f2bf(val);
  X[i] = hv;
  size_t ib = ((bc + (size_t)2*CC)*HH + h)*WW + (WW-1-w);
  X[ib] = hv;
}

// ---------------- weight prep: swizzle into MFMA-fragment order ----------------
template<int M, int K, bool FC1ORD, bool LNF, bool BIAS>
__global__ void k_prepw(const float* __restrict__ W, const float* __restrict__ lnw,
      const float* __restrict__ lnb, const float* __restrict__ bias,
      u16* __restrict__ Wb, float* __restrict__ s1, float* __restrict__ cadd){
  int lay = blockIdx.y;
  W += (size_t)lay*M*K;
  Wb += (size_t)lay*SLOTF*2;
  s1 += (size_t)lay*SLOTF;
  cadd += (size_t)lay*SLOTF;
  int m = blockIdx.x*64 + threadIdx.x;
  if (m >= M) return;
  int rowfrag = m >> 4, lr = m & 15;
  float s1v = 0.f, sbv = 0.f;
  for (int c = 0; c < K; ++c){
    float wv = W[(size_t)m*K + c];
    float wf = LNF ? wv*lnw[lay*K + c] : wv;
    u16 h = f2bf(wf);
    int colfrag = c >> 5, lg = (c >> 3) & 3, j = c & 7;
    int f;
    if (FC1ORD) f = (rowfrag/6)*18 + colfrag*6 + (rowfrag % 6);
    else        f = colfrag*(M/16) + rowfrag;
    Wb[(size_t)(f*64 + lg*16 + lr)*8 + j] = h;
    s1v += bf2f(h);
    if (LNF) sbv = fmaf(wv, lnb[lay*K + c], sbv);
  }
  if (BIAS) sbv += bias[lay*M + m];
  s1[m] = s1v;
  cadd[m] = sbv;
}

// ---------------- projection GEMM (M=96,K=96), plane-major bf16 in/out ----------------
// stages B from plane [b][c][l], computes LN stats in-kernel, LN fused via weights.
template<bool RES>
__global__ __launch_bounds__(256) void k_proj(
    const u16* __restrict__ Wb, const u16* __restrict__ inP,
    u16* __restrict__ outP, const u16* __restrict__ resP,
    const float* __restrict__ s1v, const float* __restrict__ cadd){
  __shared__ u16 bt[128*104];
  __shared__ float sA[2][128], sB[2][128], sm[128], sr[128];
  int tid = threadIdx.x, lane = tid & 63, wid = tid >> 6;
  int l0 = blockIdx.x*128;
  int b = l0 >> 14, lb0 = l0 & (LL-1);
  int lr = lane & 15, lg = lane >> 4;
  // stage: each thread owns pixel px, 48 channels
  {
    int px = tid & 127, grp = tid >> 7;
    int ch0 = grp*48;
    const u16* ip = inP + ((size_t)b*CC + ch0)*LL + lb0 + px;
    u16 ch[48];
    float s = 0.f, ss = 0.f;
    #pragma unroll
    for (int j = 0; j < 48; ++j){
      ch[j] = ip[(size_t)j*LL];
      float xv = bf2f(ch[j]);
      s += xv; ss += xv*xv;
    }
    #pragma unroll
    for (int j2 = 0; j2 < 12; ++j2){
      uint2 w2;
      w2.x = (unsigned)ch[j2*4+0] | ((unsigned)ch[j2*4+1] << 16);
      w2.y = (unsigned)ch[j2*4+2] | ((unsigned)ch[j2*4+3] << 16);
      *(uint2*)&bt[px*104 + ch0 + j2*4] = w2;
    }
    sA[grp][px] = s;
    sB[grp][px] = ss;
  }
  __syncthreads();
  if (tid < 128){
    float s = sA[0][tid] + sA[1][tid];
    float ss = sB[0][tid] + sB[1][tid];
    float mu = s*(1.f/CC);
    float var = ss*(1.f/CC) - mu*mu;
    sm[tid] = mu;
    sr[tid] = rsqrtf(var + 1e-5f);
  }
  f32x4 acc[6][2];
  #pragma unroll
  for (int mf = 0; mf < 6; ++mf){ acc[mf][0] = (f32x4){0,0,0,0}; acc[mf][1] = (f32x4){0,0,0,0}; }
  #pragma unroll
  for (int ks = 0; ks < 3; ++ks){
    bf16x8 af[6];
    #pragma unroll
    for (int mf = 0; mf < 6; ++mf)
      af[mf] = *(const bf16x8*)(Wb + (size_t)((ks*6 + mf)*64 + lane)*8);
    bf16x8 bfr[2];
    #pragma unroll
    for (int ls = 0; ls < 2; ++ls)
      bfr[ls] = *(const bf16x8*)&bt[(wid*32 + ls*16 + lr)*104 + ks*32 + lg*8];
    #pragma unroll
    for (int mf = 0; mf < 6; ++mf)
      #pragma unroll
      for (int ls = 0; ls < 2; ++ls)
        acc[mf][ls] = __builtin_amdgcn_mfma_f32_16x16x32_bf16(af[mf], bfr[ls], acc[mf][ls], 0, 0, 0);
  }
  __syncthreads();   // sm/sr ready
  #pragma unroll
  for (int ls = 0; ls < 2; ++ls){
    int row = wid*32 + ls*16 + lr;
    float mu = sm[row], rs = sr[row];
    float nmr = -mu*rs;
    #pragma unroll
    for (int mf = 0; mf < 6; ++mf){
      #pragma unroll
      for (int r = 0; r < 4; ++r){
        int mm = mf*16 + lg*4 + r;
        float vv = fmaf(rs, acc[mf][ls][r], fmaf(nmr, s1v[mm], cadd[mm]));
        size_t idx = ((size_t)b*CC + mm)*LL + lb0 + row;
        if (RES) vv += bf2f(resP[idx]);
        outP[idx] = f2bf(vv);
      }
    }
  }
}

// ---------------- fused MLP v5: plane-major bf16 io, in-kernel stats ----------------
__global__ __launch_bounds__(512, 4) void k_mlp(
    const u16* __restrict__ Wb1, const u16* __restrict__ Wb2,
    u16* __restrict__ X,
    const float* __restrict__ s11, const float* __restrict__ c1,
    const float* __restrict__ c2){
  __shared__ u16 bt[128*104];
  __shared__ u16 hs[128*104];
  __shared__ float sm[128], sr[128];
  float* sA = (float*)hs;            // [4][128] overlaid on hs (dead until cc loop)
  float* sB = sA + 512;              // [4][128]
  int tid = threadIdx.x, lane = tid & 63, wid = tid >> 6;   // wid 0..7
  int l0 = blockIdx.x*128;
  int b = l0 >> 14, lb0 = l0 & (LL-1);
  int lr = lane & 15, lg = lane >> 4;
  // stage: 4 channel-groups of 24, 128 pixels
  {
    int px = tid & 127, grp = tid >> 7;   // 0..3
    int ch0 = grp*24;
    const u16* ip = X + ((size_t)b*CC + ch0)*LL + lb0 + px;
    u16 ch[24];
    float s = 0.f, ss = 0.f;
    #pragma unroll
    for (int j = 0; j < 24; ++j){
      ch[j] = ip[(size_t)j*LL];
      float xv = bf2f(ch[j]);
      s += xv; ss += xv*xv;
    }
    #pragma unroll
    for (int j2 = 0; j2 < 6; ++j2){
      uint2 w2;
      w2.x = (unsigned)ch[j2*4+0] | ((unsigned)ch[j2*4+1] << 16);
      w2.y = (unsigned)ch[j2*4+2] | ((unsigned)ch[j2*4+3] << 16);
      *(uint2*)&bt[px*104 + ch0 + j2*4] = w2;
    }
    sA[grp*128 + px] = s;
    sB[grp*128 + px] = ss;
  }
  __syncthreads();
  if (tid < 128){
    float s = sA[tid] + sA[128+tid] + sA[256+tid] + sA[384+tid];
    float ss = sB[tid] + sB[128+tid] + sB[256+tid] + sB[384+tid];
    float mu = s*(1.f/CC);
    float var = ss*(1.f/CC) - mu*mu;
    sm[tid] = mu;
    sr[tid] = rsqrtf(var + 1e-5f);
  }
  __syncthreads();
  int row = wid*16 + lr;             // this lane's pixel (0..127)
  float rs = sr[row];
  float nmr = -sm[row]*rs;

  int hrow = row*104;
  f32x4 acc2[6];
  #pragma unroll
  for (int mf = 0; mf < 6; ++mf) acc2[mf] = (f32x4){0,0,0,0};

  for (int cc = 0; cc < 4; ++cc){
    f32x4 acc1[6];
    #pragma unroll
    for (int mf = 0; mf < 6; ++mf) acc1[mf] = (f32x4){0,0,0,0};
    #pragma unroll
    for (int ks = 0; ks < 3; ++ks){
      bf16x8 af[6];
      #pragma unroll
      for (int mf = 0; mf < 6; ++mf)
        af[mf] = *(const bf16x8*)(Wb1 + (size_t)((cc*18 + ks*6 + mf)*64 + lane)*8);
      bf16x8 bfr = *(const bf16x8*)&bt[hrow + ks*32 + lg*8];
      #pragma unroll
      for (int mf = 0; mf < 6; ++mf)
        acc1[mf] = __builtin_amdgcn_mfma_f32_16x16x32_bf16(af[mf], bfr, acc1[mf], 0, 0, 0);
    }
    #pragma unroll
    for (int mf = 0; mf < 6; ++mf){
      float4 sv = *(const float4*)&s11[cc*96 + mf*16 + lg*4];
      float4 cv = *(const float4*)&c1 [cc*96 + mf*16 + lg*4];
      float g0 = gelu_f(fmaf(rs, acc1[mf][0], fmaf(nmr, sv.x, cv.x)));
      float g1 = gelu_f(fmaf(rs, acc1[mf][1], fmaf(nmr, sv.y, cv.y)));
      float g2 = gelu_f(fmaf(rs, acc1[mf][2], fmaf(nmr, sv.z, cv.z)));
      float g3 = gelu_f(fmaf(rs, acc1[mf][3], fmaf(nmr, sv.w, cv.w)));
      uint2 pw;
      pw.x = pk_bf16(g0, g1);
      pw.y = pk_bf16(g2, g3);
      *(uint2*)&hs[hrow + mf*16 + lg*4] = pw;
    }
    #pragma unroll
    for (int ks = 0; ks < 3; ++ks){
      bf16x8 a2[6];
      #pragma unroll
      for (int mf2 = 0; mf2 < 6; ++mf2)
        a2[mf2] = *(const bf16x8*)(Wb2 + (size_t)(((cc*3 + ks)*6 + mf2)*64 + lane)*8);
      bf16x8 bfr2 = *(const bf16x8*)&hs[hrow + ks*32 + lg*8];
      #pragma unroll
      for (int mf2 = 0; mf2 < 6; ++mf2)
        acc2[mf2] = __builtin_amdgcn_mfma_f32_16x16x32_bf16(a2[mf2], bfr2, acc2[mf2], 0, 0, 0);
    }
  }
  // epilogue: + c2 + residual -> X bf16 plane
  #pragma unroll
  for (int mf = 0; mf < 6; ++mf){
    #pragma unroll
    for (int r = 0; r < 4; ++r){
      int mm = mf*16 + lg*4 + r;
      size_t idx = ((size_t)b*CC + mm)*LL + lb0 + row;
      float vv = acc2[mf][r] + c2[mm] + bf2f(X[idx]);
      X[idx] = f2bf(vv);
    }
  }
}

// ---------------- depthwise 3x3 + SiLU (bf16 in/out), fused transpose ----------------
__global__ __launch_bounds__(256) void k_dwconv_silu_t(const u16* __restrict__ u,
      u16* __restrict__ v, u16* __restrict__ vT, const float* __restrict__ cw){
  __shared__ float tl[32][33];
  int bc = blockIdx.z;
  int c = bc % CC;
  int w0 = blockIdx.x*32, h0 = blockIdx.y*32;
  const u16* up = u + (size_t)bc*LL;
  const float* k9 = cw + c*9;
  int t = threadIdx.x;
  int wl = (t & 7)*4, hl = t >> 3;
  int h = h0 + hl, w = w0 + wl;
  float acc[4] = {0.f,0.f,0.f,0.f};
  #pragma unroll
  for (int dh = -1; dh <= 1; ++dh){
    int h2 = h + dh;
    if (h2 < 0 || h2 >= HH) continue;
    const u16* row = up + (size_t)h2*WW + w;
    ushort4 mq = *(const ushort4*)row;
    float m0 = bf2f(mq.x), m1 = bf2f(mq.y), m2 = bf2f(mq.z), m3 = bf2f(mq.w);
    float lft = (w > 0) ? bf2f(row[-1]) : 0.f;
    float rgt = (w + 4 < WW) ? bf2f(row[4]) : 0.f;
    float k0 = k9[(dh+1)*3], k1 = k9[(dh+1)*3+1], k2 = k9[(dh+1)*3+2];
    acc[0] += lft*k0 + m0*k1 + m1*k2;
    acc[1] += m0*k0 + m1*k1 + m2*k2;
    acc[2] += m1*k0 + m2*k1 + m3*k2;
    acc[3] += m2*k0 + m3*k1 + rgt*k2;
  }
  float s[4];
  #pragma unroll
  for (int j = 0; j < 4; ++j){
    float a = acc[j];
    float e = __expf(-a);
    s[j] = a * __builtin_amdgcn_rcpf(1.f + e);
    tl[wl + j][hl] = s[j];
  }
  uint2 pw;
  pw.x = pk_bf16(s[0], s[1]);
  pw.y = pk_bf16(s[2], s[3]);
  *(uint2*)&v[(size_t)bc*LL + (size_t)h*WW + w] = pw;
  __syncthreads();
  int ww = t >> 3, hh4 = (t & 7)*4;
  uint2 po;
  po.x = pk_bf16(tl[ww][hh4],   tl[ww][hh4+1]);
  po.y = pk_bf16(tl[ww][hh4+2], tl[ww][hh4+3]);
  *(uint2*)&vT[(size_t)bc*LL + (size_t)(w0 + ww)*HH + h0 + hh4] = po;
}

// ---------------- x-projection (bf16 src, bf16 G out) ----------------
__global__ void k_xproj(const u16* __restrict__ v, const u16* __restrict__ vT,
                        u16* __restrict__ G, const float* __restrict__ xpw){
  int which = blockIdx.y;
  const u16* src = which ? vT : v;
  int kA = which ? 1 : 0, kB = which ? 3 : 2;
  size_t i = (size_t)blockIdx.x*256 + threadIdx.x;
  if (i >= (size_t)BT*LL) return;
  int b = (int)(i / LL), l = (int)(i % LL);
  const u16* sp = src + (size_t)b*CC*LL + l;
  const float* wA = xpw + (size_t)kA*8*CC;
  const float* wB = xpw + (size_t)kB*8*CC;
  float aA[8], aB[8];
  #pragma unroll
  for (int d = 0; d < 8; ++d){ aA[d] = 0.f; aB[d] = 0.f; }
  for (int c = 0; c < CC; ++c){
    float xv = bf2f(sp[(size_t)c*LL]);
    #pragma unroll
    for (int d = 0; d < 8; ++d){
      aA[d] = fmaf(wA[d*CC + c], xv, aA[d]);
      aB[d] = fmaf(wB[d*CC + c], xv, aB[d]);
    }
  }
  u16* gA = G + (((size_t)b*KD + kA)*8)*LL + l;
  u16* gB = G + (((size_t)b*KD + kB)*8)*LL + l;
  #pragma unroll
  for (int d = 0; d < 8; ++d){ gA[(size_t)d*LL] = f2bf(aA[d]); gB[(size_t)d*LL] = f2bf(aB[d]); }
}

// ---------------- scan v5: 4096/wave, 8 elems/lane, bf16 G/src/out ----------------
__device__ __forceinline__ void ldbf8(const u16* p, float* o){
  uint4 t = *(const uint4*)p;
  o[0]=bf2f((u16)(t.x & 0xffff)); o[1]=bf2f((u16)(t.x >> 16));
  o[2]=bf2f((u16)(t.y & 0xffff)); o[3]=bf2f((u16)(t.y >> 16));
  o[4]=bf2f((u16)(t.z & 0xffff)); o[5]=bf2f((u16)(t.z >> 16));
  o[6]=bf2f((u16)(t.w & 0xffff)); o[7]=bf2f((u16)(t.w >> 16));
}
__device__ __forceinline__ void rev8(float* a){
  #pragma unroll
  for (int i = 0; i < 4; ++i){ float t0 = a[i]; a[i] = a[7-i]; a[7-i] = t0; }
}

__global__ __launch_bounds__(256) void k_scan3(const u16* __restrict__ G,
                       const u16* __restrict__ v, const u16* __restrict__ vT,
                       u16* __restrict__ Y,
                       const float* __restrict__ dtw_, const float* __restrict__ dtb_,
                       const float* __restrict__ Alog_, const float* __restrict__ Ds_){
  const size_t SZ = (size_t)BT*CC*LL;
  const float LOG2E = 1.4426950408889634f, LN2 = 0.6931471805599453f;
  int wid = threadIdx.x >> 6, lane = threadIdx.x & 63;
  int tile = wid;                              // 0..3 (4 tiles x 4096 = 16384)
  int sy = blockIdx.y;
  bool rev = (blockIdx.z != 0);
  int c = sy % CC; int t2 = sy / CC; int kk = t2 & 1; int b = t2 >> 1;
  int k = (rev ? 2 : 0) + kk;
  const u16* src = (kk ? vT : v) + ((size_t)b*CC + c)*LL;
  const u16* g = G + (((size_t)b*KD + k)*8)*LL;
  float dtw[RR];
  #pragma unroll
  for (int r = 0; r < RR; ++r) dtw[r] = dtw_[((size_t)k*CC + c)*RR + r];
  float dtb = dtb_[k*CC + c];
  float A  = -__expf(Alog_[k*CC + c]);
  float Dv = Ds_[k*CC + c];
  u16* yout = Y + (size_t)k*SZ + ((size_t)b*CC + c)*LL;

  int lstore0 = tile*STPW;
  float carry = 0.f;
  for (int p = 0; p < 1 + STPW/WARM; ++p){
    int base = lstore0 - WARM + p*WARM;
    if (base < 0) continue;                    // tile 0: no warm-up
    bool st = (base >= lstore0);
    int l = base + (lane<<3);
    int ga = rev ? (LL-8-l) : l;
    float dsum[8], g6b[8], g7b[8], xb[8];
    #pragma unroll
    for (int i = 0; i < 8; ++i) dsum[i] = dtb;
    #pragma unroll
    for (int r = 0; r < RR; ++r){
      float t8[8];
      ldbf8(g + (size_t)r*LL + ga, t8);
      #pragma unroll
      for (int i = 0; i < 8; ++i) dsum[i] = fmaf(t8[i], dtw[r], dsum[i]);
    }
    ldbf8(g + (size_t)6*LL + ga, g6b);
    if (st){
      ldbf8(g + (size_t)7*LL + ga, g7b);
    } else {
      #pragma unroll
      for (int i = 0; i < 8; ++i) g7b[i] = 0.f;
    }
    ldbf8(src + ga, xb);
    if (rev){ rev8(dsum); rev8(g6b); rev8(g7b); rev8(xb); }
    float av[8], bt[8];
    #pragma unroll
    for (int i = 0; i < 8; ++i){
      float dl2 = dsum[i]*LOG2E;
      float y = flog2(1.f + fexp2(dl2));
      y = (dsum[i] > 20.f) ? dl2 : y;
      float delta = y*LN2;
      av[i] = fexp2(A*y);
      bt[i] = delta * g6b[i] * xb[i];
    }
    float P = av[0], Q = bt[0];
    #pragma unroll
    for (int i = 1; i < 8; ++i){ Q = fmaf(av[i], Q, bt[i]); P *= av[i]; }
    #pragma unroll
    for (int off = 1; off < 64; off <<= 1){
      float Pp = __shfl_up(P, (unsigned)off);
      float Qp = __shfl_up(Q, (unsigned)off);
      if (lane >= off){ Q = fmaf(P, Qp, Q); P *= Pp; }
    }
    float Pe = __shfl_up(P, 1u), Qe = __shfl_up(Q, 1u);
    if (lane == 0){ Pe = 1.f; Qe = 0.f; }
    float h = fmaf(Pe, carry, Qe);
    if (st){
      float ys[8];
      #pragma unroll
      for (int i = 0; i < 8; ++i){
        h = fmaf(av[i], h, bt[i]);
        ys[i] = fmaf(g7b[i], h, Dv*xb[i]);
      }
      carry = __shfl(h, 63);
      if (rev) rev8(ys);
      uint4 pw;
      pw.x = pk_bf16(ys[0], ys[1]);
      pw.y = pk_bf16(ys[2], ys[3]);
      pw.z = pk_bf16(ys[4], ys[5]);
      pw.w = pk_bf16(ys[6], ys[7]);
      *(uint4*)&yout[ga] = pw;
    } else {
      #pragma unroll
      for (int i = 0; i < 8; ++i) h = fmaf(av[i], h, bt[i]);
      carry = __shfl(h, 63);
    }
  }
}

// ---------------- combine (bf16 in/out): z = (y0+y2) + transpose(y1+y3) ----------------
__global__ __launch_bounds__(256) void k_combine4(const u16* __restrict__ Y, u16* __restrict__ z){
  const size_t SZ = (size_t)BT*CC*LL;
  __shared__ float tl[64][65];
  int bc = blockIdx.z;
  int w0 = blockIdx.x*64;
  int t = threadIdx.x;
  const u16* y1p = Y + SZ   + (size_t)bc*LL;
  const u16* y3p = Y + 3*SZ + (size_t)bc*LL;
  {
    int wl = t >> 2;            // 0..63
    int h0 = (t & 3)*16;        // 0,16,32,48
    size_t base = (size_t)(w0 + wl)*HH + h0;
    #pragma unroll
    for (int j = 0; j < 4; ++j){
      ushort4 a = *(const ushort4*)&y1p[base + j*4];
      ushort4 bq = *(const ushort4*)&y3p[base + j*4];
      tl[wl][h0 + j*4 + 0] = bf2f(a.x) + bf2f(bq.x);
      tl[wl][h0 + j*4 + 1] = bf2f(a.y) + bf2f(bq.y);
      tl[wl][h0 + j*4 + 2] = bf2f(a.z) + bf2f(bq.z);
      tl[wl][h0 + j*4 + 3] = bf2f(a.w) + bf2f(bq.w);
    }
  }
  __syncthreads();
  const u16* y0p = Y +        (size_t)bc*LL;
  const u16* y2p = Y + 2*SZ + (size_t)bc*LL;
  u16* zp = z + (size_t)bc*LL;
  {
    int h = t >> 2;             // 0..63
    int wq = (t & 3)*16;        // 0,16,32,48
    #pragma unroll
    for (int j = 0; j < 4; ++j){
      int wl = wq + j*4;
      size_t idx = (size_t)h*WW + w0 + wl;
      ushort4 a = *(const ushort4*)&y0p[idx];
      ushort4 bq = *(const ushort4*)&y2p[idx];
      ushort4 o;
      o.x = f2bf(bf2f(a.x) + bf2f(bq.x) + tl[wl+0][h]);
      o.y = f2bf(bf2f(a.y) + bf2f(bq.y) + tl[wl+1][h]);
      o.z = f2bf(bf2f(a.z) + bf2f(bq.z) + tl[wl+2][h]);
      o.w = f2bf(bf2f(a.w) + bf2f(bq.w) + tl[wl+3][h]);
      *(ushort4*)&zp[idx] = o;
    }
  }
}

// ---------------- final output split/average (bf16 X -> f32 out) ----------------
__global__ void k_output(const u16* __restrict__ X, float* __restrict__ out){
  size_t i = (size_t)blockIdx.x*256 + threadIdx.x;
  size_t half = (size_t)2*CC*HH*128;
  if (i >= half) return;
  int w = i % 128; size_t r = i / 128;
  int h = r % HH; size_t bc = r / HH;
  size_t fwd = (bc*HH + h)*WW;
  size_t bwd = ((bc + (size_t)2*CC)*HH + h)*WW;
  out[i]        = 0.5f*(bf2f(X[fwd + w])       + bf2f(X[bwd + (WW-1-w)]));
  out[half + i] = 0.5f*(bf2f(X[fwd + 128 + w]) + bf2f(X[bwd + (127 - w)]));
}

extern "C" void kernel_launch(void* const* d_in, const int* in_sizes, int n_in,
                              void* d_out, int out_size, void* d_ws, size_t ws_size,
                              hipStream_t stream){
  const float* x0        = (const float*)d_in[0];
  const float* x1        = (const float*)d_in[1];
  const float* norm_w    = (const float*)d_in[2];
  const float* norm_b    = (const float*)d_in[3];
  const float* in_proj_w = (const float*)d_in[4];
  const float* conv_w    = (const float*)d_in[5];
  const float* x_proj_w  = (const float*)d_in[6];
  const float* dt_w      = (const float*)d_in[7];
  const float* dt_b      = (const float*)d_in[8];
  const float* A_logs    = (const float*)d_in[9];
  const float* Ds        = (const float*)d_in[10];
  const float* out_norm_w= (const float*)d_in[11];
  const float* out_norm_b= (const float*)d_in[12];
  const float* out_proj_w= (const float*)d_in[13];
  const float* norm2_w   = (const float*)d_in[14];
  const float* norm2_b   = (const float*)d_in[15];
  const float* fc1_w     = (const float*)d_in[16];
  const float* fc1_b     = (const float*)d_in[17];
  const float* fc2_w     = (const float*)d_in[18];
  const float* fc2_b     = (const float*)d_in[19];

  const size_t SZ = (size_t)BT*CC*LL;            // 6,291,456 elems
  u16* Xb  = (u16*)d_ws;
  u16* tB  = Xb + SZ;
  u16* uB  = tB + SZ;
  u16* vB  = uB + SZ;
  u16* vTB = vB + SZ;
  u16* Gb  = vTB + SZ;                           // BT*KD*8*LL u16
  u16* Yb  = Gb + (size_t)BT*KD*8*LL;            // 4*SZ u16
  float* wsl = (float*)(Yb + 4*SZ);              // weight slots

  float* p0 = wsl;
  u16*  WbI0 = (u16*)p0;          float* s1I0 = p0 + 4608;  float* cI0 = p0 + 4704;
  u16*  WbO0 = (u16*)(p0+4800);   float* s1O0 = p0 + 9408;  float* cO0 = p0 + 9504;
  u16*  Wb10 = (u16*)(p0+9600);   float* s110 = p0 + 28032; float* c10 = p0 + 28416;
  u16*  Wb20 = (u16*)(p0+28800);  float* s120 = p0 + 47232; float* c20 = p0 + 47328;

  k_prepw<96,96,false,true,false><<<dim3(2,NLAY),64,0,stream>>>(in_proj_w, norm_w, norm_b, nullptr, WbI0, s1I0, cI0);
  k_prepw<96,96,false,true,false><<<dim3(2,NLAY),64,0,stream>>>(out_proj_w, out_norm_w, out_norm_b, nullptr, WbO0, s1O0, cO0);
  k_prepw<384,96,true,true,true><<<dim3(6,NLAY),64,0,stream>>>(fc1_w, norm2_w, norm2_b, fc1_b, Wb10, s110, c10);
  k_prepw<96,384,false,false,true><<<dim3(2,NLAY),64,0,stream>>>(fc2_w, nullptr, nullptr, fc2_b, Wb20, s120, c20);

  k_build<<<(2*CC*HH*WW + 255)/256, 256, 0, stream>>>(x0, x1, Xb);

  for (int lay = 0; lay < NLAY; ++lay){
    size_t so = (size_t)lay*SLOTF;
    const u16* WbI = WbI0 + so*2; const float* s1I = s1I0 + so; const float* cI = cI0 + so;
    const u16* WbO = WbO0 + so*2; const float* s1O = s1O0 + so; const float* cO = cO0 + so;
    const u16* Wb1 = Wb10 + so*2; const float* s11 = s110 + so; const float* c1 = c10 + so;
    const u16* Wb2 = Wb20 + so*2; const float* c2 = c20 + so;
    const float* cw  = conv_w    + (size_t)lay*CC*9;
    const float* xpw = x_proj_w  + (size_t)lay*KD*8*CC;
    const float* dw  = dt_w      + (size_t)lay*KD*CC*RR;
    const float* db  = dt_b      + (size_t)lay*KD*CC;
    const float* Al  = A_logs    + (size_t)lay*KD*CC;
    const float* Dp  = Ds        + (size_t)lay*KD*CC;

    // in_proj (LN fused, in-kernel stats): uB = bf16(W' * LN(X))
    k_proj<false><<<dim3(BT*LL/128),256,0,stream>>>(WbI, Xb, uB, nullptr, s1I, cI);
    k_dwconv_silu_t<<<dim3(8,2,BT*CC), 256, 0, stream>>>(uB, vB, vTB, cw);
    k_xproj<<<dim3(BT*LL/256, 2), 256, 0, stream>>>(vB, vTB, Gb, xpw);
    k_scan3<<<dim3(1,768,2), 256, 0, stream>>>(Gb, vB, vTB, Yb, dw, db, Al, Dp);
    k_combine4<<<dim3(4,1,BT*CC), 256, 0, stream>>>(Yb, tB);
    // out_proj (LN fused, in-kernel stats) + residual -> Xb
    k_proj<true><<<dim3(BT*LL/128),256,0,stream>>>(WbO, tB, Xb, Xb, s1O, cO);
    // fused MLP (LN fused, in-kernel stats) + residual -> Xb
    k_mlp<<<dim3(BT*LL/128),512,0,stream>>>(Wb1, Wb2, Xb, s11, c1, c2);
  }

  k_output<<<(unsigned)(((size_t)2*CC*HH*128 + 255)/256), 256, 0, stream>>>(Xb, (float*)d_out);
}